// Round 1
// baseline (4364.054 us; speedup 1.0000x reference)
//
#include <hip/hip_runtime.h>
#include <hip/hip_bf16.h>
#include <math.h>

// Problem constants
#define BATCH 2
#define SEQ   2048
#define EMB   1024
#define NH    16
#define HD    64
#define M_ROWS (BATCH * SEQ)   // 4096

// ---------------------------------------------------------------------------
// Tiled fp32 GEMM: C[M,N] = A[M,K] * B[N,K]^T + bias[N]
// 64x64 tile, BK=32, 256 threads, each thread computes 4x4 outputs.
// All dims divide tile sizes exactly for this problem (M=4096, N=3072/1024, K=1024).
// ---------------------------------------------------------------------------
__global__ __launch_bounds__(256) void gemm_abt(
    const float* __restrict__ A, const float* __restrict__ B,
    const float* __restrict__ bias, float* __restrict__ C,
    int M, int N, int K)
{
    __shared__ float As[64][33];   // +1 pad: column reads spread across banks
    __shared__ float Bs[64][33];

    const int tid = threadIdx.x;         // 0..255
    const int tx = tid & 15;             // 0..15
    const int ty = tid >> 4;             // 0..15
    const int m0 = blockIdx.y * 64;
    const int n0 = blockIdx.x * 64;

    float acc[4][4];
#pragma unroll
    for (int i = 0; i < 4; ++i)
#pragma unroll
        for (int j = 0; j < 4; ++j) acc[i][j] = 0.f;

    for (int k0 = 0; k0 < K; k0 += 32) {
        // Stage 64x32 tiles of A and B. 2048 floats each = 512 float4.
#pragma unroll
        for (int i = 0; i < 2; ++i) {
            int idx = tid + i * 256;          // 0..511
            int r = idx >> 3;                 // row 0..63
            int c = (idx & 7) << 2;           // col 0,4,..,28
            float4 av = *reinterpret_cast<const float4*>(
                &A[(size_t)(m0 + r) * K + k0 + c]);
            As[r][c + 0] = av.x; As[r][c + 1] = av.y;
            As[r][c + 2] = av.z; As[r][c + 3] = av.w;
            float4 bv = *reinterpret_cast<const float4*>(
                &B[(size_t)(n0 + r) * K + k0 + c]);
            Bs[r][c + 0] = bv.x; Bs[r][c + 1] = bv.y;
            Bs[r][c + 2] = bv.z; Bs[r][c + 3] = bv.w;
        }
        __syncthreads();

#pragma unroll
        for (int kk = 0; kk < 32; ++kk) {
            float a[4], b[4];
#pragma unroll
            for (int i = 0; i < 4; ++i) a[i] = As[ty * 4 + i][kk];
#pragma unroll
            for (int j = 0; j < 4; ++j) b[j] = Bs[tx * 4 + j][kk];
#pragma unroll
            for (int i = 0; i < 4; ++i)
#pragma unroll
                for (int j = 0; j < 4; ++j) acc[i][j] += a[i] * b[j];
        }
        __syncthreads();
    }

#pragma unroll
    for (int i = 0; i < 4; ++i) {
        const size_t row = (size_t)(m0 + ty * 4 + i);
#pragma unroll
        for (int j = 0; j < 4; ++j) {
            int col = n0 + tx * 4 + j;
            C[row * N + col] = acc[i][j] + bias[col];
        }
    }
}

// ---------------------------------------------------------------------------
// Causal attention, one thread per query row.
// qkv layout: [B, T, 3E] fp32; q = cols [0,E), k = [E,2E), v = [2E,3E).
// Head h occupies cols h*HD..h*HD+63 inside each third.
// y layout: [B, T, E] with head h at cols h*HD.. (matches ref transpose+reshape)
// ---------------------------------------------------------------------------
__global__ __launch_bounds__(256) void attn_kernel(
    const float* __restrict__ qkv, float* __restrict__ y)
{
    const int t  = blockIdx.x * blockDim.x + threadIdx.x;  // query row 0..2047
    const int bh = blockIdx.y;                              // 0..31
    const int b  = bh >> 4;
    const int h  = bh & 15;

    const float* base = qkv + (size_t)b * SEQ * 3 * EMB;
    const float4* qrow = reinterpret_cast<const float4*>(
        base + (size_t)t * 3 * EMB + h * HD);

    float4 q[16];
#pragma unroll
    for (int i = 0; i < 16; ++i) q[i] = qrow[i];

    float4 o[16];
#pragma unroll
    for (int i = 0; i < 16; ++i) o[i] = make_float4(0.f, 0.f, 0.f, 0.f);

    float m = -INFINITY, l = 0.f;

    for (int kt = 0; kt <= t; ++kt) {
        const float4* krow = reinterpret_cast<const float4*>(
            base + (size_t)kt * 3 * EMB + EMB + h * HD);
        float s = 0.f;
#pragma unroll
        for (int i = 0; i < 16; ++i) {
            float4 kv = krow[i];
            s += q[i].x * kv.x + q[i].y * kv.y + q[i].z * kv.z + q[i].w * kv.w;
        }
        s *= 0.125f;   // 1/sqrt(64)

        if (s > m) {   // new running max (rare after warm-up)
            float c = __expf(m - s);
            l *= c;
#pragma unroll
            for (int i = 0; i < 16; ++i) {
                o[i].x *= c; o[i].y *= c; o[i].z *= c; o[i].w *= c;
            }
            m = s;
        }
        float p = __expf(s - m);
        l += p;

        const float4* vrow = reinterpret_cast<const float4*>(
            base + (size_t)kt * 3 * EMB + 2 * EMB + h * HD);
#pragma unroll
        for (int i = 0; i < 16; ++i) {
            float4 vv = vrow[i];
            o[i].x += p * vv.x; o[i].y += p * vv.y;
            o[i].z += p * vv.z; o[i].w += p * vv.w;
        }
    }

    const float inv = 1.f / l;
    float4* yo = reinterpret_cast<float4*>(
        y + (size_t)(b * SEQ + t) * EMB + h * HD);
#pragma unroll
    for (int i = 0; i < 16; ++i) {
        yo[i] = make_float4(o[i].x * inv, o[i].y * inv, o[i].z * inv, o[i].w * inv);
    }
}

// ---------------------------------------------------------------------------
extern "C" void kernel_launch(void* const* d_in, const int* in_sizes, int n_in,
                              void* d_out, int out_size, void* d_ws, size_t ws_size,
                              hipStream_t stream)
{
    const float* x     = (const float*)d_in[0];   // [B,T,E]
    const float* qkv_w = (const float*)d_in[1];   // [3E,E]
    const float* qkv_b = (const float*)d_in[2];   // [3E]
    const float* o_w   = (const float*)d_in[3];   // [E,E]
    const float* o_b   = (const float*)d_in[4];   // [E]
    float* out = (float*)d_out;                   // [B,T,E]

    float* qkv  = (float*)d_ws;                           // [M, 3E] = 4096*3072
    float* ybuf = qkv + (size_t)M_ROWS * 3 * EMB;         // [M, E]  = 4096*1024

    // 1) QKV projection: qkv = x @ qkv_w^T + qkv_b
    {
        dim3 grid(3 * EMB / 64, M_ROWS / 64);  // (48, 64)
        gemm_abt<<<grid, 256, 0, stream>>>(x, qkv_w, qkv_b, qkv,
                                           M_ROWS, 3 * EMB, EMB);
    }

    // 2) Causal attention -> ybuf [B,T,E]
    {
        dim3 grid(SEQ / 256, BATCH * NH);      // (8, 32)
        attn_kernel<<<grid, 256, 0, stream>>>(qkv, ybuf);
    }

    // 3) Output projection: out = ybuf @ o_w^T + o_b
    {
        dim3 grid(EMB / 64, M_ROWS / 64);      // (16, 64)
        gemm_abt<<<grid, 256, 0, stream>>>(ybuf, o_w, o_b, out,
                                           M_ROWS, EMB, EMB);
    }
}

// Round 2
// 1267.243 us; speedup vs baseline: 3.4437x; 3.4437x over previous
//
#include <hip/hip_runtime.h>
#include <hip/hip_bf16.h>
#include <math.h>

// Problem constants
#define BATCH 2
#define SEQ   2048
#define EMB   1024
#define NH    16
#define HD    64
#define M_ROWS (BATCH * SEQ)   // 4096
#define LDP   72               // LDS row stride (floats): 288B, 16B-aligned, banks shift by 8

// ---------------------------------------------------------------------------
// Tiled fp32 GEMM: C[M,N] = A[M,K] * B[N,K]^T + bias[N]   (unchanged)
// ---------------------------------------------------------------------------
__global__ __launch_bounds__(256) void gemm_abt(
    const float* __restrict__ A, const float* __restrict__ B,
    const float* __restrict__ bias, float* __restrict__ C,
    int M, int N, int K)
{
    __shared__ float As[64][33];
    __shared__ float Bs[64][33];

    const int tid = threadIdx.x;
    const int tx = tid & 15;
    const int ty = tid >> 4;
    const int m0 = blockIdx.y * 64;
    const int n0 = blockIdx.x * 64;

    float acc[4][4];
#pragma unroll
    for (int i = 0; i < 4; ++i)
#pragma unroll
        for (int j = 0; j < 4; ++j) acc[i][j] = 0.f;

    for (int k0 = 0; k0 < K; k0 += 32) {
#pragma unroll
        for (int i = 0; i < 2; ++i) {
            int idx = tid + i * 256;
            int r = idx >> 3;
            int c = (idx & 7) << 2;
            float4 av = *reinterpret_cast<const float4*>(
                &A[(size_t)(m0 + r) * K + k0 + c]);
            As[r][c + 0] = av.x; As[r][c + 1] = av.y;
            As[r][c + 2] = av.z; As[r][c + 3] = av.w;
            float4 bv = *reinterpret_cast<const float4*>(
                &B[(size_t)(n0 + r) * K + k0 + c]);
            Bs[r][c + 0] = bv.x; Bs[r][c + 1] = bv.y;
            Bs[r][c + 2] = bv.z; Bs[r][c + 3] = bv.w;
        }
        __syncthreads();

#pragma unroll
        for (int kk = 0; kk < 32; ++kk) {
            float a[4], b[4];
#pragma unroll
            for (int i = 0; i < 4; ++i) a[i] = As[ty * 4 + i][kk];
#pragma unroll
            for (int j = 0; j < 4; ++j) b[j] = Bs[tx * 4 + j][kk];
#pragma unroll
            for (int i = 0; i < 4; ++i)
#pragma unroll
                for (int j = 0; j < 4; ++j) acc[i][j] += a[i] * b[j];
        }
        __syncthreads();
    }

#pragma unroll
    for (int i = 0; i < 4; ++i) {
        const size_t row = (size_t)(m0 + ty * 4 + i);
#pragma unroll
        for (int j = 0; j < 4; ++j) {
            int col = n0 + tx * 4 + j;
            C[row * N + col] = acc[i][j] + bias[col];
        }
    }
}

// ---------------------------------------------------------------------------
// Flash-attention (fp32, VALU). One block = one (b,h) x 64-query tile.
// 256 threads; thread (ty,tx) owns a 4x4 patch of the 64x64 S/P tile and a
// 4(query)x4(dim) patch of the 64x64 O tile.
// LDS: Qt/Kt transposed [d][row] so the S-GEMM reads are ds_read_b128;
//      V natural [k][d]; Pt transposed [k][q] for the PV-GEMM.
// ---------------------------------------------------------------------------
__global__ __launch_bounds__(256) void attn_flash(
    const float* __restrict__ qkv, float* __restrict__ y)
{
    __shared__ float Qt[64 * LDP];   // Qt[d][q]
    __shared__ float Kt[64 * LDP];   // Kt[d][k]
    __shared__ float Vs[64 * LDP];   // Vs[k][d]
    __shared__ float Pt[64 * LDP];   // Pt[k][q]

    const int tid = threadIdx.x;
    const int tx = tid & 15;             // col group
    const int ty = tid >> 4;             // row group
    const int qt = (gridDim.x - 1) - blockIdx.x;   // long blocks dispatch first
    const int bh = blockIdx.y;
    const int b  = bh >> 4;
    const int h  = bh & 15;

    const float* base = qkv + (size_t)b * SEQ * 3 * EMB + h * HD;

    // Stage Q tile transposed: Qt[d][q_local]
#pragma unroll
    for (int it = 0; it < 4; ++it) {
        int idx = tid + it * 256;        // 0..1023
        int r = idx >> 4;                // q_local 0..63
        int c = (idx & 15) << 2;         // dim 0,4,..,60
        float4 v = *reinterpret_cast<const float4*>(
            base + (size_t)(qt * 64 + r) * 3 * EMB + c);
        Qt[(c + 0) * LDP + r] = v.x; Qt[(c + 1) * LDP + r] = v.y;
        Qt[(c + 2) * LDP + r] = v.z; Qt[(c + 3) * LDP + r] = v.w;
    }

    float o[4][4];
    float m[4], l[4];
#pragma unroll
    for (int i = 0; i < 4; ++i) {
        m[i] = -INFINITY; l[i] = 0.f;
#pragma unroll
        for (int j = 0; j < 4; ++j) o[i][j] = 0.f;
    }

    for (int kt = 0; kt <= qt; ++kt) {
        // Stage K tile transposed + V tile natural
#pragma unroll
        for (int it = 0; it < 4; ++it) {
            int idx = tid + it * 256;
            int r = idx >> 4;            // k_local 0..63
            int c = (idx & 15) << 2;     // dim
            const float* krow = base + (size_t)(kt * 64 + r) * 3 * EMB + EMB;
            float4 kv = *reinterpret_cast<const float4*>(krow + c);
            Kt[(c + 0) * LDP + r] = kv.x; Kt[(c + 1) * LDP + r] = kv.y;
            Kt[(c + 2) * LDP + r] = kv.z; Kt[(c + 3) * LDP + r] = kv.w;
            float4 vv = *reinterpret_cast<const float4*>(krow + EMB + c);
            *reinterpret_cast<float4*>(&Vs[r * LDP + c]) = vv;
        }
        __syncthreads();

        // S = Q * K^T  (64x64x64, 4x4 per thread)
        float s[4][4];
#pragma unroll
        for (int i = 0; i < 4; ++i)
#pragma unroll
            for (int j = 0; j < 4; ++j) s[i][j] = 0.f;

        for (int d = 0; d < 64; ++d) {
            float4 a4 = *reinterpret_cast<const float4*>(&Qt[d * LDP + ty * 4]);
            float4 b4 = *reinterpret_cast<const float4*>(&Kt[d * LDP + tx * 4]);
            const float a[4] = {a4.x, a4.y, a4.z, a4.w};
            const float bb[4] = {b4.x, b4.y, b4.z, b4.w};
#pragma unroll
            for (int i = 0; i < 4; ++i)
#pragma unroll
                for (int j = 0; j < 4; ++j) s[i][j] += a[i] * bb[j];
        }

        // scale + causal mask (diagonal tile only)
#pragma unroll
        for (int i = 0; i < 4; ++i)
#pragma unroll
            for (int j = 0; j < 4; ++j) {
                s[i][j] *= 0.125f;
                if (kt == qt && (tx * 4 + j > ty * 4 + i)) s[i][j] = -INFINITY;
            }

        // online softmax: row stats across the 16 tx-lanes holding each row
#pragma unroll
        for (int i = 0; i < 4; ++i) {
            float rmax = fmaxf(fmaxf(s[i][0], s[i][1]), fmaxf(s[i][2], s[i][3]));
            rmax = fmaxf(rmax, __shfl_xor(rmax, 1, 16));
            rmax = fmaxf(rmax, __shfl_xor(rmax, 2, 16));
            rmax = fmaxf(rmax, __shfl_xor(rmax, 4, 16));
            rmax = fmaxf(rmax, __shfl_xor(rmax, 8, 16));
            float mnew = fmaxf(m[i], rmax);
            float alpha = __expf(m[i] - mnew);   // m=-inf first pass -> 0
            float p0 = __expf(s[i][0] - mnew);
            float p1 = __expf(s[i][1] - mnew);
            float p2 = __expf(s[i][2] - mnew);
            float p3 = __expf(s[i][3] - mnew);
            float rsum = p0 + p1 + p2 + p3;
            rsum += __shfl_xor(rsum, 1, 16);
            rsum += __shfl_xor(rsum, 2, 16);
            rsum += __shfl_xor(rsum, 4, 16);
            rsum += __shfl_xor(rsum, 8, 16);
            l[i] = l[i] * alpha + rsum;
            m[i] = mnew;
#pragma unroll
            for (int j = 0; j < 4; ++j) o[i][j] *= alpha;
            // write P transposed: Pt[k_local][q_local]
            Pt[(tx * 4 + 0) * LDP + ty * 4 + i] = p0;
            Pt[(tx * 4 + 1) * LDP + ty * 4 + i] = p1;
            Pt[(tx * 4 + 2) * LDP + ty * 4 + i] = p2;
            Pt[(tx * 4 + 3) * LDP + ty * 4 + i] = p3;
        }
        __syncthreads();

        // O += P * V  (64x64x64)
        for (int k = 0; k < 64; ++k) {
            float4 a4 = *reinterpret_cast<const float4*>(&Pt[k * LDP + ty * 4]);
            float4 b4 = *reinterpret_cast<const float4*>(&Vs[k * LDP + tx * 4]);
            const float a[4] = {a4.x, a4.y, a4.z, a4.w};
            const float bb[4] = {b4.x, b4.y, b4.z, b4.w};
#pragma unroll
            for (int i = 0; i < 4; ++i)
#pragma unroll
                for (int j = 0; j < 4; ++j) o[i][j] += a[i] * bb[j];
        }
        __syncthreads();
    }

    // epilogue: normalize and store. Row q gets head-h cols [h*64 .. h*64+63].
#pragma unroll
    for (int i = 0; i < 4; ++i) {
        const float inv = 1.f / l[i];
        const int q = qt * 64 + ty * 4 + i;
        float4 ov = make_float4(o[i][0] * inv, o[i][1] * inv,
                                o[i][2] * inv, o[i][3] * inv);
        *reinterpret_cast<float4*>(
            &y[(size_t)(b * SEQ + q) * EMB + h * HD + tx * 4]) = ov;
    }
}

// ---------------------------------------------------------------------------
extern "C" void kernel_launch(void* const* d_in, const int* in_sizes, int n_in,
                              void* d_out, int out_size, void* d_ws, size_t ws_size,
                              hipStream_t stream)
{
    const float* x     = (const float*)d_in[0];   // [B,T,E]
    const float* qkv_w = (const float*)d_in[1];   // [3E,E]
    const float* qkv_b = (const float*)d_in[2];   // [3E]
    const float* o_w   = (const float*)d_in[3];   // [E,E]
    const float* o_b   = (const float*)d_in[4];   // [E]
    float* out = (float*)d_out;                   // [B,T,E]

    float* qkv  = (float*)d_ws;                           // [M, 3E]
    float* ybuf = qkv + (size_t)M_ROWS * 3 * EMB;         // [M, E]

    // 1) QKV projection
    {
        dim3 grid(3 * EMB / 64, M_ROWS / 64);
        gemm_abt<<<grid, 256, 0, stream>>>(x, qkv_w, qkv_b, qkv,
                                           M_ROWS, 3 * EMB, EMB);
    }

    // 2) Flash attention -> ybuf [B,T,E]
    {
        dim3 grid(SEQ / 64, BATCH * NH);   // (32, 32)
        attn_flash<<<grid, 256, 0, stream>>>(qkv, ybuf);
    }

    // 3) Output projection
    {
        dim3 grid(EMB / 64, M_ROWS / 64);
        gemm_abt<<<grid, 256, 0, stream>>>(ybuf, o_w, o_b, out,
                                           M_ROWS, EMB, EMB);
    }
}

// Round 3
// 700.214 us; speedup vs baseline: 6.2325x; 1.8098x over previous
//
#include <hip/hip_runtime.h>
#include <hip/hip_bf16.h>
#include <math.h>

// Problem constants
#define BATCH 2
#define SEQ   2048
#define EMB   1024
#define NH    16
#define HD    64
#define M_ROWS (BATCH * SEQ)   // 4096

typedef __attribute__((ext_vector_type(8))) short bf16x8;
typedef __attribute__((ext_vector_type(4))) float f32x4;

// fp32 -> bf16 round-to-nearest-even, raw bits
__device__ __forceinline__ ushort f2bf(float f) {
    unsigned u = __float_as_uint(f);
    unsigned lsb = (u >> 16) & 1u;
    u += 0x7fffu + lsb;
    return (ushort)(u >> 16);
}

__device__ __forceinline__ void gload_lds16(const void* g, void* l) {
    __builtin_amdgcn_global_load_lds(
        (const __attribute__((address_space(1))) unsigned int*)g,
        (__attribute__((address_space(3))) unsigned int*)l, 16, 0, 0);
}

// ---------------------------------------------------------------------------
// fp32 -> bf16 conversion, 4 elements/thread. n multiple of 1024.
// ---------------------------------------------------------------------------
__global__ __launch_bounds__(256) void cvt_f32_bf16(
    const float* __restrict__ in, ushort* __restrict__ out, int n)
{
    int i = (blockIdx.x * 256 + threadIdx.x) * 4;
    if (i >= n) return;
    float4 v = *reinterpret_cast<const float4*>(&in[i]);
    uint2 pk;
    pk.x = (unsigned)f2bf(v.x) | ((unsigned)f2bf(v.y) << 16);
    pk.y = (unsigned)f2bf(v.z) | ((unsigned)f2bf(v.w) << 16);
    *reinterpret_cast<uint2*>(&out[i]) = pk;
}

// ---------------------------------------------------------------------------
// bf16 MFMA GEMM: C[M,N] = A[M,K] * B[N,K]^T + bias[N]
// 128x128 tile, BK=64, 256 threads = 4 waves (2x2), each wave 64x64 via
// 4x4 fragments of mfma_f32_16x16x32_bf16. global_load_lds width-16 staging.
// OUT_BF16: write bf16 (ushort) else fp32.
// ---------------------------------------------------------------------------
template <bool OUT_BF16>
__global__ __launch_bounds__(256) void gemm_mfma_abt(
    const ushort* __restrict__ A, const ushort* __restrict__ B,
    const float* __restrict__ bias, void* __restrict__ Cout,
    int M, int N, int K)
{
    __shared__ ushort Al[128 * 64];
    __shared__ ushort Bl[128 * 64];

    const int tid  = threadIdx.x;
    const int lane = tid & 63;
    const int wave = tid >> 6;     // 0..3
    const int wr   = wave >> 1;    // 0..1
    const int wc   = wave & 1;     // 0..1
    const int l15  = lane & 15;
    const int l4   = lane >> 4;    // 0..3
    const int m0   = blockIdx.y * 128;
    const int n0   = blockIdx.x * 128;

    f32x4 acc[4][4];
#pragma unroll
    for (int m = 0; m < 4; ++m)
#pragma unroll
        for (int n = 0; n < 4; ++n)
#pragma unroll
            for (int r = 0; r < 4; ++r) acc[m][n][r] = 0.f;

    for (int k0 = 0; k0 < K; k0 += 64) {
        // stage A,B tiles: 128x64 bf16 = 16KB each = 1024 x 16B chunks
#pragma unroll
        for (int it = 0; it < 4; ++it) {
            int chunk = tid + it * 256;
            int row = chunk >> 3;            // 0..127
            int kc  = (chunk & 7) * 8;       // 0..56
            gload_lds16(&A[(size_t)(m0 + row) * K + k0 + kc], &Al[chunk * 8]);
            gload_lds16(&B[(size_t)(n0 + row) * K + k0 + kc], &Bl[chunk * 8]);
        }
        __syncthreads();   // drains vmcnt, makes staged tiles visible

#pragma unroll
        for (int kk = 0; kk < 2; ++kk) {
            const int ko = kk * 32 + l4 * 8;
            bf16x8 a[4], b[4];
#pragma unroll
            for (int m = 0; m < 4; ++m)
                a[m] = *reinterpret_cast<const bf16x8*>(
                    &Al[(wr * 64 + m * 16 + l15) * 64 + ko]);
#pragma unroll
            for (int n = 0; n < 4; ++n)
                b[n] = *reinterpret_cast<const bf16x8*>(
                    &Bl[(wc * 64 + n * 16 + l15) * 64 + ko]);
#pragma unroll
            for (int m = 0; m < 4; ++m)
#pragma unroll
                for (int n = 0; n < 4; ++n)
                    acc[m][n] = __builtin_amdgcn_mfma_f32_16x16x32_bf16(
                        a[m], b[n], acc[m][n], 0, 0, 0);
        }
        __syncthreads();
    }

    // epilogue: C row = (lane>>4)*4 + reg, col = lane&15 within each 16x16
#pragma unroll
    for (int n = 0; n < 4; ++n) {
        const int col = n0 + wc * 64 + n * 16 + l15;
        const float bv = bias[col];
#pragma unroll
        for (int m = 0; m < 4; ++m) {
            const int row0 = m0 + wr * 64 + m * 16 + l4 * 4;
#pragma unroll
            for (int r = 0; r < 4; ++r) {
                float v = acc[m][n][r] + bv;
                if (OUT_BF16)
                    ((ushort*)Cout)[(size_t)(row0 + r) * N + col] = f2bf(v);
                else
                    ((float*)Cout)[(size_t)(row0 + r) * N + col] = v;
            }
        }
    }
}

// ---------------------------------------------------------------------------
// Flash attention, fp32 VALU math on bf16 inputs.
// LDS: Qt/Kt transposed [d][q] with float4-granule XOR swizzle (stride 64),
//      Vs natural [k][d] stride 68, Pt [k][q] stride 68 (float4 writes).
// ---------------------------------------------------------------------------
#define LQK 64
#define LPV 68

__device__ __forceinline__ void unpack8(uint4 raw, float* f) {
    unsigned u[4] = {raw.x, raw.y, raw.z, raw.w};
#pragma unroll
    for (int w = 0; w < 4; ++w) {
        f[w * 2 + 0] = __uint_as_float(u[w] << 16);
        f[w * 2 + 1] = __uint_as_float(u[w] & 0xffff0000u);
    }
}

__global__ __launch_bounds__(256) void attn_flash(
    const ushort* __restrict__ qkv, ushort* __restrict__ y)
{
    __shared__ float Qt[64 * LQK];
    __shared__ float Kt[64 * LQK];
    __shared__ float Vs[64 * LPV];
    __shared__ float Pt[64 * LPV];

    const int tid = threadIdx.x;
    const int tx = tid & 15;
    const int ty = tid >> 4;
    const int qt = (gridDim.x - 1) - blockIdx.x;   // long blocks first
    const int bh = blockIdx.y;
    const int b  = bh >> 4;
    const int h  = bh & 15;

    const ushort* base = qkv + (size_t)b * SEQ * 3 * EMB + h * HD;

    // Stage Q transposed + swizzled: element (d, q=r) at Qt[d*64 + ((r>>2)^(d&15))*4 + (r&3)]
#pragma unroll
    for (int it = 0; it < 2; ++it) {
        int idx = tid + it * 256;
        int r  = idx >> 3;             // q row 0..63
        int c8 = (idx & 7) * 8;        // dim group
        uint4 raw = *reinterpret_cast<const uint4*>(
            base + (size_t)(qt * 64 + r) * 3 * EMB + c8);
        float f[8]; unpack8(raw, f);
        int g = r >> 2, e = r & 3;
#pragma unroll
        for (int j = 0; j < 8; ++j) {
            int d = c8 + j;
            Qt[d * LQK + ((g ^ (d & 15)) << 2) + e] = f[j];
        }
    }

    float o[4][4];
    float m[4], l[4];
#pragma unroll
    for (int i = 0; i < 4; ++i) {
        m[i] = -INFINITY; l[i] = 0.f;
#pragma unroll
        for (int j = 0; j < 4; ++j) o[i][j] = 0.f;
    }

    for (int kt = 0; kt <= qt; ++kt) {
        // stage K (transposed+swizzled) and V (natural)
#pragma unroll
        for (int it = 0; it < 2; ++it) {
            int idx = tid + it * 256;
            int r  = idx >> 3;
            int c8 = (idx & 7) * 8;
            const ushort* krow = base + (size_t)(kt * 64 + r) * 3 * EMB + EMB;
            uint4 kraw = *reinterpret_cast<const uint4*>(krow + c8);
            float kf[8]; unpack8(kraw, kf);
            int g = r >> 2, e = r & 3;
#pragma unroll
            for (int j = 0; j < 8; ++j) {
                int d = c8 + j;
                Kt[d * LQK + ((g ^ (d & 15)) << 2) + e] = kf[j];
            }
            uint4 vraw = *reinterpret_cast<const uint4*>(krow + EMB + c8);
            float vf[8]; unpack8(vraw, vf);
            *reinterpret_cast<float4*>(&Vs[r * LPV + c8]) =
                make_float4(vf[0], vf[1], vf[2], vf[3]);
            *reinterpret_cast<float4*>(&Vs[r * LPV + c8 + 4]) =
                make_float4(vf[4], vf[5], vf[6], vf[7]);
        }
        __syncthreads();

        // S = Q K^T
        float s[4][4];
#pragma unroll
        for (int i = 0; i < 4; ++i)
#pragma unroll
            for (int j = 0; j < 4; ++j) s[i][j] = 0.f;

#pragma unroll 8
        for (int d = 0; d < 64; ++d) {
            float4 a4 = *reinterpret_cast<const float4*>(
                &Qt[d * LQK + ((ty ^ (d & 15)) << 2)]);
            float4 b4 = *reinterpret_cast<const float4*>(
                &Kt[d * LQK + ((tx ^ (d & 15)) << 2)]);
            const float a[4] = {a4.x, a4.y, a4.z, a4.w};
            const float bb[4] = {b4.x, b4.y, b4.z, b4.w};
#pragma unroll
            for (int i = 0; i < 4; ++i)
#pragma unroll
                for (int j = 0; j < 4; ++j) s[i][j] += a[i] * bb[j];
        }

#pragma unroll
        for (int i = 0; i < 4; ++i)
#pragma unroll
            for (int j = 0; j < 4; ++j) {
                s[i][j] *= 0.125f;
                if (kt == qt && (tx * 4 + j > ty * 4 + i)) s[i][j] = -INFINITY;
            }

        // online softmax (row reduce over the 16 tx lanes)
#pragma unroll
        for (int i = 0; i < 4; ++i) {
            float rmax = fmaxf(fmaxf(s[i][0], s[i][1]), fmaxf(s[i][2], s[i][3]));
            rmax = fmaxf(rmax, __shfl_xor(rmax, 1, 16));
            rmax = fmaxf(rmax, __shfl_xor(rmax, 2, 16));
            rmax = fmaxf(rmax, __shfl_xor(rmax, 4, 16));
            rmax = fmaxf(rmax, __shfl_xor(rmax, 8, 16));
            float mnew = fmaxf(m[i], rmax);
            float alpha = __expf(m[i] - mnew);
            float p0 = __expf(s[i][0] - mnew);
            float p1 = __expf(s[i][1] - mnew);
            float p2 = __expf(s[i][2] - mnew);
            float p3 = __expf(s[i][3] - mnew);
            float rsum = p0 + p1 + p2 + p3;
            rsum += __shfl_xor(rsum, 1, 16);
            rsum += __shfl_xor(rsum, 2, 16);
            rsum += __shfl_xor(rsum, 4, 16);
            rsum += __shfl_xor(rsum, 8, 16);
            l[i] = l[i] * alpha + rsum;
            m[i] = mnew;
#pragma unroll
            for (int j = 0; j < 4; ++j) o[i][j] *= alpha;
            s[i][0] = p0; s[i][1] = p1; s[i][2] = p2; s[i][3] = p3;
        }
        // Pt[k][q]: thread owns P[ty*4+0..3][tx*4+j] -> contiguous float4
#pragma unroll
        for (int j = 0; j < 4; ++j) {
            *reinterpret_cast<float4*>(&Pt[(tx * 4 + j) * LPV + ty * 4]) =
                make_float4(s[0][j], s[1][j], s[2][j], s[3][j]);
        }
        __syncthreads();

        // O += P V
#pragma unroll 8
        for (int k = 0; k < 64; ++k) {
            float4 a4 = *reinterpret_cast<const float4*>(&Pt[k * LPV + ty * 4]);
            float4 b4 = *reinterpret_cast<const float4*>(&Vs[k * LPV + tx * 4]);
            const float a[4] = {a4.x, a4.y, a4.z, a4.w};
            const float bb[4] = {b4.x, b4.y, b4.z, b4.w};
#pragma unroll
            for (int i = 0; i < 4; ++i)
#pragma unroll
                for (int j = 0; j < 4; ++j) o[i][j] += a[i] * bb[j];
        }
        __syncthreads();
    }

    // epilogue: bf16 output [M, E], head h at cols h*HD
#pragma unroll
    for (int i = 0; i < 4; ++i) {
        const float inv = 1.f / l[i];
        const int q = qt * 64 + ty * 4 + i;
        uint2 pk;
        pk.x = (unsigned)f2bf(o[i][0] * inv) | ((unsigned)f2bf(o[i][1] * inv) << 16);
        pk.y = (unsigned)f2bf(o[i][2] * inv) | ((unsigned)f2bf(o[i][3] * inv) << 16);
        *reinterpret_cast<uint2*>(
            &y[(size_t)(b * SEQ + q) * EMB + h * HD + tx * 4]) = pk;
    }
}

// ---------------------------------------------------------------------------
extern "C" void kernel_launch(void* const* d_in, const int* in_sizes, int n_in,
                              void* d_out, int out_size, void* d_ws, size_t ws_size,
                              hipStream_t stream)
{
    const float* x     = (const float*)d_in[0];   // [B,T,E]
    const float* qkv_w = (const float*)d_in[1];   // [3E,E]
    const float* qkv_b = (const float*)d_in[2];   // [3E]
    const float* o_w   = (const float*)d_in[3];   // [E,E]
    const float* o_b   = (const float*)d_in[4];   // [E]
    float* out = (float*)d_out;                   // [B,T,E] fp32

    // workspace (ushort bf16 buffers)
    ushort* xb    = (ushort*)d_ws;                         // 4096*1024
    ushort* wqkvb = xb    + (size_t)M_ROWS * EMB;          // 3072*1024
    ushort* owb   = wqkvb + (size_t)3 * EMB * EMB;         // 1024*1024
    ushort* qkvb  = owb   + (size_t)EMB * EMB;             // 4096*3072
    ushort* ybb   = qkvb  + (size_t)M_ROWS * 3 * EMB;      // 4096*1024

    // 0) fp32 -> bf16 conversions
    {
        int n1 = M_ROWS * EMB;        // x
        int n2 = 3 * EMB * EMB;       // qkv_w
        int n3 = EMB * EMB;           // o_w
        cvt_f32_bf16<<<n1 / 1024, 256, 0, stream>>>(x, xb, n1);
        cvt_f32_bf16<<<n2 / 1024, 256, 0, stream>>>(qkv_w, wqkvb, n2);
        cvt_f32_bf16<<<n3 / 1024, 256, 0, stream>>>(o_w, owb, n3);
    }

    // 1) QKV projection (bf16 out): qkv = x @ qkv_w^T + qkv_b
    {
        dim3 grid(3 * EMB / 128, M_ROWS / 128);   // (24, 32)
        gemm_mfma_abt<true><<<grid, 256, 0, stream>>>(
            xb, wqkvb, qkv_b, qkvb, M_ROWS, 3 * EMB, EMB);
    }

    // 2) Flash attention -> ybb (bf16 [M,E])
    {
        dim3 grid(SEQ / 64, BATCH * NH);          // (32, 32)
        attn_flash<<<grid, 256, 0, stream>>>(qkvb, ybb);
    }

    // 3) Output projection (fp32 out): out = ybb @ o_w^T + o_b
    {
        dim3 grid(EMB / 128, M_ROWS / 128);       // (8, 32)
        gemm_mfma_abt<false><<<grid, 256, 0, stream>>>(
            ybb, owb, o_b, out, M_ROWS, EMB, EMB);
    }
}

// Round 4
// 199.879 us; speedup vs baseline: 21.8335x; 3.5032x over previous
//
#include <hip/hip_runtime.h>
#include <hip/hip_bf16.h>
#include <math.h>

// Problem constants
#define BATCH 2
#define SEQ   2048
#define EMB   1024
#define NH    16
#define HD    64
#define M_ROWS (BATCH * SEQ)   // 4096
#define STR3E (3 * EMB)        // qkv row stride in ushorts

typedef __attribute__((ext_vector_type(8))) short bf16x8;
typedef __attribute__((ext_vector_type(4))) float f32x4;

// fp32 -> bf16 round-to-nearest-even, raw bits
__device__ __forceinline__ ushort f2bf(float f) {
    unsigned u = __float_as_uint(f);
    unsigned lsb = (u >> 16) & 1u;
    u += 0x7fffu + lsb;
    return (ushort)(u >> 16);
}

__device__ __forceinline__ void gload_lds16(const void* g, void* l) {
    __builtin_amdgcn_global_load_lds(
        (const __attribute__((address_space(1))) unsigned int*)g,
        (__attribute__((address_space(3))) unsigned int*)l, 16, 0, 0);
}

// ---------------------------------------------------------------------------
// fp32 -> bf16 conversion, 4 elements/thread.
// ---------------------------------------------------------------------------
__global__ __launch_bounds__(256) void cvt_f32_bf16(
    const float* __restrict__ in, ushort* __restrict__ out, int n)
{
    int i = (blockIdx.x * 256 + threadIdx.x) * 4;
    if (i >= n) return;
    float4 v = *reinterpret_cast<const float4*>(&in[i]);
    uint2 pk;
    pk.x = (unsigned)f2bf(v.x) | ((unsigned)f2bf(v.y) << 16);
    pk.y = (unsigned)f2bf(v.z) | ((unsigned)f2bf(v.w) << 16);
    *reinterpret_cast<uint2*>(&out[i]) = pk;
}

// ---------------------------------------------------------------------------
// bf16 MFMA GEMM: C[M,N] = A[M,K] * B[N,K]^T + bias[N]   (unchanged, verified)
// ---------------------------------------------------------------------------
template <bool OUT_BF16>
__global__ __launch_bounds__(256) void gemm_mfma_abt(
    const ushort* __restrict__ A, const ushort* __restrict__ B,
    const float* __restrict__ bias, void* __restrict__ Cout,
    int M, int N, int K)
{
    __shared__ ushort Al[128 * 64];
    __shared__ ushort Bl[128 * 64];

    const int tid  = threadIdx.x;
    const int lane = tid & 63;
    const int wave = tid >> 6;
    const int wr   = wave >> 1;
    const int wc   = wave & 1;
    const int l15  = lane & 15;
    const int l4   = lane >> 4;
    const int m0   = blockIdx.y * 128;
    const int n0   = blockIdx.x * 128;

    f32x4 acc[4][4];
#pragma unroll
    for (int m = 0; m < 4; ++m)
#pragma unroll
        for (int n = 0; n < 4; ++n)
#pragma unroll
            for (int r = 0; r < 4; ++r) acc[m][n][r] = 0.f;

    for (int k0 = 0; k0 < K; k0 += 64) {
#pragma unroll
        for (int it = 0; it < 4; ++it) {
            int chunk = tid + it * 256;
            int row = chunk >> 3;
            int kc  = (chunk & 7) * 8;
            gload_lds16(&A[(size_t)(m0 + row) * K + k0 + kc], &Al[chunk * 8]);
            gload_lds16(&B[(size_t)(n0 + row) * K + k0 + kc], &Bl[chunk * 8]);
        }
        __syncthreads();

#pragma unroll
        for (int kk = 0; kk < 2; ++kk) {
            const int ko = kk * 32 + l4 * 8;
            bf16x8 a[4], b[4];
#pragma unroll
            for (int m = 0; m < 4; ++m)
                a[m] = *reinterpret_cast<const bf16x8*>(
                    &Al[(wr * 64 + m * 16 + l15) * 64 + ko]);
#pragma unroll
            for (int n = 0; n < 4; ++n)
                b[n] = *reinterpret_cast<const bf16x8*>(
                    &Bl[(wc * 64 + n * 16 + l15) * 64 + ko]);
#pragma unroll
            for (int m = 0; m < 4; ++m)
#pragma unroll
                for (int n = 0; n < 4; ++n)
                    acc[m][n] = __builtin_amdgcn_mfma_f32_16x16x32_bf16(
                        a[m], b[n], acc[m][n], 0, 0, 0);
        }
        __syncthreads();
    }

#pragma unroll
    for (int n = 0; n < 4; ++n) {
        const int col = n0 + wc * 64 + n * 16 + l15;
        const float bv = bias[col];
#pragma unroll
        for (int m = 0; m < 4; ++m) {
            const int row0 = m0 + wr * 64 + m * 16 + l4 * 4;
#pragma unroll
            for (int r = 0; r < 4; ++r) {
                float v = acc[m][n][r] + bv;
                if (OUT_BF16)
                    ((ushort*)Cout)[(size_t)(row0 + r) * N + col] = f2bf(v);
                else
                    ((float*)Cout)[(size_t)(row0 + r) * N + col] = v;
            }
        }
    }
}

// ---------------------------------------------------------------------------
// MFMA flash attention. One block = (b,h) x 64-query tile, 4 waves, each
// wave owns 16 q rows. K/V double-buffered in LDS; Q buffer becomes P buffer.
//
// LDS layouts (all rows 64 ushorts = 128B, XOR-swizzled by ((row&7)<<4) on
// the byte-in-row):
//   QP: Q rows q (staged via pre-swizzled gload_lds), later P rows q in
//       sigma-k-order: sigma(k) = (k&15)*4 + (k>>4).
//   Kl: K rows k (pre-swizzled gload_lds).
//   Vl: rows d, cols sigma(k) (reg-transposed scatter; 2-way banks).
// MFMA fragments: A/B-frag row = lane&15, 8 contiguous k at (lane>>4)*8;
// C/D col = lane&15, row = (lane>>4)*4 + reg (verified by gemm_mfma_abt).
// ---------------------------------------------------------------------------
__global__ __launch_bounds__(256) void attn_mfma(
    const ushort* __restrict__ qkv, ushort* __restrict__ y)
{
    __shared__ alignas(16) ushort Kl[2][4096];
    __shared__ alignas(16) ushort Vl[2][4096];
    __shared__ alignas(16) ushort QP[4096];

    const int tid  = threadIdx.x;
    const int lane = tid & 63;
    const int w    = tid >> 6;     // wave 0..3
    const int l15  = lane & 15;
    const int l4   = lane >> 4;

    // XCD-chunked mapping: 4 consecutive bh per XCD (K/V set = 2MB < 4MB L2)
    const int id  = blockIdx.x;
    const int sub = id >> 3;
    const int bh  = ((id & 7) << 2) + (sub >> 5);
    const int qt  = 31 - (sub & 31);              // long blocks first
    const int b   = bh >> 4;
    const int h   = bh & 15;

    const ushort* base = qkv + (size_t)b * SEQ * STR3E + h * HD;

    // shared per-lane read offsets (ushort units) for all swizzled-row reads
    const int swz   = (l15 & 7) << 4;
    const int koff0 = ((l4 * 16) ^ swz) >> 1;
    const int koff1 = ((64 + l4 * 16) ^ swz) >> 1;
    const int sig2  = (l15 * 4 + l4) * 2;   // sigma(lane) in bytes

    // ---- prologue: stage Q, K0, V0 ----
#pragma unroll
    for (int it = 0; it < 2; ++it) {
        int i = tid + it * 256;
        int q = i >> 3;
        int d8 = ((i & 7) ^ (q & 7)) << 3;
        gload_lds16(base + (size_t)(qt * 64 + q) * STR3E + d8, &QP[i * 8]);
    }
#pragma unroll
    for (int it = 0; it < 2; ++it) {
        int i = tid + it * 256;
        int k = i >> 3;
        int d8 = ((i & 7) ^ (k & 7)) << 3;
        gload_lds16(base + (size_t)k * STR3E + EMB + d8, &Kl[0][i * 8]);
    }
    uint4 vr0 = *reinterpret_cast<const uint4*>(
        base + (size_t)lane * STR3E + 2 * EMB + w * 8);
    uint4 vr1 = *reinterpret_cast<const uint4*>(
        base + (size_t)lane * STR3E + 2 * EMB + (w + 4) * 8);
    {
        const unsigned* u0 = reinterpret_cast<const unsigned*>(&vr0);
        const unsigned* u1 = reinterpret_cast<const unsigned*>(&vr1);
#pragma unroll
        for (int j = 0; j < 8; ++j) {
            int cidx = (sig2 ^ (j << 4)) >> 1;
            ushort v0 = (j & 1) ? (ushort)(u0[j >> 1] >> 16) : (ushort)(u0[j >> 1] & 0xffffu);
            ushort v1 = (j & 1) ? (ushort)(u1[j >> 1] >> 16) : (ushort)(u1[j >> 1] & 0xffffu);
            Vl[0][(w * 8 + j) * 64 + cidx] = v0;
            Vl[0][((w + 4) * 8 + j) * 64 + cidx] = v1;
        }
    }
    __syncthreads();

    // Q fragments, kept in registers for the whole block
    const bf16x8 qf0 = *reinterpret_cast<const bf16x8*>(&QP[(w * 16 + l15) * 64 + koff0]);
    const bf16x8 qf1 = *reinterpret_cast<const bf16x8*>(&QP[(w * 16 + l15) * 64 + koff1]);

    f32x4 o[4];
    float m[4], l[4];
#pragma unroll
    for (int r = 0; r < 4; ++r) { m[r] = -3.0e38f; l[r] = 0.f; }
#pragma unroll
    for (int n = 0; n < 4; ++n)
#pragma unroll
        for (int r = 0; r < 4; ++r) o[n][r] = 0.f;

    for (int kt = 0; kt <= qt; ++kt) {
        const int p = kt & 1;

        // prefetch tile kt+1 (K async to LDS; V to regs, stored after softmax)
        if (kt < qt) {
#pragma unroll
            for (int it = 0; it < 2; ++it) {
                int i = tid + it * 256;
                int k = i >> 3;
                int d8 = ((i & 7) ^ (k & 7)) << 3;
                gload_lds16(base + (size_t)((kt + 1) * 64 + k) * STR3E + EMB + d8,
                            &Kl[p ^ 1][i * 8]);
            }
            vr0 = *reinterpret_cast<const uint4*>(
                base + (size_t)((kt + 1) * 64 + lane) * STR3E + 2 * EMB + w * 8);
            vr1 = *reinterpret_cast<const uint4*>(
                base + (size_t)((kt + 1) * 64 + lane) * STR3E + 2 * EMB + (w + 4) * 8);
        }

        // S = Q K^T  (wave's 16 q rows x 64 k cols)
        f32x4 s[4];
#pragma unroll
        for (int n = 0; n < 4; ++n) {
#pragma unroll
            for (int r = 0; r < 4; ++r) s[n][r] = 0.f;
            bf16x8 kf0 = *reinterpret_cast<const bf16x8*>(
                &Kl[p][(n * 16 + l15) * 64 + koff0]);
            bf16x8 kf1 = *reinterpret_cast<const bf16x8*>(
                &Kl[p][(n * 16 + l15) * 64 + koff1]);
            s[n] = __builtin_amdgcn_mfma_f32_16x16x32_bf16(qf0, kf0, s[n], 0, 0, 0);
            s[n] = __builtin_amdgcn_mfma_f32_16x16x32_bf16(qf1, kf1, s[n], 0, 0, 0);
        }

        // scale + causal mask (diagonal tile only)
#pragma unroll
        for (int n = 0; n < 4; ++n)
#pragma unroll
            for (int r = 0; r < 4; ++r) s[n][r] *= 0.125f;
        if (kt == qt) {
#pragma unroll
            for (int n = 0; n < 4; ++n)
#pragma unroll
                for (int r = 0; r < 4; ++r)
                    if (n * 16 + l15 > w * 16 + l4 * 4 + r) s[n][r] = -3.0e38f;
        }

        // online softmax: rows r (q = w*16 + l4*4 + r), reduce over n and l15
#pragma unroll
        for (int r = 0; r < 4; ++r) {
            float rm = fmaxf(fmaxf(s[0][r], s[1][r]), fmaxf(s[2][r], s[3][r]));
            rm = fmaxf(rm, __shfl_xor(rm, 1, 16));
            rm = fmaxf(rm, __shfl_xor(rm, 2, 16));
            rm = fmaxf(rm, __shfl_xor(rm, 4, 16));
            rm = fmaxf(rm, __shfl_xor(rm, 8, 16));
            float mn = fmaxf(m[r], rm);
            float al = __expf(m[r] - mn);
            float p0 = __expf(s[0][r] - mn);
            float p1 = __expf(s[1][r] - mn);
            float p2 = __expf(s[2][r] - mn);
            float p3 = __expf(s[3][r] - mn);
            float rs = p0 + p1 + p2 + p3;
            rs += __shfl_xor(rs, 1, 16);
            rs += __shfl_xor(rs, 2, 16);
            rs += __shfl_xor(rs, 4, 16);
            rs += __shfl_xor(rs, 8, 16);
            l[r] = l[r] * al + rs;
            m[r] = mn;
#pragma unroll
            for (int n = 0; n < 4; ++n) o[n][r] *= al;
            // P row store: k' = l15*4 + n contiguous -> one 8B write
            uint2 pk;
            pk.x = (unsigned)f2bf(p0) | ((unsigned)f2bf(p1) << 16);
            pk.y = (unsigned)f2bf(p2) | ((unsigned)f2bf(p3) << 16);
            int row = w * 16 + l4 * 4 + r;
            int pidx = row * 64 + (((l15 * 8) ^ ((row & 7) << 4)) >> 1);
            *reinterpret_cast<uint2*>(&QP[pidx]) = pk;
        }

        // V(kt+1) scatter store (loads issued at loop top have had QK^T+softmax
        // to land — T14 async-split)
        if (kt < qt) {
            const unsigned* u0 = reinterpret_cast<const unsigned*>(&vr0);
            const unsigned* u1 = reinterpret_cast<const unsigned*>(&vr1);
#pragma unroll
            for (int j = 0; j < 8; ++j) {
                int cidx = (sig2 ^ (j << 4)) >> 1;
                ushort v0 = (j & 1) ? (ushort)(u0[j >> 1] >> 16) : (ushort)(u0[j >> 1] & 0xffffu);
                ushort v1 = (j & 1) ? (ushort)(u1[j >> 1] >> 16) : (ushort)(u1[j >> 1] & 0xffffu);
                Vl[p ^ 1][(w * 8 + j) * 64 + cidx] = v0;
                Vl[p ^ 1][((w + 4) * 8 + j) * 64 + cidx] = v1;
            }
        }

        // O += P V   (k' order consistent between P and Vl)
        bf16x8 pf0 = *reinterpret_cast<const bf16x8*>(&QP[(w * 16 + l15) * 64 + koff0]);
        bf16x8 pf1 = *reinterpret_cast<const bf16x8*>(&QP[(w * 16 + l15) * 64 + koff1]);
#pragma unroll
        for (int n = 0; n < 4; ++n) {
            bf16x8 vf0 = *reinterpret_cast<const bf16x8*>(
                &Vl[p][(n * 16 + l15) * 64 + koff0]);
            bf16x8 vf1 = *reinterpret_cast<const bf16x8*>(
                &Vl[p][(n * 16 + l15) * 64 + koff1]);
            o[n] = __builtin_amdgcn_mfma_f32_16x16x32_bf16(pf0, vf0, o[n], 0, 0, 0);
            o[n] = __builtin_amdgcn_mfma_f32_16x16x32_bf16(pf1, vf1, o[n], 0, 0, 0);
        }
        __syncthreads();
    }

    // epilogue: normalize, write bf16 y[M,E] (head h at cols h*HD)
#pragma unroll
    for (int r = 0; r < 4; ++r) {
        float inv = 1.f / l[r];
        int row = qt * 64 + w * 16 + l4 * 4 + r;
#pragma unroll
        for (int n = 0; n < 4; ++n) {
            y[(size_t)(b * SEQ + row) * EMB + h * HD + n * 16 + l15] =
                f2bf(o[n][r] * inv);
        }
    }
}

// ---------------------------------------------------------------------------
extern "C" void kernel_launch(void* const* d_in, const int* in_sizes, int n_in,
                              void* d_out, int out_size, void* d_ws, size_t ws_size,
                              hipStream_t stream)
{
    const float* x     = (const float*)d_in[0];   // [B,T,E]
    const float* qkv_w = (const float*)d_in[1];   // [3E,E]
    const float* qkv_b = (const float*)d_in[2];   // [3E]
    const float* o_w   = (const float*)d_in[3];   // [E,E]
    const float* o_b   = (const float*)d_in[4];   // [E]
    float* out = (float*)d_out;                   // [B,T,E] fp32

    ushort* xb    = (ushort*)d_ws;                         // 4096*1024
    ushort* wqkvb = xb    + (size_t)M_ROWS * EMB;          // 3072*1024
    ushort* owb   = wqkvb + (size_t)3 * EMB * EMB;         // 1024*1024
    ushort* qkvb  = owb   + (size_t)EMB * EMB;             // 4096*3072
    ushort* ybb   = qkvb  + (size_t)M_ROWS * 3 * EMB;      // 4096*1024

    // 0) fp32 -> bf16
    {
        int n1 = M_ROWS * EMB;
        int n2 = 3 * EMB * EMB;
        int n3 = EMB * EMB;
        cvt_f32_bf16<<<n1 / 1024, 256, 0, stream>>>(x, xb, n1);
        cvt_f32_bf16<<<n2 / 1024, 256, 0, stream>>>(qkv_w, wqkvb, n2);
        cvt_f32_bf16<<<n3 / 1024, 256, 0, stream>>>(o_w, owb, n3);
    }

    // 1) QKV projection (bf16 out)
    {
        dim3 grid(3 * EMB / 128, M_ROWS / 128);   // (24, 32)
        gemm_mfma_abt<true><<<grid, 256, 0, stream>>>(
            xb, wqkvb, qkv_b, qkvb, M_ROWS, 3 * EMB, EMB);
    }

    // 2) MFMA flash attention -> ybb (bf16 [M,E])
    {
        attn_mfma<<<1024, 256, 0, stream>>>(qkvb, ybb);
    }

    // 3) Output projection (fp32 out)
    {
        dim3 grid(EMB / 128, M_ROWS / 128);       // (8, 32)
        gemm_mfma_abt<false><<<grid, 256, 0, stream>>>(
            ybb, owb, o_b, out, M_ROWS, EMB, EMB);
    }
}

// Round 5
// 175.533 us; speedup vs baseline: 24.8617x; 1.1387x over previous
//
#include <hip/hip_runtime.h>
#include <hip/hip_bf16.h>
#include <math.h>

// Problem constants
#define BATCH 2
#define SEQ   2048
#define EMB   1024
#define NH    16
#define HD    64
#define M_ROWS (BATCH * SEQ)   // 4096

typedef __attribute__((ext_vector_type(8))) short bf16x8;
typedef __attribute__((ext_vector_type(4))) float f32x4;

// fp32 -> bf16 round-to-nearest-even, raw bits
__device__ __forceinline__ ushort f2bf(float f) {
    unsigned u = __float_as_uint(f);
    unsigned lsb = (u >> 16) & 1u;
    u += 0x7fffu + lsb;
    return (ushort)(u >> 16);
}

__device__ __forceinline__ void gload_lds16(const void* g, void* l) {
    __builtin_amdgcn_global_load_lds(
        (const __attribute__((address_space(1))) unsigned int*)g,
        (__attribute__((address_space(3))) unsigned int*)l, 16, 0, 0);
}

// ---------------------------------------------------------------------------
// fp32 -> bf16 conversion, 4 elements/thread.
// ---------------------------------------------------------------------------
__global__ __launch_bounds__(256) void cvt_f32_bf16(
    const float* __restrict__ in, ushort* __restrict__ out, int n)
{
    int i = (blockIdx.x * 256 + threadIdx.x) * 4;
    if (i >= n) return;
    float4 v = *reinterpret_cast<const float4*>(&in[i]);
    uint2 pk;
    pk.x = (unsigned)f2bf(v.x) | ((unsigned)f2bf(v.y) << 16);
    pk.y = (unsigned)f2bf(v.z) | ((unsigned)f2bf(v.w) << 16);
    *reinterpret_cast<uint2*>(&out[i]) = pk;
}

// ---------------------------------------------------------------------------
// bf16 MFMA GEMM: C[M,N] = A[M,K] * B[N,K]^T + bias[N]
// MODE 0: fp32 output to Cout (O-projection).
// MODE 1: QKV split — cols [0,2048) bf16 to qkb (stride 2048);
//         cols [2048,3072) = V written TRANSPOSED to vtb[b*16+h][d][t].
// ---------------------------------------------------------------------------
template <int MODE>
__global__ __launch_bounds__(256) void gemm_mfma_abt(
    const ushort* __restrict__ A, const ushort* __restrict__ B,
    const float* __restrict__ bias, float* __restrict__ Cout,
    ushort* __restrict__ qkb, ushort* __restrict__ vtb,
    int M, int N, int K)
{
    __shared__ ushort Al[128 * 64];
    __shared__ ushort Bl[128 * 64];

    const int tid  = threadIdx.x;
    const int lane = tid & 63;
    const int wave = tid >> 6;
    const int wr   = wave >> 1;
    const int wc   = wave & 1;
    const int l15  = lane & 15;
    const int l4   = lane >> 4;
    const int m0   = blockIdx.y * 128;
    const int n0   = blockIdx.x * 128;

    f32x4 acc[4][4];
#pragma unroll
    for (int m = 0; m < 4; ++m)
#pragma unroll
        for (int n = 0; n < 4; ++n)
#pragma unroll
            for (int r = 0; r < 4; ++r) acc[m][n][r] = 0.f;

    for (int k0 = 0; k0 < K; k0 += 64) {
#pragma unroll
        for (int it = 0; it < 4; ++it) {
            int chunk = tid + it * 256;
            int row = chunk >> 3;
            int kc  = (chunk & 7) * 8;
            gload_lds16(&A[(size_t)(m0 + row) * K + k0 + kc], &Al[chunk * 8]);
            gload_lds16(&B[(size_t)(n0 + row) * K + k0 + kc], &Bl[chunk * 8]);
        }
        __syncthreads();

#pragma unroll
        for (int kk = 0; kk < 2; ++kk) {
            const int ko = kk * 32 + l4 * 8;
            bf16x8 a[4], b[4];
#pragma unroll
            for (int m = 0; m < 4; ++m)
                a[m] = *reinterpret_cast<const bf16x8*>(
                    &Al[(wr * 64 + m * 16 + l15) * 64 + ko]);
#pragma unroll
            for (int n = 0; n < 4; ++n)
                b[n] = *reinterpret_cast<const bf16x8*>(
                    &Bl[(wc * 64 + n * 16 + l15) * 64 + ko]);
#pragma unroll
            for (int m = 0; m < 4; ++m)
#pragma unroll
                for (int n = 0; n < 4; ++n)
                    acc[m][n] = __builtin_amdgcn_mfma_f32_16x16x32_bf16(
                        a[m], b[n], acc[m][n], 0, 0, 0);
        }
        __syncthreads();
    }

    // epilogue; C/D: col = lane&15, row = (lane>>4)*4 + reg (verified)
#pragma unroll
    for (int n = 0; n < 4; ++n) {
        const int col = n0 + wc * 64 + n * 16 + l15;
        const float bv = bias[col];
        if (MODE == 0) {
#pragma unroll
            for (int m = 0; m < 4; ++m) {
                const int row0 = m0 + wr * 64 + m * 16 + l4 * 4;
#pragma unroll
                for (int r = 0; r < 4; ++r)
                    Cout[(size_t)(row0 + r) * N + col] = acc[m][n][r] + bv;
            }
        } else if (col < 2 * EMB) {
            // Q/K part, row-major bf16, stride 2048
#pragma unroll
            for (int m = 0; m < 4; ++m) {
                const int row0 = m0 + wr * 64 + m * 16 + l4 * 4;
#pragma unroll
                for (int r = 0; r < 4; ++r)
                    qkb[(size_t)(row0 + r) * 2048 + col] = f2bf(acc[m][n][r] + bv);
            }
        } else {
            // V part, transposed: vtb[(b*16+h)*64 + d][t], t = row
            const int h = (col - 2 * EMB) >> 6;
            const int d = col & 63;
#pragma unroll
            for (int m = 0; m < 4; ++m) {
                const int row0 = m0 + wr * 64 + m * 16 + l4 * 4;
                const int bb = row0 >> 11;
                const int t  = row0 & 2047;
                uint2 pk;
                pk.x = (unsigned)f2bf(acc[m][n][0] + bv) |
                       ((unsigned)f2bf(acc[m][n][1] + bv) << 16);
                pk.y = (unsigned)f2bf(acc[m][n][2] + bv) |
                       ((unsigned)f2bf(acc[m][n][3] + bv) << 16);
                *reinterpret_cast<uint2*>(
                    &vtb[((size_t)(bb * 16 + h) * 64 + d) * 2048 + t]) = pk;
            }
        }
    }
}

// ---------------------------------------------------------------------------
// MFMA flash attention, swapped-QK softmax.
// One block = (b,h) x 64-query tile, 4 waves x 16 q rows.
// S^T = mfma(K,Q): lane holds S^T[k = n*16+l4*4+r][q = l15] -> k-reduce is
// 15 in-reg fmax + 2 shfl_xor. P stored natural-k to QP (wave-local rows);
// V staged PRE-TRANSPOSED from vtb via global_load_lds (no thread scatter).
// All LDS rows 128B, XOR-swizzled by ((row&7)<<4) bytes (pre-swizzled source).
// ---------------------------------------------------------------------------
__global__ __launch_bounds__(256) void attn_mfma(
    const ushort* __restrict__ qk, const ushort* __restrict__ vt,
    ushort* __restrict__ y)
{
    __shared__ alignas(16) ushort Kl[2][4096];
    __shared__ alignas(16) ushort Vl[2][4096];
    __shared__ alignas(16) ushort QP[4096];

    const int tid  = threadIdx.x;
    const int lane = tid & 63;
    const int w    = tid >> 6;
    const int l15  = lane & 15;
    const int l4   = lane >> 4;

    // XCD-chunked mapping: 4 consecutive bh per XCD
    const int id  = blockIdx.x;
    const int sub = id >> 3;
    const int bh  = ((id & 7) << 2) + (sub >> 5);
    const int qt  = 31 - (sub & 31);              // long blocks first
    const int b   = bh >> 4;
    const int h   = bh & 15;

    const ushort* qbase = qk + (size_t)b * SEQ * 2048 + h * HD;
    const ushort* kbase = qbase + EMB;                       // K cols at +1024
    const ushort* vbase = vt + (size_t)bh * HD * SEQ;        // [d][t]

    const int swz   = (l15 & 7) << 4;
    const int koff0 = ((l4 * 16) ^ swz) >> 1;        // ushort units
    const int koff1 = ((64 + l4 * 16) ^ swz) >> 1;

    // ---- prologue: stage Q, K0, V0 (all gload_lds, pre-swizzled source) ----
#pragma unroll
    for (int it = 0; it < 2; ++it) {
        int i = tid + it * 256;
        int r = i >> 3;
        int c = ((i & 7) ^ (r & 7)) << 3;
        gload_lds16(qbase + (size_t)(qt * 64 + r) * 2048 + c, &QP[i * 8]);
    }
#pragma unroll
    for (int it = 0; it < 2; ++it) {
        int i = tid + it * 256;
        int r = i >> 3;
        int c = ((i & 7) ^ (r & 7)) << 3;
        gload_lds16(kbase + (size_t)r * 2048 + c, &Kl[0][i * 8]);
    }
#pragma unroll
    for (int it = 0; it < 2; ++it) {
        int i = tid + it * 256;
        int d = i >> 3;
        int c = ((i & 7) ^ (d & 7)) << 3;
        gload_lds16(vbase + (size_t)d * 2048 + c, &Vl[0][i * 8]);
    }
    __syncthreads();

    const bf16x8 qf0 = *reinterpret_cast<const bf16x8*>(&QP[(w * 16 + l15) * 64 + koff0]);
    const bf16x8 qf1 = *reinterpret_cast<const bf16x8*>(&QP[(w * 16 + l15) * 64 + koff1]);

    f32x4 o[4];
#pragma unroll
    for (int n = 0; n < 4; ++n)
#pragma unroll
        for (int r = 0; r < 4; ++r) o[n][r] = 0.f;
    float m = -3.0e38f, l = 0.f;       // per-lane, row q = l15 (replicated x4)

    const float BETA = 0.18033688f;    // 0.125 * log2(e)

    for (int kt = 0; kt <= qt; ++kt) {
        const int p = kt & 1;

        // prefetch tile kt+1 (K and V^T, async to LDS)
        if (kt < qt) {
#pragma unroll
            for (int it = 0; it < 2; ++it) {
                int i = tid + it * 256;
                int r = i >> 3;
                int c = ((i & 7) ^ (r & 7)) << 3;
                gload_lds16(kbase + (size_t)((kt + 1) * 64 + r) * 2048 + c,
                            &Kl[p ^ 1][i * 8]);
            }
#pragma unroll
            for (int it = 0; it < 2; ++it) {
                int i = tid + it * 256;
                int d = i >> 3;
                int c = ((i & 7) ^ (d & 7)) << 3;
                gload_lds16(vbase + (size_t)d * 2048 + (kt + 1) * 64 + c,
                            &Vl[p ^ 1][i * 8]);
            }
        }

        // S^T = mfma(K, Q): rows k, cols q
        f32x4 s[4];
#pragma unroll
        for (int n = 0; n < 4; ++n) {
            bf16x8 kf0 = *reinterpret_cast<const bf16x8*>(
                &Kl[p][(n * 16 + l15) * 64 + koff0]);
            bf16x8 kf1 = *reinterpret_cast<const bf16x8*>(
                &Kl[p][(n * 16 + l15) * 64 + koff1]);
            f32x4 z;
#pragma unroll
            for (int r = 0; r < 4; ++r) z[r] = 0.f;
            z = __builtin_amdgcn_mfma_f32_16x16x32_bf16(kf0, qf0, z, 0, 0, 0);
            s[n] = __builtin_amdgcn_mfma_f32_16x16x32_bf16(kf1, qf1, z, 0, 0, 0);
        }

        // to log2 domain + causal mask (diagonal tile only)
        float t[4][4];
#pragma unroll
        for (int n = 0; n < 4; ++n)
#pragma unroll
            for (int r = 0; r < 4; ++r) t[n][r] = s[n][r] * BETA;
        if (kt == qt) {
#pragma unroll
            for (int n = 0; n < 4; ++n)
#pragma unroll
                for (int r = 0; r < 4; ++r)
                    if (n * 16 + l4 * 4 + r > w * 16 + l15) t[n][r] = -3.0e38f;
        }

        // row max: 15 in-reg + 2 shfl (across l4 groups)
        float tm = t[0][0];
#pragma unroll
        for (int n = 0; n < 4; ++n)
#pragma unroll
            for (int r = 0; r < 4; ++r) tm = fmaxf(tm, t[n][r]);
        tm = fmaxf(tm, __shfl_xor(tm, 16));
        tm = fmaxf(tm, __shfl_xor(tm, 32));

        // defer-max: rescale only if some row grew past THR=8 (log2 units)
        if (__any(tm > m + 8.0f)) {
            float mn = fmaxf(m, tm);
            float al = exp2f(m - mn);
            m = mn;
            l *= al;
            float a0 = __shfl(al, l4 * 4 + 0, 16);
            float a1 = __shfl(al, l4 * 4 + 1, 16);
            float a2 = __shfl(al, l4 * 4 + 2, 16);
            float a3 = __shfl(al, l4 * 4 + 3, 16);
#pragma unroll
            for (int n = 0; n < 4; ++n) {
                o[n][0] *= a0; o[n][1] *= a1; o[n][2] *= a2; o[n][3] *= a3;
            }
        }

        // p = 2^(t-m), row sum, pack P natural-k, store to wave-local QP rows
        float rs = 0.f;
#pragma unroll
        for (int n = 0; n < 4; ++n) {
            float p0 = exp2f(t[n][0] - m);
            float p1 = exp2f(t[n][1] - m);
            float p2 = exp2f(t[n][2] - m);
            float p3 = exp2f(t[n][3] - m);
            rs += (p0 + p1) + (p2 + p3);
            uint2 pk;
            pk.x = (unsigned)f2bf(p0) | ((unsigned)f2bf(p1) << 16);
            pk.y = (unsigned)f2bf(p2) | ((unsigned)f2bf(p3) << 16);
            *reinterpret_cast<uint2*>(
                &QP[(w * 16 + l15) * 64 + (((n * 32 + l4 * 8) ^ swz) >> 1)]) = pk;
        }
        rs += __shfl_xor(rs, 16);
        rs += __shfl_xor(rs, 32);
        l += rs;

        // O += P V  (P rows q, V^T rows d, both natural k)
        bf16x8 pf0 = *reinterpret_cast<const bf16x8*>(&QP[(w * 16 + l15) * 64 + koff0]);
        bf16x8 pf1 = *reinterpret_cast<const bf16x8*>(&QP[(w * 16 + l15) * 64 + koff1]);
#pragma unroll
        for (int n = 0; n < 4; ++n) {
            bf16x8 vf0 = *reinterpret_cast<const bf16x8*>(
                &Vl[p][(n * 16 + l15) * 64 + koff0]);
            bf16x8 vf1 = *reinterpret_cast<const bf16x8*>(
                &Vl[p][(n * 16 + l15) * 64 + koff1]);
            o[n] = __builtin_amdgcn_mfma_f32_16x16x32_bf16(pf0, vf0, o[n], 0, 0, 0);
            o[n] = __builtin_amdgcn_mfma_f32_16x16x32_bf16(pf1, vf1, o[n], 0, 0, 0);
        }
        __syncthreads();
    }

    // epilogue: O rows q = l4*4+r, cols d = n*16+l15; 1/l fetched via shfl
#pragma unroll
    for (int r = 0; r < 4; ++r) {
        float lr = __shfl(l, l4 * 4 + r, 16);
        float inv = 1.f / lr;
        int row = qt * 64 + w * 16 + l4 * 4 + r;
#pragma unroll
        for (int n = 0; n < 4; ++n) {
            y[(size_t)(b * SEQ + row) * EMB + h * HD + n * 16 + l15] =
                f2bf(o[n][r] * inv);
        }
    }
}

// ---------------------------------------------------------------------------
extern "C" void kernel_launch(void* const* d_in, const int* in_sizes, int n_in,
                              void* d_out, int out_size, void* d_ws, size_t ws_size,
                              hipStream_t stream)
{
    const float* x     = (const float*)d_in[0];   // [B,T,E]
    const float* qkv_w = (const float*)d_in[1];   // [3E,E]
    const float* qkv_b = (const float*)d_in[2];   // [3E]
    const float* o_w   = (const float*)d_in[3];   // [E,E]
    const float* o_b   = (const float*)d_in[4];   // [E]
    float* out = (float*)d_out;                   // [B,T,E] fp32

    // workspace (ushort units): 24M ushort = 48 MB total
    ushort* xb    = (ushort*)d_ws;                       // 4M
    ushort* wqkvb = xb    + (size_t)M_ROWS * EMB;        // 3M
    ushort* owb   = wqkvb + (size_t)3 * EMB * EMB;       // 1M
    ushort* qkb   = owb   + (size_t)EMB * EMB;           // 8M  [4096][2048]
    ushort* vtb   = qkb   + (size_t)M_ROWS * 2 * EMB;    // 4M  [32][64][2048]
    ushort* ybb   = vtb   + (size_t)32 * HD * SEQ;       // 4M  [4096][1024]

    // 0) fp32 -> bf16
    {
        int n1 = M_ROWS * EMB;
        int n2 = 3 * EMB * EMB;
        int n3 = EMB * EMB;
        cvt_f32_bf16<<<n1 / 1024, 256, 0, stream>>>(x, xb, n1);
        cvt_f32_bf16<<<n2 / 1024, 256, 0, stream>>>(qkv_w, wqkvb, n2);
        cvt_f32_bf16<<<n3 / 1024, 256, 0, stream>>>(o_w, owb, n3);
    }

    // 1) QKV projection, split output: Q/K row-major, V transposed
    {
        dim3 grid(3 * EMB / 128, M_ROWS / 128);   // (24, 32)
        gemm_mfma_abt<1><<<grid, 256, 0, stream>>>(
            xb, wqkvb, qkv_b, nullptr, qkb, vtb, M_ROWS, 3 * EMB, EMB);
    }

    // 2) MFMA flash attention -> ybb (bf16 [M,E])
    {
        attn_mfma<<<1024, 256, 0, stream>>>(qkb, vtb, ybb);
    }

    // 3) Output projection (fp32 out)
    {
        dim3 grid(EMB / 128, M_ROWS / 128);       // (8, 32)
        gemm_mfma_abt<0><<<grid, 256, 0, stream>>>(
            ybb, owb, o_b, out, nullptr, nullptr, M_ROWS, EMB, EMB);
    }
}

// Round 6
// 172.344 us; speedup vs baseline: 25.3217x; 1.0185x over previous
//
#include <hip/hip_runtime.h>
#include <hip/hip_bf16.h>
#include <math.h>

// Problem constants
#define BATCH 2
#define SEQ   2048
#define EMB   1024
#define NH    16
#define HD    64
#define M_ROWS (BATCH * SEQ)   // 4096

typedef __attribute__((ext_vector_type(8))) short bf16x8;
typedef __attribute__((ext_vector_type(4))) float f32x4;

// fp32 -> bf16 round-to-nearest-even, raw bits
__device__ __forceinline__ ushort f2bf(float f) {
    unsigned u = __float_as_uint(f);
    unsigned lsb = (u >> 16) & 1u;
    u += 0x7fffu + lsb;
    return (ushort)(u >> 16);
}

// packed f32 pair -> 2 bf16 in one u32 (RNE), single VALU op
__device__ __forceinline__ unsigned cvt_pk_bf16(float lo, float hi) {
    unsigned r;
    asm("v_cvt_pk_bf16_f32 %0, %1, %2" : "=v"(r) : "v"(lo), "v"(hi));
    return r;
}

__device__ __forceinline__ void gload_lds16(const void* g, void* l) {
    __builtin_amdgcn_global_load_lds(
        (const __attribute__((address_space(1))) unsigned int*)g,
        (__attribute__((address_space(3))) unsigned int*)l, 16, 0, 0);
}

// ---------------------------------------------------------------------------
// fused fp32 -> bf16 conversion of x, qkv_w, o_w (outputs contiguous in ws)
// ---------------------------------------------------------------------------
__global__ __launch_bounds__(256) void cvt3_f32_bf16(
    const float* __restrict__ s1, const float* __restrict__ s2,
    const float* __restrict__ s3, ushort* __restrict__ out,
    int n1, int n2)
{
    int i = (blockIdx.x * 256 + threadIdx.x) * 4;
    const float* src;
    int off;
    if (i < n1)            { src = s1; off = i; }
    else if (i < n1 + n2)  { src = s2; off = i - n1; }
    else                   { src = s3; off = i - n1 - n2; }
    float4 v = *reinterpret_cast<const float4*>(&src[off]);
    uint2 pk;
    pk.x = cvt_pk_bf16(v.x, v.y);
    pk.y = cvt_pk_bf16(v.z, v.w);
    *reinterpret_cast<uint2*>(&out[i]) = pk;
}

// ---------------------------------------------------------------------------
// bf16 MFMA GEMM: C[M,N] = A[M,K] * B[N,K]^T + bias[N]
// MODE 0: fp32 output to Cout (O-projection).
// MODE 1: QKV split — cols [0,2048) bf16 to qkb (stride 2048);
//         cols [2048,3072) = V written TRANSPOSED to vtb[b*16+h][d][t].
// ---------------------------------------------------------------------------
template <int MODE>
__global__ __launch_bounds__(256) void gemm_mfma_abt(
    const ushort* __restrict__ A, const ushort* __restrict__ B,
    const float* __restrict__ bias, float* __restrict__ Cout,
    ushort* __restrict__ qkb, ushort* __restrict__ vtb,
    int M, int N, int K)
{
    __shared__ ushort Al[128 * 64];
    __shared__ ushort Bl[128 * 64];

    const int tid  = threadIdx.x;
    const int lane = tid & 63;
    const int wave = tid >> 6;
    const int wr   = wave >> 1;
    const int wc   = wave & 1;
    const int l15  = lane & 15;
    const int l4   = lane >> 4;
    const int m0   = blockIdx.y * 128;
    const int n0   = blockIdx.x * 128;

    f32x4 acc[4][4];
#pragma unroll
    for (int m = 0; m < 4; ++m)
#pragma unroll
        for (int n = 0; n < 4; ++n)
#pragma unroll
            for (int r = 0; r < 4; ++r) acc[m][n][r] = 0.f;

    for (int k0 = 0; k0 < K; k0 += 64) {
#pragma unroll
        for (int it = 0; it < 4; ++it) {
            int chunk = tid + it * 256;
            int row = chunk >> 3;
            int kc  = (chunk & 7) * 8;
            gload_lds16(&A[(size_t)(m0 + row) * K + k0 + kc], &Al[chunk * 8]);
            gload_lds16(&B[(size_t)(n0 + row) * K + k0 + kc], &Bl[chunk * 8]);
        }
        __syncthreads();

#pragma unroll
        for (int kk = 0; kk < 2; ++kk) {
            const int ko = kk * 32 + l4 * 8;
            bf16x8 a[4], b[4];
#pragma unroll
            for (int m = 0; m < 4; ++m)
                a[m] = *reinterpret_cast<const bf16x8*>(
                    &Al[(wr * 64 + m * 16 + l15) * 64 + ko]);
#pragma unroll
            for (int n = 0; n < 4; ++n)
                b[n] = *reinterpret_cast<const bf16x8*>(
                    &Bl[(wc * 64 + n * 16 + l15) * 64 + ko]);
#pragma unroll
            for (int m = 0; m < 4; ++m)
#pragma unroll
                for (int n = 0; n < 4; ++n)
                    acc[m][n] = __builtin_amdgcn_mfma_f32_16x16x32_bf16(
                        a[m], b[n], acc[m][n], 0, 0, 0);
        }
        __syncthreads();
    }

    // epilogue; C/D: col = lane&15, row = (lane>>4)*4 + reg (verified)
#pragma unroll
    for (int n = 0; n < 4; ++n) {
        const int col = n0 + wc * 64 + n * 16 + l15;
        const float bv = bias[col];
        if (MODE == 0) {
#pragma unroll
            for (int m = 0; m < 4; ++m) {
                const int row0 = m0 + wr * 64 + m * 16 + l4 * 4;
#pragma unroll
                for (int r = 0; r < 4; ++r)
                    Cout[(size_t)(row0 + r) * N + col] = acc[m][n][r] + bv;
            }
        } else if (col < 2 * EMB) {
            // Q/K part, row-major bf16, stride 2048
#pragma unroll
            for (int m = 0; m < 4; ++m) {
                const int row0 = m0 + wr * 64 + m * 16 + l4 * 4;
#pragma unroll
                for (int r = 0; r < 4; ++r)
                    qkb[(size_t)(row0 + r) * 2048 + col] = f2bf(acc[m][n][r] + bv);
            }
        } else {
            // V part, transposed: vtb[(b*16+h)*64 + d][t], t = row
            const int h = (col - 2 * EMB) >> 6;
            const int d = col & 63;
#pragma unroll
            for (int m = 0; m < 4; ++m) {
                const int row0 = m0 + wr * 64 + m * 16 + l4 * 4;
                const int bb = row0 >> 11;
                const int t  = row0 & 2047;
                uint2 pk;
                pk.x = cvt_pk_bf16(acc[m][n][0] + bv, acc[m][n][1] + bv);
                pk.y = cvt_pk_bf16(acc[m][n][2] + bv, acc[m][n][3] + bv);
                *reinterpret_cast<uint2*>(
                    &vtb[((size_t)(bb * 16 + h) * 64 + d) * 2048 + t]) = pk;
            }
        }
    }
}

// ---------------------------------------------------------------------------
// MFMA flash attention, swapped-QK softmax, 32 q-rows per wave.
// One block = (b,h) x 64-query tile, 2 waves (128 thr), wave w owns q rows
// [w*32, w*32+32). K/V fragments read ONCE per wave, reused for both 16-q
// subblocks (register-level reuse). P per wave-local rows in QP (= Q buffer).
// All LDS rows 128B, XOR-swizzled by ((row&7)<<4) bytes (pre-swizzled source).
// ---------------------------------------------------------------------------
__global__ __launch_bounds__(128) void attn_mfma(
    const ushort* __restrict__ qk, const ushort* __restrict__ vt,
    ushort* __restrict__ y)
{
    __shared__ alignas(16) ushort Kl[2][4096];
    __shared__ alignas(16) ushort Vl[2][4096];
    __shared__ alignas(16) ushort QP[4096];

    const int tid  = threadIdx.x;
    const int lane = tid & 63;
    const int w    = tid >> 6;     // wave 0..1
    const int l15  = lane & 15;
    const int l4   = lane >> 4;

    // XCD-chunked mapping: 4 consecutive bh per XCD
    const int id  = blockIdx.x;
    const int sub = id >> 3;
    const int bh  = ((id & 7) << 2) + (sub >> 5);
    const int qt  = 31 - (sub & 31);              // long blocks first
    const int b   = bh >> 4;
    const int h   = bh & 15;

    const ushort* qbase = qk + (size_t)b * SEQ * 2048 + h * HD;
    const ushort* kbase = qbase + EMB;
    const ushort* vbase = vt + (size_t)bh * HD * SEQ;        // [d][t]

    const int swz   = (l15 & 7) << 4;
    const int koff0 = ((l4 * 16) ^ swz) >> 1;        // ushort units
    const int koff1 = ((64 + l4 * 16) ^ swz) >> 1;

    // ---- prologue: stage Q, K0, V0 ----
#pragma unroll
    for (int it = 0; it < 4; ++it) {
        int i = tid + it * 128;
        int r = i >> 3;
        int c = ((i & 7) ^ (r & 7)) << 3;
        gload_lds16(qbase + (size_t)(qt * 64 + r) * 2048 + c, &QP[i * 8]);
    }
#pragma unroll
    for (int it = 0; it < 4; ++it) {
        int i = tid + it * 128;
        int r = i >> 3;
        int c = ((i & 7) ^ (r & 7)) << 3;
        gload_lds16(kbase + (size_t)r * 2048 + c, &Kl[0][i * 8]);
    }
#pragma unroll
    for (int it = 0; it < 4; ++it) {
        int i = tid + it * 128;
        int d = i >> 3;
        int c = ((i & 7) ^ (d & 7)) << 3;
        gload_lds16(vbase + (size_t)d * 2048 + c, &Vl[0][i * 8]);
    }
    __syncthreads();

    // Q fragments for both q-subblocks (rows w*32 + qs*16 + l15)
    const int qrow0 = (w * 32 + l15) * 64;
    const int qrow1 = (w * 32 + 16 + l15) * 64;
    const bf16x8 qf00 = *reinterpret_cast<const bf16x8*>(&QP[qrow0 + koff0]);
    const bf16x8 qf01 = *reinterpret_cast<const bf16x8*>(&QP[qrow0 + koff1]);
    const bf16x8 qf10 = *reinterpret_cast<const bf16x8*>(&QP[qrow1 + koff0]);
    const bf16x8 qf11 = *reinterpret_cast<const bf16x8*>(&QP[qrow1 + koff1]);

    f32x4 o0[4], o1[4];
#pragma unroll
    for (int n = 0; n < 4; ++n)
#pragma unroll
        for (int r = 0; r < 4; ++r) { o0[n][r] = 0.f; o1[n][r] = 0.f; }
    float m0 = -3.0e38f, l0 = 0.f;   // per-lane, q = w*32 + l15
    float m1 = -3.0e38f, l1 = 0.f;   // per-lane, q = w*32 + 16 + l15

    const float BETA = 0.18033688f;  // 0.125 * log2(e)

    for (int kt = 0; kt <= qt; ++kt) {
        const int p = kt & 1;

        // prefetch tile kt+1 (K rows, V^T cols) async to LDS
        if (kt < qt) {
#pragma unroll
            for (int it = 0; it < 4; ++it) {
                int i = tid + it * 128;
                int r = i >> 3;
                int c = ((i & 7) ^ (r & 7)) << 3;
                gload_lds16(kbase + (size_t)((kt + 1) * 64 + r) * 2048 + c,
                            &Kl[p ^ 1][i * 8]);
            }
#pragma unroll
            for (int it = 0; it < 4; ++it) {
                int i = tid + it * 128;
                int d = i >> 3;
                int c = ((i & 7) ^ (d & 7)) << 3;
                gload_lds16(vbase + (size_t)d * 2048 + (kt + 1) * 64 + c,
                            &Vl[p ^ 1][i * 8]);
            }
        }

        // K fragments (shared by both q-subblocks)
        bf16x8 kf[4][2];
#pragma unroll
        for (int n = 0; n < 4; ++n) {
            kf[n][0] = *reinterpret_cast<const bf16x8*>(
                &Kl[p][(n * 16 + l15) * 64 + koff0]);
            kf[n][1] = *reinterpret_cast<const bf16x8*>(
                &Kl[p][(n * 16 + l15) * 64 + koff1]);
        }

        // S^T = mfma(K, Q): rows k = n*16+l4*4+r, cols q = l15 (per subblock)
        f32x4 s0[4], s1[4];
#pragma unroll
        for (int n = 0; n < 4; ++n) {
            f32x4 z0 = {0.f, 0.f, 0.f, 0.f};
            z0 = __builtin_amdgcn_mfma_f32_16x16x32_bf16(kf[n][0], qf00, z0, 0, 0, 0);
            s0[n] = __builtin_amdgcn_mfma_f32_16x16x32_bf16(kf[n][1], qf01, z0, 0, 0, 0);
            f32x4 z1 = {0.f, 0.f, 0.f, 0.f};
            z1 = __builtin_amdgcn_mfma_f32_16x16x32_bf16(kf[n][0], qf10, z1, 0, 0, 0);
            s1[n] = __builtin_amdgcn_mfma_f32_16x16x32_bf16(kf[n][1], qf11, z1, 0, 0, 0);
        }

        // V fragments (shared; issue early so ds latency hides under softmax)
        bf16x8 vf[4][2];
#pragma unroll
        for (int n = 0; n < 4; ++n) {
            vf[n][0] = *reinterpret_cast<const bf16x8*>(
                &Vl[p][(n * 16 + l15) * 64 + koff0]);
            vf[n][1] = *reinterpret_cast<const bf16x8*>(
                &Vl[p][(n * 16 + l15) * 64 + koff1]);
        }

        // causal mask (diagonal tile only), on raw scores
        if (kt == qt) {
#pragma unroll
            for (int n = 0; n < 4; ++n)
#pragma unroll
                for (int r = 0; r < 4; ++r) {
                    int kl = n * 16 + l4 * 4 + r;
                    if (kl > w * 32 + l15)      s0[n][r] = -3.0e38f;
                    if (kl > w * 32 + 16 + l15) s1[n][r] = -3.0e38f;
                }
        }

        // row max over k (15 in-reg + 2 shfl), then scale once
        float tm0 = s0[0][0], tm1 = s1[0][0];
#pragma unroll
        for (int n = 0; n < 4; ++n)
#pragma unroll
            for (int r = 0; r < 4; ++r) {
                tm0 = fmaxf(tm0, s0[n][r]);
                tm1 = fmaxf(tm1, s1[n][r]);
            }
        tm0 = fmaxf(tm0, __shfl_xor(tm0, 16));
        tm0 = fmaxf(tm0, __shfl_xor(tm0, 32));
        tm1 = fmaxf(tm1, __shfl_xor(tm1, 16));
        tm1 = fmaxf(tm1, __shfl_xor(tm1, 32));
        tm0 *= BETA;
        tm1 *= BETA;

        // defer-max rescale (rare, wave-uniform)
        if (__any((tm0 > m0 + 8.0f) || (tm1 > m1 + 8.0f))) {
            float mn0 = fmaxf(m0, tm0);
            float al0 = exp2f(m0 - mn0);
            m0 = mn0; l0 *= al0;
            float mn1 = fmaxf(m1, tm1);
            float al1 = exp2f(m1 - mn1);
            m1 = mn1; l1 *= al1;
            float a00 = __shfl(al0, l4 * 4 + 0, 16);
            float a01 = __shfl(al0, l4 * 4 + 1, 16);
            float a02 = __shfl(al0, l4 * 4 + 2, 16);
            float a03 = __shfl(al0, l4 * 4 + 3, 16);
            float a10 = __shfl(al1, l4 * 4 + 0, 16);
            float a11 = __shfl(al1, l4 * 4 + 1, 16);
            float a12 = __shfl(al1, l4 * 4 + 2, 16);
            float a13 = __shfl(al1, l4 * 4 + 3, 16);
#pragma unroll
            for (int n = 0; n < 4; ++n) {
                o0[n][0] *= a00; o0[n][1] *= a01; o0[n][2] *= a02; o0[n][3] *= a03;
                o1[n][0] *= a10; o1[n][1] *= a11; o1[n][2] *= a12; o1[n][3] *= a13;
            }
        }

        // p = 2^(s*BETA - m), row-sum, pack + store P (wave-local rows)
        const int prow0 = qrow0;   // (w*32 + l15) * 64
        const int prow1 = qrow1;
        float rs0 = 0.f, rs1 = 0.f;
#pragma unroll
        for (int n = 0; n < 4; ++n) {
            float pa = exp2f(fmaf(s0[n][0], BETA, -m0));
            float pb = exp2f(fmaf(s0[n][1], BETA, -m0));
            float pc = exp2f(fmaf(s0[n][2], BETA, -m0));
            float pd = exp2f(fmaf(s0[n][3], BETA, -m0));
            rs0 += (pa + pb) + (pc + pd);
            uint2 pk;
            pk.x = cvt_pk_bf16(pa, pb);
            pk.y = cvt_pk_bf16(pc, pd);
            *reinterpret_cast<uint2*>(
                &QP[prow0 + (((n * 32 + l4 * 8) ^ swz) >> 1)]) = pk;
            pa = exp2f(fmaf(s1[n][0], BETA, -m1));
            pb = exp2f(fmaf(s1[n][1], BETA, -m1));
            pc = exp2f(fmaf(s1[n][2], BETA, -m1));
            pd = exp2f(fmaf(s1[n][3], BETA, -m1));
            rs1 += (pa + pb) + (pc + pd);
            pk.x = cvt_pk_bf16(pa, pb);
            pk.y = cvt_pk_bf16(pc, pd);
            *reinterpret_cast<uint2*>(
                &QP[prow1 + (((n * 32 + l4 * 8) ^ swz) >> 1)]) = pk;
        }
        rs0 += __shfl_xor(rs0, 16);
        rs0 += __shfl_xor(rs0, 32);
        rs1 += __shfl_xor(rs1, 16);
        rs1 += __shfl_xor(rs1, 32);
        l0 += rs0;
        l1 += rs1;

        // O += P V  (P rows q, V^T rows d, natural k)
        bf16x8 pf00 = *reinterpret_cast<const bf16x8*>(&QP[prow0 + koff0]);
        bf16x8 pf01 = *reinterpret_cast<const bf16x8*>(&QP[prow0 + koff1]);
        bf16x8 pf10 = *reinterpret_cast<const bf16x8*>(&QP[prow1 + koff0]);
        bf16x8 pf11 = *reinterpret_cast<const bf16x8*>(&QP[prow1 + koff1]);
#pragma unroll
        for (int n = 0; n < 4; ++n) {
            o0[n] = __builtin_amdgcn_mfma_f32_16x16x32_bf16(pf00, vf[n][0], o0[n], 0, 0, 0);
            o0[n] = __builtin_amdgcn_mfma_f32_16x16x32_bf16(pf01, vf[n][1], o0[n], 0, 0, 0);
            o1[n] = __builtin_amdgcn_mfma_f32_16x16x32_bf16(pf10, vf[n][0], o1[n], 0, 0, 0);
            o1[n] = __builtin_amdgcn_mfma_f32_16x16x32_bf16(pf11, vf[n][1], o1[n], 0, 0, 0);
        }
        __syncthreads();
    }

    // epilogue: O rows q = qs*16 + l4*4 + r (within wave), cols d = n*16+l15
#pragma unroll
    for (int r = 0; r < 4; ++r) {
        float lr0 = __shfl(l0, l4 * 4 + r, 16);
        float lr1 = __shfl(l1, l4 * 4 + r, 16);
        float inv0 = 1.f / lr0;
        float inv1 = 1.f / lr1;
        int row0 = qt * 64 + w * 32 + l4 * 4 + r;
        int row1 = row0 + 16;
#pragma unroll
        for (int n = 0; n < 4; ++n) {
            y[(size_t)(b * SEQ + row0) * EMB + h * HD + n * 16 + l15] =
                f2bf(o0[n][r] * inv0);
            y[(size_t)(b * SEQ + row1) * EMB + h * HD + n * 16 + l15] =
                f2bf(o1[n][r] * inv1);
        }
    }
}

// ---------------------------------------------------------------------------
extern "C" void kernel_launch(void* const* d_in, const int* in_sizes, int n_in,
                              void* d_out, int out_size, void* d_ws, size_t ws_size,
                              hipStream_t stream)
{
    const float* x     = (const float*)d_in[0];   // [B,T,E]
    const float* qkv_w = (const float*)d_in[1];   // [3E,E]
    const float* qkv_b = (const float*)d_in[2];   // [3E]
    const float* o_w   = (const float*)d_in[3];   // [E,E]
    const float* o_b   = (const float*)d_in[4];   // [E]
    float* out = (float*)d_out;                   // [B,T,E] fp32

    // workspace (ushort units)
    ushort* xb    = (ushort*)d_ws;                       // 4M
    ushort* wqkvb = xb    + (size_t)M_ROWS * EMB;        // 3M
    ushort* owb   = wqkvb + (size_t)3 * EMB * EMB;       // 1M
    ushort* qkb   = owb   + (size_t)EMB * EMB;           // 8M  [4096][2048]
    ushort* vtb   = qkb   + (size_t)M_ROWS * 2 * EMB;    // 4M  [32][64][2048]
    ushort* ybb   = vtb   + (size_t)32 * HD * SEQ;       // 4M  [4096][1024]

    // 0) fused fp32 -> bf16 (x, qkv_w, o_w -> contiguous xb/wqkvb/owb)
    {
        int n1 = M_ROWS * EMB;        // 4M
        int n2 = 3 * EMB * EMB;       // 3M
        int ntot = n1 + n2 + EMB * EMB;
        cvt3_f32_bf16<<<ntot / 1024, 256, 0, stream>>>(
            x, qkv_w, o_w, xb, n1, n2);
    }

    // 1) QKV projection, split output: Q/K row-major, V transposed
    {
        dim3 grid(3 * EMB / 128, M_ROWS / 128);   // (24, 32)
        gemm_mfma_abt<1><<<grid, 256, 0, stream>>>(
            xb, wqkvb, qkv_b, nullptr, qkb, vtb, M_ROWS, 3 * EMB, EMB);
    }

    // 2) MFMA flash attention -> ybb (bf16 [M,E])
    {
        attn_mfma<<<1024, 128, 0, stream>>>(qkb, vtb, ybb);
    }

    // 3) Output projection (fp32 out)
    {
        dim3 grid(EMB / 128, M_ROWS / 128);       // (8, 32)
        gemm_mfma_abt<0><<<grid, 256, 0, stream>>>(
            ybb, owb, o_b, out, nullptr, nullptr, M_ROWS, EMB, EMB);
    }
}

// Round 7
// 152.812 us; speedup vs baseline: 28.5583x; 1.1278x over previous
//
#include <hip/hip_runtime.h>
#include <hip/hip_bf16.h>
#include <math.h>

// Problem constants
#define BATCH 2
#define SEQ   2048
#define EMB   1024
#define NH    16
#define HD    64
#define M_ROWS (BATCH * SEQ)   // 4096

typedef __attribute__((ext_vector_type(8))) short bf16x8;
typedef __attribute__((ext_vector_type(4))) float f32x4;

// fp32 -> bf16 round-to-nearest-even, raw bits
__device__ __forceinline__ ushort f2bf(float f) {
    unsigned u = __float_as_uint(f);
    unsigned lsb = (u >> 16) & 1u;
    u += 0x7fffu + lsb;
    return (ushort)(u >> 16);
}

// packed f32 pair -> 2 bf16 in one u32 (RNE), single VALU op
__device__ __forceinline__ unsigned cvt_pk_bf16(float lo, float hi) {
    unsigned r;
    asm("v_cvt_pk_bf16_f32 %0, %1, %2" : "=v"(r) : "v"(lo), "v"(hi));
    return r;
}

__device__ __forceinline__ void gload_lds16(const void* g, void* l) {
    __builtin_amdgcn_global_load_lds(
        (const __attribute__((address_space(1))) unsigned int*)g,
        (__attribute__((address_space(3))) unsigned int*)l, 16, 0, 0);
}

// ---------------------------------------------------------------------------
// fused fp32 -> bf16 conversion of x, qkv_w, o_w (outputs contiguous in ws)
// ---------------------------------------------------------------------------
__global__ __launch_bounds__(256) void cvt3_f32_bf16(
    const float* __restrict__ s1, const float* __restrict__ s2,
    const float* __restrict__ s3, ushort* __restrict__ out,
    int n1, int n2)
{
    int i = (blockIdx.x * 256 + threadIdx.x) * 4;
    const float* src;
    int off;
    if (i < n1)            { src = s1; off = i; }
    else if (i < n1 + n2)  { src = s2; off = i - n1; }
    else                   { src = s3; off = i - n1 - n2; }
    float4 v = *reinterpret_cast<const float4*>(&src[off]);
    uint2 pk;
    pk.x = cvt_pk_bf16(v.x, v.y);
    pk.y = cvt_pk_bf16(v.z, v.w);
    *reinterpret_cast<uint2*>(&out[i]) = pk;
}

// ---------------------------------------------------------------------------
// bf16 MFMA GEMM: C[M,N] = A[M,K] * B[N,K]^T + bias[N]
// MODE 0: fp32 output to Cout (O-projection).
// MODE 1: QKV split — cols [0,2048) bf16 to qkb (stride 2048);
//         cols [2048,3072) = V written TRANSPOSED to vtb[b*16+h][d][t].
// ---------------------------------------------------------------------------
template <int MODE>
__global__ __launch_bounds__(256) void gemm_mfma_abt(
    const ushort* __restrict__ A, const ushort* __restrict__ B,
    const float* __restrict__ bias, float* __restrict__ Cout,
    ushort* __restrict__ qkb, ushort* __restrict__ vtb,
    int M, int N, int K)
{
    __shared__ ushort Al[128 * 64];
    __shared__ ushort Bl[128 * 64];

    const int tid  = threadIdx.x;
    const int lane = tid & 63;
    const int wave = tid >> 6;
    const int wr   = wave >> 1;
    const int wc   = wave & 1;
    const int l15  = lane & 15;
    const int l4   = lane >> 4;
    const int m0   = blockIdx.y * 128;
    const int n0   = blockIdx.x * 128;

    f32x4 acc[4][4];
#pragma unroll
    for (int m = 0; m < 4; ++m)
#pragma unroll
        for (int n = 0; n < 4; ++n)
#pragma unroll
            for (int r = 0; r < 4; ++r) acc[m][n][r] = 0.f;

    for (int k0 = 0; k0 < K; k0 += 64) {
#pragma unroll
        for (int it = 0; it < 4; ++it) {
            int chunk = tid + it * 256;
            int row = chunk >> 3;
            int kc  = (chunk & 7) * 8;
            gload_lds16(&A[(size_t)(m0 + row) * K + k0 + kc], &Al[chunk * 8]);
            gload_lds16(&B[(size_t)(n0 + row) * K + k0 + kc], &Bl[chunk * 8]);
        }
        __syncthreads();

#pragma unroll
        for (int kk = 0; kk < 2; ++kk) {
            const int ko = kk * 32 + l4 * 8;
            bf16x8 a[4], b[4];
#pragma unroll
            for (int m = 0; m < 4; ++m)
                a[m] = *reinterpret_cast<const bf16x8*>(
                    &Al[(wr * 64 + m * 16 + l15) * 64 + ko]);
#pragma unroll
            for (int n = 0; n < 4; ++n)
                b[n] = *reinterpret_cast<const bf16x8*>(
                    &Bl[(wc * 64 + n * 16 + l15) * 64 + ko]);
            __builtin_amdgcn_s_setprio(1);
#pragma unroll
            for (int m = 0; m < 4; ++m)
#pragma unroll
                for (int n = 0; n < 4; ++n)
                    acc[m][n] = __builtin_amdgcn_mfma_f32_16x16x32_bf16(
                        a[m], b[n], acc[m][n], 0, 0, 0);
            __builtin_amdgcn_s_setprio(0);
        }
        __syncthreads();
    }

    // epilogue; C/D: col = lane&15, row = (lane>>4)*4 + reg (verified)
#pragma unroll
    for (int n = 0; n < 4; ++n) {
        const int col = n0 + wc * 64 + n * 16 + l15;
        const float bv = bias[col];
        if (MODE == 0) {
#pragma unroll
            for (int m = 0; m < 4; ++m) {
                const int row0 = m0 + wr * 64 + m * 16 + l4 * 4;
#pragma unroll
                for (int r = 0; r < 4; ++r)
                    Cout[(size_t)(row0 + r) * N + col] = acc[m][n][r] + bv;
            }
        } else if (col < 2 * EMB) {
            // Q/K part, row-major bf16, stride 2048
#pragma unroll
            for (int m = 0; m < 4; ++m) {
                const int row0 = m0 + wr * 64 + m * 16 + l4 * 4;
#pragma unroll
                for (int r = 0; r < 4; ++r)
                    qkb[(size_t)(row0 + r) * 2048 + col] = f2bf(acc[m][n][r] + bv);
            }
        } else {
            // V part, transposed: vtb[(b*16+h)*64 + d][t], t = row
            const int h = (col - 2 * EMB) >> 6;
            const int d = col & 63;
#pragma unroll
            for (int m = 0; m < 4; ++m) {
                const int row0 = m0 + wr * 64 + m * 16 + l4 * 4;
                const int bb = row0 >> 11;
                const int t  = row0 & 2047;
                uint2 pk;
                pk.x = cvt_pk_bf16(acc[m][n][0] + bv, acc[m][n][1] + bv);
                pk.y = cvt_pk_bf16(acc[m][n][2] + bv, acc[m][n][3] + bv);
                *reinterpret_cast<uint2*>(
                    &vtb[((size_t)(bb * 16 + h) * 64 + d) * 2048 + t]) = pk;
            }
        }
    }
}

// ---------------------------------------------------------------------------
// MFMA flash attention, swapped-QK softmax, 128 q-rows per block.
// 4 waves (256 thr); wave w owns q rows [w*32, w*32+32) of the q-tile, as
// two 16-row subblocks. K/V tiles (64 kv) double-buffered; staging cost
// amortized over 128 q rows. P reuses the Q LDS buffer (wave-local rows).
// All LDS rows 128B, XOR-swizzled by ((row&7)<<4) bytes (pre-swizzled source).
// ---------------------------------------------------------------------------
__global__ __launch_bounds__(256) void attn_mfma(
    const ushort* __restrict__ qk, const ushort* __restrict__ vt,
    ushort* __restrict__ y)
{
    __shared__ alignas(16) ushort Kl[2][4096];
    __shared__ alignas(16) ushort Vl[2][4096];
    __shared__ alignas(16) ushort QP[8192];     // 128 rows x 64

    const int tid  = threadIdx.x;
    const int lane = tid & 63;
    const int w    = tid >> 6;     // wave 0..3
    const int l15  = lane & 15;
    const int l4   = lane >> 4;

    // XCD-chunked mapping (512 blocks, 64 per XCD), long q-tiles first
    const int id  = blockIdx.x;
    const int sub = id >> 3;                      // 0..63
    const int bh  = ((id & 7) << 2) + (sub >> 4); // 0..31
    const int qt  = 15 - (sub & 15);              // q-tile index 0..15
    const int b   = bh >> 4;
    const int h   = bh & 15;

    const ushort* qbase = qk + (size_t)b * SEQ * 2048 + h * HD;
    const ushort* kbase = qbase + EMB;
    const ushort* vbase = vt + (size_t)bh * HD * SEQ;        // [d][t]

    const int swz   = (l15 & 7) << 4;
    const int koff0 = ((l4 * 16) ^ swz) >> 1;        // ushort units
    const int koff1 = ((64 + l4 * 16) ^ swz) >> 1;

    // ---- prologue: stage Q (128x64), K0, V0 ----
#pragma unroll
    for (int it = 0; it < 4; ++it) {
        int i = tid + it * 256;              // 0..1023
        int r = i >> 3;                      // q row 0..127
        int c = ((i & 7) ^ (r & 7)) << 3;
        gload_lds16(qbase + (size_t)(qt * 128 + r) * 2048 + c, &QP[i * 8]);
    }
#pragma unroll
    for (int it = 0; it < 2; ++it) {
        int i = tid + it * 256;
        int r = i >> 3;
        int c = ((i & 7) ^ (r & 7)) << 3;
        gload_lds16(kbase + (size_t)r * 2048 + c, &Kl[0][i * 8]);
    }
#pragma unroll
    for (int it = 0; it < 2; ++it) {
        int i = tid + it * 256;
        int d = i >> 3;
        int c = ((i & 7) ^ (d & 7)) << 3;
        gload_lds16(vbase + (size_t)d * 2048 + c, &Vl[0][i * 8]);
    }
    __syncthreads();

    // Q fragments for both q-subblocks (rows w*32 + qs*16 + l15)
    const int qrow0 = (w * 32 + l15) * 64;
    const int qrow1 = (w * 32 + 16 + l15) * 64;
    const bf16x8 qf00 = *reinterpret_cast<const bf16x8*>(&QP[qrow0 + koff0]);
    const bf16x8 qf01 = *reinterpret_cast<const bf16x8*>(&QP[qrow0 + koff1]);
    const bf16x8 qf10 = *reinterpret_cast<const bf16x8*>(&QP[qrow1 + koff0]);
    const bf16x8 qf11 = *reinterpret_cast<const bf16x8*>(&QP[qrow1 + koff1]);

    f32x4 o0[4], o1[4];
#pragma unroll
    for (int n = 0; n < 4; ++n)
#pragma unroll
        for (int r = 0; r < 4; ++r) { o0[n][r] = 0.f; o1[n][r] = 0.f; }
    float m0 = -3.0e38f, l0 = 0.f;   // per-lane, q = qt*128 + w*32 + l15
    float m1 = -3.0e38f, l1 = 0.f;   // per-lane, q = qt*128 + w*32 + 16 + l15

    const float BETA = 0.18033688f;  // 0.125 * log2(e)
    const int nkv = 2 * qt + 2;      // kv tiles of 64 covering [0, (qt+1)*128)

    for (int kk = 0; kk < nkv; ++kk) {
        const int p = kk & 1;

        // prefetch tile kk+1 (K rows, V^T cols) async to LDS
        if (kk < nkv - 1) {
#pragma unroll
            for (int it = 0; it < 2; ++it) {
                int i = tid + it * 256;
                int r = i >> 3;
                int c = ((i & 7) ^ (r & 7)) << 3;
                gload_lds16(kbase + (size_t)((kk + 1) * 64 + r) * 2048 + c,
                            &Kl[p ^ 1][i * 8]);
            }
#pragma unroll
            for (int it = 0; it < 2; ++it) {
                int i = tid + it * 256;
                int d = i >> 3;
                int c = ((i & 7) ^ (d & 7)) << 3;
                gload_lds16(vbase + (size_t)d * 2048 + (kk + 1) * 64 + c,
                            &Vl[p ^ 1][i * 8]);
            }
        }

        // K fragments (shared by both q-subblocks)
        bf16x8 kf[4][2];
#pragma unroll
        for (int n = 0; n < 4; ++n) {
            kf[n][0] = *reinterpret_cast<const bf16x8*>(
                &Kl[p][(n * 16 + l15) * 64 + koff0]);
            kf[n][1] = *reinterpret_cast<const bf16x8*>(
                &Kl[p][(n * 16 + l15) * 64 + koff1]);
        }

        // S^T = mfma(K, Q): rows k = n*16+l4*4+r, cols q = l15 (per subblock)
        f32x4 s0[4], s1[4];
        __builtin_amdgcn_s_setprio(1);
#pragma unroll
        for (int n = 0; n < 4; ++n) {
            f32x4 z0 = {0.f, 0.f, 0.f, 0.f};
            z0 = __builtin_amdgcn_mfma_f32_16x16x32_bf16(kf[n][0], qf00, z0, 0, 0, 0);
            s0[n] = __builtin_amdgcn_mfma_f32_16x16x32_bf16(kf[n][1], qf01, z0, 0, 0, 0);
            f32x4 z1 = {0.f, 0.f, 0.f, 0.f};
            z1 = __builtin_amdgcn_mfma_f32_16x16x32_bf16(kf[n][0], qf10, z1, 0, 0, 0);
            s1[n] = __builtin_amdgcn_mfma_f32_16x16x32_bf16(kf[n][1], qf11, z1, 0, 0, 0);
        }
        __builtin_amdgcn_s_setprio(0);

        // V fragments (shared; issue early so ds latency hides under softmax)
        bf16x8 vf[4][2];
#pragma unroll
        for (int n = 0; n < 4; ++n) {
            vf[n][0] = *reinterpret_cast<const bf16x8*>(
                &Vl[p][(n * 16 + l15) * 64 + koff0]);
            vf[n][1] = *reinterpret_cast<const bf16x8*>(
                &Vl[p][(n * 16 + l15) * 64 + koff1]);
        }

        // causal mask: only the last two kv tiles can violate causality
        if (kk >= nkv - 2) {
            const int q0 = qt * 128 + w * 32 + l15;
            const int q1 = q0 + 16;
#pragma unroll
            for (int n = 0; n < 4; ++n)
#pragma unroll
                for (int r = 0; r < 4; ++r) {
                    int kg = kk * 64 + n * 16 + l4 * 4 + r;
                    if (kg > q0) s0[n][r] = -3.0e38f;
                    if (kg > q1) s1[n][r] = -3.0e38f;
                }
        }

        // row max over k (15 in-reg + 2 shfl), then scale once
        float tm0 = s0[0][0], tm1 = s1[0][0];
#pragma unroll
        for (int n = 0; n < 4; ++n)
#pragma unroll
            for (int r = 0; r < 4; ++r) {
                tm0 = fmaxf(tm0, s0[n][r]);
                tm1 = fmaxf(tm1, s1[n][r]);
            }
        tm0 = fmaxf(tm0, __shfl_xor(tm0, 16));
        tm0 = fmaxf(tm0, __shfl_xor(tm0, 32));
        tm1 = fmaxf(tm1, __shfl_xor(tm1, 16));
        tm1 = fmaxf(tm1, __shfl_xor(tm1, 32));
        tm0 *= BETA;
        tm1 *= BETA;

        // defer-max rescale (rare, wave-uniform)
        if (__any((tm0 > m0 + 8.0f) || (tm1 > m1 + 8.0f))) {
            float mn0 = fmaxf(m0, tm0);
            float al0 = exp2f(m0 - mn0);
            m0 = mn0; l0 *= al0;
            float mn1 = fmaxf(m1, tm1);
            float al1 = exp2f(m1 - mn1);
            m1 = mn1; l1 *= al1;
            float a00 = __shfl(al0, l4 * 4 + 0, 16);
            float a01 = __shfl(al0, l4 * 4 + 1, 16);
            float a02 = __shfl(al0, l4 * 4 + 2, 16);
            float a03 = __shfl(al0, l4 * 4 + 3, 16);
            float a10 = __shfl(al1, l4 * 4 + 0, 16);
            float a11 = __shfl(al1, l4 * 4 + 1, 16);
            float a12 = __shfl(al1, l4 * 4 + 2, 16);
            float a13 = __shfl(al1, l4 * 4 + 3, 16);
#pragma unroll
            for (int n = 0; n < 4; ++n) {
                o0[n][0] *= a00; o0[n][1] *= a01; o0[n][2] *= a02; o0[n][3] *= a03;
                o1[n][0] *= a10; o1[n][1] *= a11; o1[n][2] *= a12; o1[n][3] *= a13;
            }
        }

        // p = 2^(s*BETA - m), row-sum, pack + store P (wave-local rows)
        float rs0 = 0.f, rs1 = 0.f;
#pragma unroll
        for (int n = 0; n < 4; ++n) {
            float pa = exp2f(fmaf(s0[n][0], BETA, -m0));
            float pb = exp2f(fmaf(s0[n][1], BETA, -m0));
            float pc = exp2f(fmaf(s0[n][2], BETA, -m0));
            float pd = exp2f(fmaf(s0[n][3], BETA, -m0));
            rs0 += (pa + pb) + (pc + pd);
            uint2 pk;
            pk.x = cvt_pk_bf16(pa, pb);
            pk.y = cvt_pk_bf16(pc, pd);
            *reinterpret_cast<uint2*>(
                &QP[qrow0 + (((n * 32 + l4 * 8) ^ swz) >> 1)]) = pk;
            pa = exp2f(fmaf(s1[n][0], BETA, -m1));
            pb = exp2f(fmaf(s1[n][1], BETA, -m1));
            pc = exp2f(fmaf(s1[n][2], BETA, -m1));
            pd = exp2f(fmaf(s1[n][3], BETA, -m1));
            rs1 += (pa + pb) + (pc + pd);
            pk.x = cvt_pk_bf16(pa, pb);
            pk.y = cvt_pk_bf16(pc, pd);
            *reinterpret_cast<uint2*>(
                &QP[qrow1 + (((n * 32 + l4 * 8) ^ swz) >> 1)]) = pk;
        }
        rs0 += __shfl_xor(rs0, 16);
        rs0 += __shfl_xor(rs0, 32);
        rs1 += __shfl_xor(rs1, 16);
        rs1 += __shfl_xor(rs1, 32);
        l0 += rs0;
        l1 += rs1;

        // O += P V  (P rows q, V^T rows d, natural k)
        bf16x8 pf00 = *reinterpret_cast<const bf16x8*>(&QP[qrow0 + koff0]);
        bf16x8 pf01 = *reinterpret_cast<const bf16x8*>(&QP[qrow0 + koff1]);
        bf16x8 pf10 = *reinterpret_cast<const bf16x8*>(&QP[qrow1 + koff0]);
        bf16x8 pf11 = *reinterpret_cast<const bf16x8*>(&QP[qrow1 + koff1]);
        __builtin_amdgcn_s_setprio(1);
#pragma unroll
        for (int n = 0; n < 4; ++n) {
            o0[n] = __builtin_amdgcn_mfma_f32_16x16x32_bf16(pf00, vf[n][0], o0[n], 0, 0, 0);
            o0[n] = __builtin_amdgcn_mfma_f32_16x16x32_bf16(pf01, vf[n][1], o0[n], 0, 0, 0);
            o1[n] = __builtin_amdgcn_mfma_f32_16x16x32_bf16(pf10, vf[n][0], o1[n], 0, 0, 0);
            o1[n] = __builtin_amdgcn_mfma_f32_16x16x32_bf16(pf11, vf[n][1], o1[n], 0, 0, 0);
        }
        __builtin_amdgcn_s_setprio(0);
        __syncthreads();
    }

    // epilogue: O rows q = qs*16 + l4*4 + r (within wave), cols d = n*16+l15
#pragma unroll
    for (int r = 0; r < 4; ++r) {
        float lr0 = __shfl(l0, l4 * 4 + r, 16);
        float lr1 = __shfl(l1, l4 * 4 + r, 16);
        float inv0 = 1.f / lr0;
        float inv1 = 1.f / lr1;
        int row0 = qt * 128 + w * 32 + l4 * 4 + r;
        int row1 = row0 + 16;
#pragma unroll
        for (int n = 0; n < 4; ++n) {
            y[(size_t)(b * SEQ + row0) * EMB + h * HD + n * 16 + l15] =
                f2bf(o0[n][r] * inv0);
            y[(size_t)(b * SEQ + row1) * EMB + h * HD + n * 16 + l15] =
                f2bf(o1[n][r] * inv1);
        }
    }
}

// ---------------------------------------------------------------------------
extern "C" void kernel_launch(void* const* d_in, const int* in_sizes, int n_in,
                              void* d_out, int out_size, void* d_ws, size_t ws_size,
                              hipStream_t stream)
{
    const float* x     = (const float*)d_in[0];   // [B,T,E]
    const float* qkv_w = (const float*)d_in[1];   // [3E,E]
    const float* qkv_b = (const float*)d_in[2];   // [3E]
    const float* o_w   = (const float*)d_in[3];   // [E,E]
    const float* o_b   = (const float*)d_in[4];   // [E]
    float* out = (float*)d_out;                   // [B,T,E] fp32

    // workspace (ushort units)
    ushort* xb    = (ushort*)d_ws;                       // 4M
    ushort* wqkvb = xb    + (size_t)M_ROWS * EMB;        // 3M
    ushort* owb   = wqkvb + (size_t)3 * EMB * EMB;       // 1M
    ushort* qkb   = owb   + (size_t)EMB * EMB;           // 8M  [4096][2048]
    ushort* vtb   = qkb   + (size_t)M_ROWS * 2 * EMB;    // 4M  [32][64][2048]
    ushort* ybb   = vtb   + (size_t)32 * HD * SEQ;       // 4M  [4096][1024]

    // 0) fused fp32 -> bf16 (x, qkv_w, o_w -> contiguous xb/wqkvb/owb)
    {
        int n1 = M_ROWS * EMB;        // 4M
        int n2 = 3 * EMB * EMB;       // 3M
        int ntot = n1 + n2 + EMB * EMB;
        cvt3_f32_bf16<<<ntot / 1024, 256, 0, stream>>>(
            x, qkv_w, o_w, xb, n1, n2);
    }

    // 1) QKV projection, split output: Q/K row-major, V transposed
    {
        dim3 grid(3 * EMB / 128, M_ROWS / 128);   // (24, 32)
        gemm_mfma_abt<1><<<grid, 256, 0, stream>>>(
            xb, wqkvb, qkv_b, nullptr, qkb, vtb, M_ROWS, 3 * EMB, EMB);
    }

    // 2) MFMA flash attention -> ybb (bf16 [M,E])
    {
        attn_mfma<<<512, 256, 0, stream>>>(qkb, vtb, ybb);
    }

    // 3) Output projection (fp32 out)
    {
        dim3 grid(EMB / 128, M_ROWS / 128);       // (8, 32)
        gemm_mfma_abt<0><<<grid, 256, 0, stream>>>(
            ybb, owb, o_b, out, nullptr, nullptr, M_ROWS, EMB, EMB);
    }
}

// Round 8
// 146.302 us; speedup vs baseline: 29.8291x; 1.0445x over previous
//
#include <hip/hip_runtime.h>
#include <hip/hip_bf16.h>
#include <math.h>

// Problem constants
#define BATCH 2
#define SEQ   2048
#define EMB   1024
#define NH    16
#define HD    64
#define M_ROWS (BATCH * SEQ)   // 4096

typedef __attribute__((ext_vector_type(8))) short bf16x8;
typedef __attribute__((ext_vector_type(4))) float f32x4;

// fp32 -> bf16 round-to-nearest-even, raw bits
__device__ __forceinline__ ushort f2bf(float f) {
    unsigned u = __float_as_uint(f);
    unsigned lsb = (u >> 16) & 1u;
    u += 0x7fffu + lsb;
    return (ushort)(u >> 16);
}

// packed f32 pair -> 2 bf16 in one u32 (RNE), single VALU op
__device__ __forceinline__ unsigned cvt_pk_bf16(float lo, float hi) {
    unsigned r;
    asm("v_cvt_pk_bf16_f32 %0, %1, %2" : "=v"(r) : "v"(lo), "v"(hi));
    return r;
}

__device__ __forceinline__ void gload_lds16(const void* g, void* l) {
    __builtin_amdgcn_global_load_lds(
        (const __attribute__((address_space(1))) unsigned int*)g,
        (__attribute__((address_space(3))) unsigned int*)l, 16, 0, 0);
}

// ---------------------------------------------------------------------------
// fused fp32 -> bf16 conversion of x, qkv_w, o_w (outputs contiguous in ws)
// ---------------------------------------------------------------------------
__global__ __launch_bounds__(256) void cvt3_f32_bf16(
    const float* __restrict__ s1, const float* __restrict__ s2,
    const float* __restrict__ s3, ushort* __restrict__ out,
    int n1, int n2)
{
    int i = (blockIdx.x * 256 + threadIdx.x) * 4;
    const float* src;
    int off;
    if (i < n1)            { src = s1; off = i; }
    else if (i < n1 + n2)  { src = s2; off = i - n1; }
    else                   { src = s3; off = i - n1 - n2; }
    float4 v = *reinterpret_cast<const float4*>(&src[off]);
    uint2 pk;
    pk.x = cvt_pk_bf16(v.x, v.y);
    pk.y = cvt_pk_bf16(v.z, v.w);
    *reinterpret_cast<uint2*>(&out[i]) = pk;
}

// ---------------------------------------------------------------------------
// bf16 MFMA GEMM: C[M,N] = A[M,K] * B[N,K]^T + bias[N]
// MODE 0: fp32 output to Cout (O-projection).
// MODE 1: QKV split — cols [0,2048) bf16 to qkb (stride 2048);
//         cols [2048,3072) = V written TRANSPOSED to vtb[b*16+h][d][t].
// ---------------------------------------------------------------------------
template <int MODE>
__global__ __launch_bounds__(256) void gemm_mfma_abt(
    const ushort* __restrict__ A, const ushort* __restrict__ B,
    const float* __restrict__ bias, float* __restrict__ Cout,
    ushort* __restrict__ qkb, ushort* __restrict__ vtb,
    int M, int N, int K)
{
    __shared__ ushort Al[128 * 64];
    __shared__ ushort Bl[128 * 64];

    const int tid  = threadIdx.x;
    const int lane = tid & 63;
    const int wave = tid >> 6;
    const int wr   = wave >> 1;
    const int wc   = wave & 1;
    const int l15  = lane & 15;
    const int l4   = lane >> 4;
    const int m0   = blockIdx.y * 128;
    const int n0   = blockIdx.x * 128;

    f32x4 acc[4][4];
#pragma unroll
    for (int m = 0; m < 4; ++m)
#pragma unroll
        for (int n = 0; n < 4; ++n)
#pragma unroll
            for (int r = 0; r < 4; ++r) acc[m][n][r] = 0.f;

    for (int k0 = 0; k0 < K; k0 += 64) {
#pragma unroll
        for (int it = 0; it < 4; ++it) {
            int chunk = tid + it * 256;
            int row = chunk >> 3;
            int kc  = (chunk & 7) * 8;
            gload_lds16(&A[(size_t)(m0 + row) * K + k0 + kc], &Al[chunk * 8]);
            gload_lds16(&B[(size_t)(n0 + row) * K + k0 + kc], &Bl[chunk * 8]);
        }
        __syncthreads();

#pragma unroll
        for (int kk = 0; kk < 2; ++kk) {
            const int ko = kk * 32 + l4 * 8;
            bf16x8 a[4], b[4];
#pragma unroll
            for (int m = 0; m < 4; ++m)
                a[m] = *reinterpret_cast<const bf16x8*>(
                    &Al[(wr * 64 + m * 16 + l15) * 64 + ko]);
#pragma unroll
            for (int n = 0; n < 4; ++n)
                b[n] = *reinterpret_cast<const bf16x8*>(
                    &Bl[(wc * 64 + n * 16 + l15) * 64 + ko]);
            __builtin_amdgcn_s_setprio(1);
#pragma unroll
            for (int m = 0; m < 4; ++m)
#pragma unroll
                for (int n = 0; n < 4; ++n)
                    acc[m][n] = __builtin_amdgcn_mfma_f32_16x16x32_bf16(
                        a[m], b[n], acc[m][n], 0, 0, 0);
            __builtin_amdgcn_s_setprio(0);
        }
        __syncthreads();
    }

    // epilogue; C/D: col = lane&15, row = (lane>>4)*4 + reg (verified)
#pragma unroll
    for (int n = 0; n < 4; ++n) {
        const int col = n0 + wc * 64 + n * 16 + l15;
        const float bv = bias[col];
        if (MODE == 0) {
#pragma unroll
            for (int m = 0; m < 4; ++m) {
                const int row0 = m0 + wr * 64 + m * 16 + l4 * 4;
#pragma unroll
                for (int r = 0; r < 4; ++r)
                    Cout[(size_t)(row0 + r) * N + col] = acc[m][n][r] + bv;
            }
        } else if (col < 2 * EMB) {
            // Q/K part, row-major bf16, stride 2048
#pragma unroll
            for (int m = 0; m < 4; ++m) {
                const int row0 = m0 + wr * 64 + m * 16 + l4 * 4;
#pragma unroll
                for (int r = 0; r < 4; ++r)
                    qkb[(size_t)(row0 + r) * 2048 + col] = f2bf(acc[m][n][r] + bv);
            }
        } else {
            // V part, transposed: vtb[(b*16+h)*64 + d][t], t = row
            const int h = (col - 2 * EMB) >> 6;
            const int d = col & 63;
#pragma unroll
            for (int m = 0; m < 4; ++m) {
                const int row0 = m0 + wr * 64 + m * 16 + l4 * 4;
                const int bb = row0 >> 11;
                const int t  = row0 & 2047;
                uint2 pk;
                pk.x = cvt_pk_bf16(acc[m][n][0] + bv, acc[m][n][1] + bv);
                pk.y = cvt_pk_bf16(acc[m][n][2] + bv, acc[m][n][3] + bv);
                *reinterpret_cast<uint2*>(
                    &vtb[((size_t)(bb * 16 + h) * 64 + d) * 2048 + t]) = pk;
            }
        }
    }
}

// ---------------------------------------------------------------------------
// MFMA flash attention, swapped-QK softmax, 128 q-rows per block.
// 4 waves (256 thr); wave w owns q rows [w*32, w*32+32), two 16-row
// subblocks. K/V double-buffered. Critical-path-lean softmax:
//  - per-lane partial-max tree + __any ballot (no shuffles common path)
//  - l accumulated via MFMA with a ones B-fragment (layout == o) — no sum
//    chain, no epilogue shuffles.
// All LDS rows 128B, XOR-swizzled by ((row&7)<<4) bytes (pre-swizzled source).
// ---------------------------------------------------------------------------
__global__ __launch_bounds__(256) void attn_mfma(
    const ushort* __restrict__ qk, const ushort* __restrict__ vt,
    ushort* __restrict__ y)
{
    __shared__ alignas(16) ushort Kl[2][4096];
    __shared__ alignas(16) ushort Vl[2][4096];
    __shared__ alignas(16) ushort QP[8192];     // 128 rows x 64

    const int tid  = threadIdx.x;
    const int lane = tid & 63;
    const int w    = tid >> 6;     // wave 0..3
    const int l15  = lane & 15;
    const int l4   = lane >> 4;

    // XCD-chunked mapping (512 blocks, 64 per XCD), long q-tiles first
    const int id  = blockIdx.x;
    const int sub = id >> 3;                      // 0..63
    const int bh  = ((id & 7) << 2) + (sub >> 4); // 0..31
    const int qt  = 15 - (sub & 15);              // q-tile index 0..15
    const int b   = bh >> 4;
    const int h   = bh & 15;

    const ushort* qbase = qk + (size_t)b * SEQ * 2048 + h * HD;
    const ushort* kbase = qbase + EMB;
    const ushort* vbase = vt + (size_t)bh * HD * SEQ;        // [d][t]

    const int swz   = (l15 & 7) << 4;
    const int koff0 = ((l4 * 16) ^ swz) >> 1;        // ushort units
    const int koff1 = ((64 + l4 * 16) ^ swz) >> 1;

    // ---- prologue: stage Q (128x64), K0, V0 ----
#pragma unroll
    for (int it = 0; it < 4; ++it) {
        int i = tid + it * 256;              // 0..1023
        int r = i >> 3;                      // q row 0..127
        int c = ((i & 7) ^ (r & 7)) << 3;
        gload_lds16(qbase + (size_t)(qt * 128 + r) * 2048 + c, &QP[i * 8]);
    }
#pragma unroll
    for (int it = 0; it < 2; ++it) {
        int i = tid + it * 256;
        int r = i >> 3;
        int c = ((i & 7) ^ (r & 7)) << 3;
        gload_lds16(kbase + (size_t)r * 2048 + c, &Kl[0][i * 8]);
    }
#pragma unroll
    for (int it = 0; it < 2; ++it) {
        int i = tid + it * 256;
        int d = i >> 3;
        int c = ((i & 7) ^ (d & 7)) << 3;
        gload_lds16(vbase + (size_t)d * 2048 + c, &Vl[0][i * 8]);
    }
    __syncthreads();

    // Q fragments for both q-subblocks (rows w*32 + qs*16 + l15)
    const int qrow0 = (w * 32 + l15) * 64;
    const int qrow1 = (w * 32 + 16 + l15) * 64;
    const bf16x8 qf00 = *reinterpret_cast<const bf16x8*>(&QP[qrow0 + koff0]);
    const bf16x8 qf01 = *reinterpret_cast<const bf16x8*>(&QP[qrow0 + koff1]);
    const bf16x8 qf10 = *reinterpret_cast<const bf16x8*>(&QP[qrow1 + koff0]);
    const bf16x8 qf11 = *reinterpret_cast<const bf16x8*>(&QP[qrow1 + koff1]);

    const short OBF = (short)0x3F80;   // 1.0 bf16
    const bf16x8 ones = {OBF, OBF, OBF, OBF, OBF, OBF, OBF, OBF};

    f32x4 o0[4], o1[4];
#pragma unroll
    for (int n = 0; n < 4; ++n)
#pragma unroll
        for (int r = 0; r < 4; ++r) { o0[n][r] = 0.f; o1[n][r] = 0.f; }
    f32x4 lacc0 = {0.f, 0.f, 0.f, 0.f};   // row-sums of P, layout == o rows
    f32x4 lacc1 = {0.f, 0.f, 0.f, 0.f};
    float m0 = -3.0e38f;   // per-lane running max (log2 units), q = .. + l15
    float m1 = -3.0e38f;

    const float BETA = 0.18033688f;  // 0.125 * log2(e)
    const int nkv = 2 * qt + 2;      // kv tiles of 64 covering [0, (qt+1)*128)

    for (int kk = 0; kk < nkv; ++kk) {
        const int p = kk & 1;

        // prefetch tile kk+1 (K rows, V^T cols) async to LDS
        if (kk < nkv - 1) {
#pragma unroll
            for (int it = 0; it < 2; ++it) {
                int i = tid + it * 256;
                int r = i >> 3;
                int c = ((i & 7) ^ (r & 7)) << 3;
                gload_lds16(kbase + (size_t)((kk + 1) * 64 + r) * 2048 + c,
                            &Kl[p ^ 1][i * 8]);
            }
#pragma unroll
            for (int it = 0; it < 2; ++it) {
                int i = tid + it * 256;
                int d = i >> 3;
                int c = ((i & 7) ^ (d & 7)) << 3;
                gload_lds16(vbase + (size_t)d * 2048 + (kk + 1) * 64 + c,
                            &Vl[p ^ 1][i * 8]);
            }
        }

        // K fragments (shared by both q-subblocks)
        bf16x8 kf[4][2];
#pragma unroll
        for (int n = 0; n < 4; ++n) {
            kf[n][0] = *reinterpret_cast<const bf16x8*>(
                &Kl[p][(n * 16 + l15) * 64 + koff0]);
            kf[n][1] = *reinterpret_cast<const bf16x8*>(
                &Kl[p][(n * 16 + l15) * 64 + koff1]);
        }

        // S^T = mfma(K, Q): rows k = n*16+l4*4+r, cols q = l15 (per subblock)
        f32x4 s0[4], s1[4];
        __builtin_amdgcn_s_setprio(1);
#pragma unroll
        for (int n = 0; n < 4; ++n) {
            f32x4 z0 = {0.f, 0.f, 0.f, 0.f};
            z0 = __builtin_amdgcn_mfma_f32_16x16x32_bf16(kf[n][0], qf00, z0, 0, 0, 0);
            s0[n] = __builtin_amdgcn_mfma_f32_16x16x32_bf16(kf[n][1], qf01, z0, 0, 0, 0);
            f32x4 z1 = {0.f, 0.f, 0.f, 0.f};
            z1 = __builtin_amdgcn_mfma_f32_16x16x32_bf16(kf[n][0], qf10, z1, 0, 0, 0);
            s1[n] = __builtin_amdgcn_mfma_f32_16x16x32_bf16(kf[n][1], qf11, z1, 0, 0, 0);
        }
        __builtin_amdgcn_s_setprio(0);

        // V fragments (shared; issue early so ds latency hides under softmax)
        bf16x8 vf[4][2];
#pragma unroll
        for (int n = 0; n < 4; ++n) {
            vf[n][0] = *reinterpret_cast<const bf16x8*>(
                &Vl[p][(n * 16 + l15) * 64 + koff0]);
            vf[n][1] = *reinterpret_cast<const bf16x8*>(
                &Vl[p][(n * 16 + l15) * 64 + koff1]);
        }

        // causal mask: only the last two kv tiles can violate causality
        if (kk >= nkv - 2) {
            const int q0 = qt * 128 + w * 32 + l15;
            const int q1 = q0 + 16;
#pragma unroll
            for (int n = 0; n < 4; ++n)
#pragma unroll
                for (int r = 0; r < 4; ++r) {
                    int kg = kk * 64 + n * 16 + l4 * 4 + r;
                    if (kg > q0) s0[n][r] = -3.0e38f;
                    if (kg > q1) s1[n][r] = -3.0e38f;
                }
        }

        // per-lane partial max (tree, depth 4) -> conservative rescale check
        float pm0, pm1;
        {
            float a0 = fmaxf(fmaxf(s0[0][0], s0[0][1]), fmaxf(s0[0][2], s0[0][3]));
            float a1 = fmaxf(fmaxf(s0[1][0], s0[1][1]), fmaxf(s0[1][2], s0[1][3]));
            float a2 = fmaxf(fmaxf(s0[2][0], s0[2][1]), fmaxf(s0[2][2], s0[2][3]));
            float a3 = fmaxf(fmaxf(s0[3][0], s0[3][1]), fmaxf(s0[3][2], s0[3][3]));
            pm0 = fmaxf(fmaxf(a0, a1), fmaxf(a2, a3)) * BETA;
            float b0 = fmaxf(fmaxf(s1[0][0], s1[0][1]), fmaxf(s1[0][2], s1[0][3]));
            float b1 = fmaxf(fmaxf(s1[1][0], s1[1][1]), fmaxf(s1[1][2], s1[1][3]));
            float b2 = fmaxf(fmaxf(s1[2][0], s1[2][1]), fmaxf(s1[2][2], s1[2][3]));
            float b3 = fmaxf(fmaxf(s1[3][0], s1[3][1]), fmaxf(s1[3][2], s1[3][3]));
            pm1 = fmaxf(fmaxf(b0, b1), fmaxf(b2, b3)) * BETA;
        }

        // defer-max rescale (rare, wave-uniform). Ballot covers every (k,q)
        // value of both subblocks, so the bound p <= 2^8 is exact.
        if (__any((pm0 > m0 + 8.0f) || (pm1 > m1 + 8.0f))) {
            float tm0 = fmaxf(pm0, __shfl_xor(pm0, 16));
            tm0 = fmaxf(tm0, __shfl_xor(tm0, 32));
            float tm1 = fmaxf(pm1, __shfl_xor(pm1, 16));
            tm1 = fmaxf(tm1, __shfl_xor(tm1, 32));
            float mn0 = fmaxf(m0, tm0);
            float al0 = exp2f(m0 - mn0);
            m0 = mn0;
            float mn1 = fmaxf(m1, tm1);
            float al1 = exp2f(m1 - mn1);
            m1 = mn1;
            float a00 = __shfl(al0, l4 * 4 + 0, 16);
            float a01 = __shfl(al0, l4 * 4 + 1, 16);
            float a02 = __shfl(al0, l4 * 4 + 2, 16);
            float a03 = __shfl(al0, l4 * 4 + 3, 16);
            float a10 = __shfl(al1, l4 * 4 + 0, 16);
            float a11 = __shfl(al1, l4 * 4 + 1, 16);
            float a12 = __shfl(al1, l4 * 4 + 2, 16);
            float a13 = __shfl(al1, l4 * 4 + 3, 16);
            lacc0[0] *= a00; lacc0[1] *= a01; lacc0[2] *= a02; lacc0[3] *= a03;
            lacc1[0] *= a10; lacc1[1] *= a11; lacc1[2] *= a12; lacc1[3] *= a13;
#pragma unroll
            for (int n = 0; n < 4; ++n) {
                o0[n][0] *= a00; o0[n][1] *= a01; o0[n][2] *= a02; o0[n][3] *= a03;
                o1[n][0] *= a10; o1[n][1] *= a11; o1[n][2] *= a12; o1[n][3] *= a13;
            }
        }

        // p = 2^(s*BETA - m), pack + store P (wave-local rows; no sum chain)
#pragma unroll
        for (int n = 0; n < 4; ++n) {
            float pa = exp2f(fmaf(s0[n][0], BETA, -m0));
            float pb = exp2f(fmaf(s0[n][1], BETA, -m0));
            float pc = exp2f(fmaf(s0[n][2], BETA, -m0));
            float pd = exp2f(fmaf(s0[n][3], BETA, -m0));
            uint2 pk;
            pk.x = cvt_pk_bf16(pa, pb);
            pk.y = cvt_pk_bf16(pc, pd);
            *reinterpret_cast<uint2*>(
                &QP[qrow0 + (((n * 32 + l4 * 8) ^ swz) >> 1)]) = pk;
            pa = exp2f(fmaf(s1[n][0], BETA, -m1));
            pb = exp2f(fmaf(s1[n][1], BETA, -m1));
            pc = exp2f(fmaf(s1[n][2], BETA, -m1));
            pd = exp2f(fmaf(s1[n][3], BETA, -m1));
            pk.x = cvt_pk_bf16(pa, pb);
            pk.y = cvt_pk_bf16(pc, pd);
            *reinterpret_cast<uint2*>(
                &QP[qrow1 + (((n * 32 + l4 * 8) ^ swz) >> 1)]) = pk;
        }

        // O += P V, l += P·1  (P rows q, V^T rows d, natural k)
        bf16x8 pf00 = *reinterpret_cast<const bf16x8*>(&QP[qrow0 + koff0]);
        bf16x8 pf01 = *reinterpret_cast<const bf16x8*>(&QP[qrow0 + koff1]);
        bf16x8 pf10 = *reinterpret_cast<const bf16x8*>(&QP[qrow1 + koff0]);
        bf16x8 pf11 = *reinterpret_cast<const bf16x8*>(&QP[qrow1 + koff1]);
        __builtin_amdgcn_s_setprio(1);
        lacc0 = __builtin_amdgcn_mfma_f32_16x16x32_bf16(pf00, ones, lacc0, 0, 0, 0);
        lacc0 = __builtin_amdgcn_mfma_f32_16x16x32_bf16(pf01, ones, lacc0, 0, 0, 0);
        lacc1 = __builtin_amdgcn_mfma_f32_16x16x32_bf16(pf10, ones, lacc1, 0, 0, 0);
        lacc1 = __builtin_amdgcn_mfma_f32_16x16x32_bf16(pf11, ones, lacc1, 0, 0, 0);
#pragma unroll
        for (int n = 0; n < 4; ++n) {
            o0[n] = __builtin_amdgcn_mfma_f32_16x16x32_bf16(pf00, vf[n][0], o0[n], 0, 0, 0);
            o0[n] = __builtin_amdgcn_mfma_f32_16x16x32_bf16(pf01, vf[n][1], o0[n], 0, 0, 0);
            o1[n] = __builtin_amdgcn_mfma_f32_16x16x32_bf16(pf10, vf[n][0], o1[n], 0, 0, 0);
            o1[n] = __builtin_amdgcn_mfma_f32_16x16x32_bf16(pf11, vf[n][1], o1[n], 0, 0, 0);
        }
        __builtin_amdgcn_s_setprio(0);
        __syncthreads();
    }

    // epilogue: O rows q = qs*16 + l4*4 + r (within wave), cols d = n*16+l15
    // lacc[r] already sits in the o-row layout — no shuffles needed.
#pragma unroll
    for (int r = 0; r < 4; ++r) {
        float inv0 = 1.f / lacc0[r];
        float inv1 = 1.f / lacc1[r];
        int row0 = qt * 128 + w * 32 + l4 * 4 + r;
        int row1 = row0 + 16;
#pragma unroll
        for (int n = 0; n < 4; ++n) {
            y[(size_t)(b * SEQ + row0) * EMB + h * HD + n * 16 + l15] =
                f2bf(o0[n][r] * inv0);
            y[(size_t)(b * SEQ + row1) * EMB + h * HD + n * 16 + l15] =
                f2bf(o1[n][r] * inv1);
        }
    }
}

// ---------------------------------------------------------------------------
extern "C" void kernel_launch(void* const* d_in, const int* in_sizes, int n_in,
                              void* d_out, int out_size, void* d_ws, size_t ws_size,
                              hipStream_t stream)
{
    const float* x     = (const float*)d_in[0];   // [B,T,E]
    const float* qkv_w = (const float*)d_in[1];   // [3E,E]
    const float* qkv_b = (const float*)d_in[2];   // [3E]
    const float* o_w   = (const float*)d_in[3];   // [E,E]
    const float* o_b   = (const float*)d_in[4];   // [E]
    float* out = (float*)d_out;                   // [B,T,E] fp32

    // workspace (ushort units)
    ushort* xb    = (ushort*)d_ws;                       // 4M
    ushort* wqkvb = xb    + (size_t)M_ROWS * EMB;        // 3M
    ushort* owb   = wqkvb + (size_t)3 * EMB * EMB;       // 1M
    ushort* qkb   = owb   + (size_t)EMB * EMB;           // 8M  [4096][2048]
    ushort* vtb   = qkb   + (size_t)M_ROWS * 2 * EMB;    // 4M  [32][64][2048]
    ushort* ybb   = vtb   + (size_t)32 * HD * SEQ;       // 4M  [4096][1024]

    // 0) fused fp32 -> bf16 (x, qkv_w, o_w -> contiguous xb/wqkvb/owb)
    {
        int n1 = M_ROWS * EMB;        // 4M
        int n2 = 3 * EMB * EMB;       // 3M
        int ntot = n1 + n2 + EMB * EMB;
        cvt3_f32_bf16<<<ntot / 1024, 256, 0, stream>>>(
            x, qkv_w, o_w, xb, n1, n2);
    }

    // 1) QKV projection, split output: Q/K row-major, V transposed
    {
        dim3 grid(3 * EMB / 128, M_ROWS / 128);   // (24, 32)
        gemm_mfma_abt<1><<<grid, 256, 0, stream>>>(
            xb, wqkvb, qkv_b, nullptr, qkb, vtb, M_ROWS, 3 * EMB, EMB);
    }

    // 2) MFMA flash attention -> ybb (bf16 [M,E])
    {
        attn_mfma<<<512, 256, 0, stream>>>(qkb, vtb, ybb);
    }

    // 3) Output projection (fp32 out)
    {
        dim3 grid(EMB / 128, M_ROWS / 128);       // (8, 32)
        gemm_mfma_abt<0><<<grid, 256, 0, stream>>>(
            ybb, owb, o_b, out, nullptr, nullptr, M_ROWS, EMB, EMB);
    }
}

// Round 9
// 134.477 us; speedup vs baseline: 32.4521x; 1.0879x over previous
//
#include <hip/hip_runtime.h>
#include <hip/hip_bf16.h>
#include <math.h>

// Problem constants
#define BATCH 2
#define SEQ   2048
#define EMB   1024
#define NH    16
#define HD    64
#define M_ROWS (BATCH * SEQ)   // 4096

typedef __attribute__((ext_vector_type(8))) short bf16x8;
typedef __attribute__((ext_vector_type(4))) float f32x4;

// fp32 -> bf16 round-to-nearest-even, raw bits
__device__ __forceinline__ ushort f2bf(float f) {
    unsigned u = __float_as_uint(f);
    unsigned lsb = (u >> 16) & 1u;
    u += 0x7fffu + lsb;
    return (ushort)(u >> 16);
}

// packed f32 pair -> 2 bf16 in one u32 (RNE), single VALU op
__device__ __forceinline__ unsigned cvt_pk_bf16(float lo, float hi) {
    unsigned r;
    asm("v_cvt_pk_bf16_f32 %0, %1, %2" : "=v"(r) : "v"(lo), "v"(hi));
    return r;
}

__device__ __forceinline__ void gload_lds16(const void* g, void* l) {
    __builtin_amdgcn_global_load_lds(
        (const __attribute__((address_space(1))) unsigned int*)g,
        (__attribute__((address_space(3))) unsigned int*)l, 16, 0, 0);
}

// ---------------------------------------------------------------------------
// fused fp32 -> bf16 conversion of x, qkv_w, o_w (outputs contiguous in ws)
// ---------------------------------------------------------------------------
__global__ __launch_bounds__(256) void cvt3_f32_bf16(
    const float* __restrict__ s1, const float* __restrict__ s2,
    const float* __restrict__ s3, ushort* __restrict__ out,
    int n1, int n2)
{
    int i = (blockIdx.x * 256 + threadIdx.x) * 4;
    const float* src;
    int off;
    if (i < n1)            { src = s1; off = i; }
    else if (i < n1 + n2)  { src = s2; off = i - n1; }
    else                   { src = s3; off = i - n1 - n2; }
    float4 v = *reinterpret_cast<const float4*>(&src[off]);
    uint2 pk;
    pk.x = cvt_pk_bf16(v.x, v.y);
    pk.y = cvt_pk_bf16(v.z, v.w);
    *reinterpret_cast<uint2*>(&out[i]) = pk;
}

// ---------------------------------------------------------------------------
// bf16 MFMA GEMM: C[M,N] = A[M,K] * B[N,K]^T + bias[N]
// MODE 0: fp32 output to Cout (O-projection).
// MODE 1: QKV split — cols [0,2048) bf16 to qkb (stride 2048);
//         cols [2048,3072) = V written TRANSPOSED to vtb[b*16+h][d][t].
// ---------------------------------------------------------------------------
template <int MODE>
__global__ __launch_bounds__(256) void gemm_mfma_abt(
    const ushort* __restrict__ A, const ushort* __restrict__ B,
    const float* __restrict__ bias, float* __restrict__ Cout,
    ushort* __restrict__ qkb, ushort* __restrict__ vtb,
    int M, int N, int K)
{
    __shared__ ushort Al[128 * 64];
    __shared__ ushort Bl[128 * 64];

    const int tid  = threadIdx.x;
    const int lane = tid & 63;
    const int wave = tid >> 6;
    const int wr   = wave >> 1;
    const int wc   = wave & 1;
    const int l15  = lane & 15;
    const int l4   = lane >> 4;
    const int m0   = blockIdx.y * 128;
    const int n0   = blockIdx.x * 128;

    f32x4 acc[4][4];
#pragma unroll
    for (int m = 0; m < 4; ++m)
#pragma unroll
        for (int n = 0; n < 4; ++n)
#pragma unroll
            for (int r = 0; r < 4; ++r) acc[m][n][r] = 0.f;

    for (int k0 = 0; k0 < K; k0 += 64) {
#pragma unroll
        for (int it = 0; it < 4; ++it) {
            int chunk = tid + it * 256;
            int row = chunk >> 3;
            int kc  = (chunk & 7) * 8;
            gload_lds16(&A[(size_t)(m0 + row) * K + k0 + kc], &Al[chunk * 8]);
            gload_lds16(&B[(size_t)(n0 + row) * K + k0 + kc], &Bl[chunk * 8]);
        }
        __syncthreads();

#pragma unroll
        for (int kk = 0; kk < 2; ++kk) {
            const int ko = kk * 32 + l4 * 8;
            bf16x8 a[4], b[4];
#pragma unroll
            for (int m = 0; m < 4; ++m)
                a[m] = *reinterpret_cast<const bf16x8*>(
                    &Al[(wr * 64 + m * 16 + l15) * 64 + ko]);
#pragma unroll
            for (int n = 0; n < 4; ++n)
                b[n] = *reinterpret_cast<const bf16x8*>(
                    &Bl[(wc * 64 + n * 16 + l15) * 64 + ko]);
            __builtin_amdgcn_s_setprio(1);
#pragma unroll
            for (int m = 0; m < 4; ++m)
#pragma unroll
                for (int n = 0; n < 4; ++n)
                    acc[m][n] = __builtin_amdgcn_mfma_f32_16x16x32_bf16(
                        a[m], b[n], acc[m][n], 0, 0, 0);
            __builtin_amdgcn_s_setprio(0);
        }
        __syncthreads();
    }

    // epilogue; C/D: col = lane&15, row = (lane>>4)*4 + reg (verified)
#pragma unroll
    for (int n = 0; n < 4; ++n) {
        const int col = n0 + wc * 64 + n * 16 + l15;
        const float bv = bias[col];
        if (MODE == 0) {
#pragma unroll
            for (int m = 0; m < 4; ++m) {
                const int row0 = m0 + wr * 64 + m * 16 + l4 * 4;
#pragma unroll
                for (int r = 0; r < 4; ++r)
                    Cout[(size_t)(row0 + r) * N + col] = acc[m][n][r] + bv;
            }
        } else if (col < 2 * EMB) {
            // Q/K part, row-major bf16, stride 2048
#pragma unroll
            for (int m = 0; m < 4; ++m) {
                const int row0 = m0 + wr * 64 + m * 16 + l4 * 4;
#pragma unroll
                for (int r = 0; r < 4; ++r)
                    qkb[(size_t)(row0 + r) * 2048 + col] = f2bf(acc[m][n][r] + bv);
            }
        } else {
            // V part, transposed: vtb[(b*16+h)*64 + d][t], t = row
            const int h = (col - 2 * EMB) >> 6;
            const int d = col & 63;
#pragma unroll
            for (int m = 0; m < 4; ++m) {
                const int row0 = m0 + wr * 64 + m * 16 + l4 * 4;
                const int bb = row0 >> 11;
                const int t  = row0 & 2047;
                uint2 pk;
                pk.x = cvt_pk_bf16(acc[m][n][0] + bv, acc[m][n][1] + bv);
                pk.y = cvt_pk_bf16(acc[m][n][2] + bv, acc[m][n][3] + bv);
                *reinterpret_cast<uint2*>(
                    &vtb[((size_t)(bb * 16 + h) * 64 + d) * 2048 + t]) = pk;
            }
        }
    }
}

// ---------------------------------------------------------------------------
// MFMA flash attention, swapped-QK softmax, 128 q-rows per block.
// 4 waves (256 thr); wave w owns q rows [w*32, w*32+32), two 16-row
// subblocks. K/V double-buffered. Critical-path-lean softmax (per-lane
// partial max + ballot; l via MFMA-ones).
//
// Block mapping: co-resident pairs (id, id+256) get COMPLEMENTARY q-tile
// lengths (qt and 15-qt) so every CU's two blocks sum to constant work
// (34 kv-tile iterations). xcd = id&7 keeps 4 heads per XCD L2.
// ---------------------------------------------------------------------------
__global__ __launch_bounds__(256) void attn_mfma(
    const ushort* __restrict__ qk, const ushort* __restrict__ vt,
    ushort* __restrict__ y)
{
    __shared__ alignas(16) ushort Kl[2][4096];
    __shared__ alignas(16) ushort Vl[2][4096];
    __shared__ alignas(16) ushort QP[8192];     // 128 rows x 64

    const int tid  = threadIdx.x;
    const int lane = tid & 63;
    const int w    = tid >> 6;     // wave 0..3
    const int l15  = lane & 15;
    const int l4   = lane >> 4;

    // Complementary-pair mapping (see header comment)
    const int id  = blockIdx.x;
    const int xcd = id & 7;
    const int s   = (id >> 3) & 15;
    const int g   = id >> 7;                      // 0..3
    const int bh  = xcd * 4 + g;                  // 0..31
    const int qt  = (g < 2) ? (15 - s) : s;       // q-tile index 0..15
    const int b   = bh >> 4;
    const int h   = bh & 15;

    const ushort* qbase = qk + (size_t)b * SEQ * 2048 + h * HD;
    const ushort* kbase = qbase + EMB;
    const ushort* vbase = vt + (size_t)bh * HD * SEQ;        // [d][t]

    const int swz   = (l15 & 7) << 4;
    const int koff0 = ((l4 * 16) ^ swz) >> 1;        // ushort units
    const int koff1 = ((64 + l4 * 16) ^ swz) >> 1;

    // ---- prologue: stage Q (128x64), K0, V0 ----
#pragma unroll
    for (int it = 0; it < 4; ++it) {
        int i = tid + it * 256;              // 0..1023
        int r = i >> 3;                      // q row 0..127
        int c = ((i & 7) ^ (r & 7)) << 3;
        gload_lds16(qbase + (size_t)(qt * 128 + r) * 2048 + c, &QP[i * 8]);
    }
#pragma unroll
    for (int it = 0; it < 2; ++it) {
        int i = tid + it * 256;
        int r = i >> 3;
        int c = ((i & 7) ^ (r & 7)) << 3;
        gload_lds16(kbase + (size_t)r * 2048 + c, &Kl[0][i * 8]);
    }
#pragma unroll
    for (int it = 0; it < 2; ++it) {
        int i = tid + it * 256;
        int d = i >> 3;
        int c = ((i & 7) ^ (d & 7)) << 3;
        gload_lds16(vbase + (size_t)d * 2048 + c, &Vl[0][i * 8]);
    }
    __syncthreads();

    // Q fragments for both q-subblocks (rows w*32 + qs*16 + l15)
    const int qrow0 = (w * 32 + l15) * 64;
    const int qrow1 = (w * 32 + 16 + l15) * 64;
    const bf16x8 qf00 = *reinterpret_cast<const bf16x8*>(&QP[qrow0 + koff0]);
    const bf16x8 qf01 = *reinterpret_cast<const bf16x8*>(&QP[qrow0 + koff1]);
    const bf16x8 qf10 = *reinterpret_cast<const bf16x8*>(&QP[qrow1 + koff0]);
    const bf16x8 qf11 = *reinterpret_cast<const bf16x8*>(&QP[qrow1 + koff1]);

    const short OBF = (short)0x3F80;   // 1.0 bf16
    const bf16x8 ones = {OBF, OBF, OBF, OBF, OBF, OBF, OBF, OBF};

    f32x4 o0[4], o1[4];
#pragma unroll
    for (int n = 0; n < 4; ++n)
#pragma unroll
        for (int r = 0; r < 4; ++r) { o0[n][r] = 0.f; o1[n][r] = 0.f; }
    f32x4 lacc0 = {0.f, 0.f, 0.f, 0.f};   // row-sums of P, layout == o rows
    f32x4 lacc1 = {0.f, 0.f, 0.f, 0.f};
    float m0 = -3.0e38f;   // per-lane running max (log2 units), q = .. + l15
    float m1 = -3.0e38f;

    const float BETA = 0.18033688f;  // 0.125 * log2(e)
    const int nkv = 2 * qt + 2;      // kv tiles of 64 covering [0, (qt+1)*128)

    for (int kk = 0; kk < nkv; ++kk) {
        const int p = kk & 1;

        // prefetch tile kk+1 (K rows, V^T cols) async to LDS
        if (kk < nkv - 1) {
#pragma unroll
            for (int it = 0; it < 2; ++it) {
                int i = tid + it * 256;
                int r = i >> 3;
                int c = ((i & 7) ^ (r & 7)) << 3;
                gload_lds16(kbase + (size_t)((kk + 1) * 64 + r) * 2048 + c,
                            &Kl[p ^ 1][i * 8]);
            }
#pragma unroll
            for (int it = 0; it < 2; ++it) {
                int i = tid + it * 256;
                int d = i >> 3;
                int c = ((i & 7) ^ (d & 7)) << 3;
                gload_lds16(vbase + (size_t)d * 2048 + (kk + 1) * 64 + c,
                            &Vl[p ^ 1][i * 8]);
            }
        }

        // K fragments (shared by both q-subblocks)
        bf16x8 kf[4][2];
#pragma unroll
        for (int n = 0; n < 4; ++n) {
            kf[n][0] = *reinterpret_cast<const bf16x8*>(
                &Kl[p][(n * 16 + l15) * 64 + koff0]);
            kf[n][1] = *reinterpret_cast<const bf16x8*>(
                &Kl[p][(n * 16 + l15) * 64 + koff1]);
        }

        // S^T = mfma(K, Q): rows k = n*16+l4*4+r, cols q = l15 (per subblock)
        f32x4 s0[4], s1[4];
        __builtin_amdgcn_s_setprio(1);
#pragma unroll
        for (int n = 0; n < 4; ++n) {
            f32x4 z0 = {0.f, 0.f, 0.f, 0.f};
            z0 = __builtin_amdgcn_mfma_f32_16x16x32_bf16(kf[n][0], qf00, z0, 0, 0, 0);
            s0[n] = __builtin_amdgcn_mfma_f32_16x16x32_bf16(kf[n][1], qf01, z0, 0, 0, 0);
            f32x4 z1 = {0.f, 0.f, 0.f, 0.f};
            z1 = __builtin_amdgcn_mfma_f32_16x16x32_bf16(kf[n][0], qf10, z1, 0, 0, 0);
            s1[n] = __builtin_amdgcn_mfma_f32_16x16x32_bf16(kf[n][1], qf11, z1, 0, 0, 0);
        }
        __builtin_amdgcn_s_setprio(0);

        // V fragments (shared; issue early so ds latency hides under softmax)
        bf16x8 vf[4][2];
#pragma unroll
        for (int n = 0; n < 4; ++n) {
            vf[n][0] = *reinterpret_cast<const bf16x8*>(
                &Vl[p][(n * 16 + l15) * 64 + koff0]);
            vf[n][1] = *reinterpret_cast<const bf16x8*>(
                &Vl[p][(n * 16 + l15) * 64 + koff1]);
        }

        // causal mask: only the last two kv tiles can violate causality
        if (kk >= nkv - 2) {
            const int q0 = qt * 128 + w * 32 + l15;
            const int q1 = q0 + 16;
#pragma unroll
            for (int n = 0; n < 4; ++n)
#pragma unroll
                for (int r = 0; r < 4; ++r) {
                    int kg = kk * 64 + n * 16 + l4 * 4 + r;
                    if (kg > q0) s0[n][r] = -3.0e38f;
                    if (kg > q1) s1[n][r] = -3.0e38f;
                }
        }

        // per-lane partial max (tree, depth 4) -> conservative rescale check
        float pm0, pm1;
        {
            float a0 = fmaxf(fmaxf(s0[0][0], s0[0][1]), fmaxf(s0[0][2], s0[0][3]));
            float a1 = fmaxf(fmaxf(s0[1][0], s0[1][1]), fmaxf(s0[1][2], s0[1][3]));
            float a2 = fmaxf(fmaxf(s0[2][0], s0[2][1]), fmaxf(s0[2][2], s0[2][3]));
            float a3 = fmaxf(fmaxf(s0[3][0], s0[3][1]), fmaxf(s0[3][2], s0[3][3]));
            pm0 = fmaxf(fmaxf(a0, a1), fmaxf(a2, a3)) * BETA;
            float b0 = fmaxf(fmaxf(s1[0][0], s1[0][1]), fmaxf(s1[0][2], s1[0][3]));
            float b1 = fmaxf(fmaxf(s1[1][0], s1[1][1]), fmaxf(s1[1][2], s1[1][3]));
            float b2 = fmaxf(fmaxf(s1[2][0], s1[2][1]), fmaxf(s1[2][2], s1[2][3]));
            float b3 = fmaxf(fmaxf(s1[3][0], s1[3][1]), fmaxf(s1[3][2], s1[3][3]));
            pm1 = fmaxf(fmaxf(b0, b1), fmaxf(b2, b3)) * BETA;
        }

        // defer-max rescale (rare, wave-uniform). Ballot covers every (k,q)
        // value of both subblocks, so the bound p <= 2^8 is exact.
        if (__any((pm0 > m0 + 8.0f) || (pm1 > m1 + 8.0f))) {
            float tm0 = fmaxf(pm0, __shfl_xor(pm0, 16));
            tm0 = fmaxf(tm0, __shfl_xor(tm0, 32));
            float tm1 = fmaxf(pm1, __shfl_xor(pm1, 16));
            tm1 = fmaxf(tm1, __shfl_xor(tm1, 32));
            float mn0 = fmaxf(m0, tm0);
            float al0 = exp2f(m0 - mn0);
            m0 = mn0;
            float mn1 = fmaxf(m1, tm1);
            float al1 = exp2f(m1 - mn1);
            m1 = mn1;
            float a00 = __shfl(al0, l4 * 4 + 0, 16);
            float a01 = __shfl(al0, l4 * 4 + 1, 16);
            float a02 = __shfl(al0, l4 * 4 + 2, 16);
            float a03 = __shfl(al0, l4 * 4 + 3, 16);
            float a10 = __shfl(al1, l4 * 4 + 0, 16);
            float a11 = __shfl(al1, l4 * 4 + 1, 16);
            float a12 = __shfl(al1, l4 * 4 + 2, 16);
            float a13 = __shfl(al1, l4 * 4 + 3, 16);
            lacc0[0] *= a00; lacc0[1] *= a01; lacc0[2] *= a02; lacc0[3] *= a03;
            lacc1[0] *= a10; lacc1[1] *= a11; lacc1[2] *= a12; lacc1[3] *= a13;
#pragma unroll
            for (int n = 0; n < 4; ++n) {
                o0[n][0] *= a00; o0[n][1] *= a01; o0[n][2] *= a02; o0[n][3] *= a03;
                o1[n][0] *= a10; o1[n][1] *= a11; o1[n][2] *= a12; o1[n][3] *= a13;
            }
        }

        // p = 2^(s*BETA - m), pack + store P (wave-local rows; no sum chain)
#pragma unroll
        for (int n = 0; n < 4; ++n) {
            float pa = exp2f(fmaf(s0[n][0], BETA, -m0));
            float pb = exp2f(fmaf(s0[n][1], BETA, -m0));
            float pc = exp2f(fmaf(s0[n][2], BETA, -m0));
            float pd = exp2f(fmaf(s0[n][3], BETA, -m0));
            uint2 pk;
            pk.x = cvt_pk_bf16(pa, pb);
            pk.y = cvt_pk_bf16(pc, pd);
            *reinterpret_cast<uint2*>(
                &QP[qrow0 + (((n * 32 + l4 * 8) ^ swz) >> 1)]) = pk;
            pa = exp2f(fmaf(s1[n][0], BETA, -m1));
            pb = exp2f(fmaf(s1[n][1], BETA, -m1));
            pc = exp2f(fmaf(s1[n][2], BETA, -m1));
            pd = exp2f(fmaf(s1[n][3], BETA, -m1));
            pk.x = cvt_pk_bf16(pa, pb);
            pk.y = cvt_pk_bf16(pc, pd);
            *reinterpret_cast<uint2*>(
                &QP[qrow1 + (((n * 32 + l4 * 8) ^ swz) >> 1)]) = pk;
        }

        // O += P V, l += P·1  (P rows q, V^T rows d, natural k)
        bf16x8 pf00 = *reinterpret_cast<const bf16x8*>(&QP[qrow0 + koff0]);
        bf16x8 pf01 = *reinterpret_cast<const bf16x8*>(&QP[qrow0 + koff1]);
        bf16x8 pf10 = *reinterpret_cast<const bf16x8*>(&QP[qrow1 + koff0]);
        bf16x8 pf11 = *reinterpret_cast<const bf16x8*>(&QP[qrow1 + koff1]);
        __builtin_amdgcn_s_setprio(1);
        lacc0 = __builtin_amdgcn_mfma_f32_16x16x32_bf16(pf00, ones, lacc0, 0, 0, 0);
        lacc0 = __builtin_amdgcn_mfma_f32_16x16x32_bf16(pf01, ones, lacc0, 0, 0, 0);
        lacc1 = __builtin_amdgcn_mfma_f32_16x16x32_bf16(pf10, ones, lacc1, 0, 0, 0);
        lacc1 = __builtin_amdgcn_mfma_f32_16x16x32_bf16(pf11, ones, lacc1, 0, 0, 0);
#pragma unroll
        for (int n = 0; n < 4; ++n) {
            o0[n] = __builtin_amdgcn_mfma_f32_16x16x32_bf16(pf00, vf[n][0], o0[n], 0, 0, 0);
            o0[n] = __builtin_amdgcn_mfma_f32_16x16x32_bf16(pf01, vf[n][1], o0[n], 0, 0, 0);
            o1[n] = __builtin_amdgcn_mfma_f32_16x16x32_bf16(pf10, vf[n][0], o1[n], 0, 0, 0);
            o1[n] = __builtin_amdgcn_mfma_f32_16x16x32_bf16(pf11, vf[n][1], o1[n], 0, 0, 0);
        }
        __builtin_amdgcn_s_setprio(0);
        __syncthreads();
    }

    // epilogue: O rows q = qs*16 + l4*4 + r (within wave), cols d = n*16+l15
    // lacc[r] already sits in the o-row layout — no shuffles needed.
#pragma unroll
    for (int r = 0; r < 4; ++r) {
        float inv0 = 1.f / lacc0[r];
        float inv1 = 1.f / lacc1[r];
        int row0 = qt * 128 + w * 32 + l4 * 4 + r;
        int row1 = row0 + 16;
#pragma unroll
        for (int n = 0; n < 4; ++n) {
            y[(size_t)(b * SEQ + row0) * EMB + h * HD + n * 16 + l15] =
                f2bf(o0[n][r] * inv0);
            y[(size_t)(b * SEQ + row1) * EMB + h * HD + n * 16 + l15] =
                f2bf(o1[n][r] * inv1);
        }
    }
}

// ---------------------------------------------------------------------------
extern "C" void kernel_launch(void* const* d_in, const int* in_sizes, int n_in,
                              void* d_out, int out_size, void* d_ws, size_t ws_size,
                              hipStream_t stream)
{
    const float* x     = (const float*)d_in[0];   // [B,T,E]
    const float* qkv_w = (const float*)d_in[1];   // [3E,E]
    const float* qkv_b = (const float*)d_in[2];   // [3E]
    const float* o_w   = (const float*)d_in[3];   // [E,E]
    const float* o_b   = (const float*)d_in[4];   // [E]
    float* out = (float*)d_out;                   // [B,T,E] fp32

    // workspace (ushort units)
    ushort* xb    = (ushort*)d_ws;                       // 4M
    ushort* wqkvb = xb    + (size_t)M_ROWS * EMB;        // 3M
    ushort* owb   = wqkvb + (size_t)3 * EMB * EMB;       // 1M
    ushort* qkb   = owb   + (size_t)EMB * EMB;           // 8M  [4096][2048]
    ushort* vtb   = qkb   + (size_t)M_ROWS * 2 * EMB;    // 4M  [32][64][2048]
    ushort* ybb   = vtb   + (size_t)32 * HD * SEQ;       // 4M  [4096][1024]

    // 0) fused fp32 -> bf16 (x, qkv_w, o_w -> contiguous xb/wqkvb/owb)
    {
        int n1 = M_ROWS * EMB;        // 4M
        int n2 = 3 * EMB * EMB;       // 3M
        int ntot = n1 + n2 + EMB * EMB;
        cvt3_f32_bf16<<<ntot / 1024, 256, 0, stream>>>(
            x, qkv_w, o_w, xb, n1, n2);
    }

    // 1) QKV projection, split output: Q/K row-major, V transposed
    {
        dim3 grid(3 * EMB / 128, M_ROWS / 128);   // (24, 32)
        gemm_mfma_abt<1><<<grid, 256, 0, stream>>>(
            xb, wqkvb, qkv_b, nullptr, qkb, vtb, M_ROWS, 3 * EMB, EMB);
    }

    // 2) MFMA flash attention -> ybb (bf16 [M,E])
    {
        attn_mfma<<<512, 256, 0, stream>>>(qkb, vtb, ybb);
    }

    // 3) Output projection (fp32 out)
    {
        dim3 grid(EMB / 128, M_ROWS / 128);       // (8, 32)
        gemm_mfma_abt<0><<<grid, 256, 0, stream>>>(
            ybb, owb, o_b, out, nullptr, nullptr, M_ROWS, EMB, EMB);
    }
}

// Round 10
// 129.177 us; speedup vs baseline: 33.7835x; 1.0410x over previous
//
#include <hip/hip_runtime.h>
#include <hip/hip_bf16.h>
#include <math.h>

// Problem constants
#define BATCH 2
#define SEQ   2048
#define EMB   1024
#define NH    16
#define HD    64
#define M_ROWS (BATCH * SEQ)   // 4096

typedef __attribute__((ext_vector_type(8))) short bf16x8;
typedef __attribute__((ext_vector_type(4))) float f32x4;

// fp32 -> bf16 round-to-nearest-even, raw bits
__device__ __forceinline__ ushort f2bf(float f) {
    unsigned u = __float_as_uint(f);
    unsigned lsb = (u >> 16) & 1u;
    u += 0x7fffu + lsb;
    return (ushort)(u >> 16);
}

// packed f32 pair -> 2 bf16 in one u32 (RNE), single VALU op
__device__ __forceinline__ unsigned cvt_pk_bf16(float lo, float hi) {
    unsigned r;
    asm("v_cvt_pk_bf16_f32 %0, %1, %2" : "=v"(r) : "v"(lo), "v"(hi));
    return r;
}

__device__ __forceinline__ void gload_lds16(const void* g, void* l) {
    __builtin_amdgcn_global_load_lds(
        (const __attribute__((address_space(1))) unsigned int*)g,
        (__attribute__((address_space(3))) unsigned int*)l, 16, 0, 0);
}

// ---------------------------------------------------------------------------
// fused fp32 -> bf16 conversion of x, qkv_w, o_w (outputs contiguous in ws)
// ---------------------------------------------------------------------------
__global__ __launch_bounds__(256) void cvt3_f32_bf16(
    const float* __restrict__ s1, const float* __restrict__ s2,
    const float* __restrict__ s3, ushort* __restrict__ out,
    int n1, int n2)
{
    int i = (blockIdx.x * 256 + threadIdx.x) * 4;
    const float* src;
    int off;
    if (i < n1)            { src = s1; off = i; }
    else if (i < n1 + n2)  { src = s2; off = i - n1; }
    else                   { src = s3; off = i - n1 - n2; }
    float4 v = *reinterpret_cast<const float4*>(&src[off]);
    uint2 pk;
    pk.x = cvt_pk_bf16(v.x, v.y);
    pk.y = cvt_pk_bf16(v.z, v.w);
    *reinterpret_cast<uint2*>(&out[i]) = pk;
}

// ---------------------------------------------------------------------------
// bf16 MFMA GEMM: C[M,N] = A[M,K] * B[N,K]^T + bias[N]
// MODE 0: fp32 output to Cout (O-projection).
// MODE 1: QKV split — cols [0,2048) bf16 to qkb (stride 2048);
//         cols [2048,3072) = V written TRANSPOSED to vtb[b*16+h][d][t].
// ---------------------------------------------------------------------------
template <int MODE>
__global__ __launch_bounds__(256) void gemm_mfma_abt(
    const ushort* __restrict__ A, const ushort* __restrict__ B,
    const float* __restrict__ bias, float* __restrict__ Cout,
    ushort* __restrict__ qkb, ushort* __restrict__ vtb,
    int M, int N, int K)
{
    __shared__ ushort Al[128 * 64];
    __shared__ ushort Bl[128 * 64];

    const int tid  = threadIdx.x;
    const int lane = tid & 63;
    const int wave = tid >> 6;
    const int wr   = wave >> 1;
    const int wc   = wave & 1;
    const int l15  = lane & 15;
    const int l4   = lane >> 4;
    const int m0   = blockIdx.y * 128;
    const int n0   = blockIdx.x * 128;

    f32x4 acc[4][4];
#pragma unroll
    for (int m = 0; m < 4; ++m)
#pragma unroll
        for (int n = 0; n < 4; ++n)
#pragma unroll
            for (int r = 0; r < 4; ++r) acc[m][n][r] = 0.f;

    for (int k0 = 0; k0 < K; k0 += 64) {
#pragma unroll
        for (int it = 0; it < 4; ++it) {
            int chunk = tid + it * 256;
            int row = chunk >> 3;
            int kc  = (chunk & 7) * 8;
            gload_lds16(&A[(size_t)(m0 + row) * K + k0 + kc], &Al[chunk * 8]);
            gload_lds16(&B[(size_t)(n0 + row) * K + k0 + kc], &Bl[chunk * 8]);
        }
        __syncthreads();

#pragma unroll
        for (int kk = 0; kk < 2; ++kk) {
            const int ko = kk * 32 + l4 * 8;
            bf16x8 a[4], b[4];
#pragma unroll
            for (int m = 0; m < 4; ++m)
                a[m] = *reinterpret_cast<const bf16x8*>(
                    &Al[(wr * 64 + m * 16 + l15) * 64 + ko]);
#pragma unroll
            for (int n = 0; n < 4; ++n)
                b[n] = *reinterpret_cast<const bf16x8*>(
                    &Bl[(wc * 64 + n * 16 + l15) * 64 + ko]);
            __builtin_amdgcn_s_setprio(1);
#pragma unroll
            for (int m = 0; m < 4; ++m)
#pragma unroll
                for (int n = 0; n < 4; ++n)
                    acc[m][n] = __builtin_amdgcn_mfma_f32_16x16x32_bf16(
                        a[m], b[n], acc[m][n], 0, 0, 0);
            __builtin_amdgcn_s_setprio(0);
        }
        __syncthreads();
    }

    // epilogue; C/D: col = lane&15, row = (lane>>4)*4 + reg (verified)
#pragma unroll
    for (int n = 0; n < 4; ++n) {
        const int col = n0 + wc * 64 + n * 16 + l15;
        const float bv = bias[col];
        if (MODE == 0) {
#pragma unroll
            for (int m = 0; m < 4; ++m) {
                const int row0 = m0 + wr * 64 + m * 16 + l4 * 4;
#pragma unroll
                for (int r = 0; r < 4; ++r)
                    Cout[(size_t)(row0 + r) * N + col] = acc[m][n][r] + bv;
            }
        } else if (col < 2 * EMB) {
            // Q/K part, row-major bf16, stride 2048
#pragma unroll
            for (int m = 0; m < 4; ++m) {
                const int row0 = m0 + wr * 64 + m * 16 + l4 * 4;
#pragma unroll
                for (int r = 0; r < 4; ++r)
                    qkb[(size_t)(row0 + r) * 2048 + col] = f2bf(acc[m][n][r] + bv);
            }
        } else {
            // V part, transposed: vtb[(b*16+h)*64 + d][t], t = row
            const int h = (col - 2 * EMB) >> 6;
            const int d = col & 63;
#pragma unroll
            for (int m = 0; m < 4; ++m) {
                const int row0 = m0 + wr * 64 + m * 16 + l4 * 4;
                const int bb = row0 >> 11;
                const int t  = row0 & 2047;
                uint2 pk;
                pk.x = cvt_pk_bf16(acc[m][n][0] + bv, acc[m][n][1] + bv);
                pk.y = cvt_pk_bf16(acc[m][n][2] + bv, acc[m][n][3] + bv);
                *reinterpret_cast<uint2*>(
                    &vtb[((size_t)(bb * 16 + h) * 64 + d) * 2048 + t]) = pk;
            }
        }
    }
}

// ---------------------------------------------------------------------------
// MFMA flash attention, swapped-QK softmax, 128 q-rows per block, 4 waves.
// QUAD-buffered K/V (tile t -> buffer t&3); main loop processes 2 kv-tiles
// per barrier: stage kk+2,kk+3 -> compute kk -> compute kk+1 -> sync.
// Tile B's MFMAs overlap tile A's softmax VALU (different pipes).
// Critical-path-lean softmax (per-lane partial max + ballot; l via MFMA-ones).
// Complementary-pair block mapping balances per-CU work (34 tile-iters).
// ---------------------------------------------------------------------------
__global__ __launch_bounds__(256) void attn_mfma(
    const ushort* __restrict__ qk, const ushort* __restrict__ vt,
    ushort* __restrict__ y)
{
    __shared__ alignas(16) ushort Kl[4][4096];
    __shared__ alignas(16) ushort Vl[4][4096];
    __shared__ alignas(16) ushort QP[8192];     // 128 rows x 64

    const int tid  = threadIdx.x;
    const int lane = tid & 63;
    const int w    = tid >> 6;     // wave 0..3
    const int l15  = lane & 15;
    const int l4   = lane >> 4;

    // Complementary-pair mapping: (id, id+256) get qt and 15-qt
    const int id  = blockIdx.x;
    const int xcd = id & 7;
    const int s   = (id >> 3) & 15;
    const int g   = id >> 7;                      // 0..3
    const int bh  = xcd * 4 + g;                  // 0..31
    const int qt  = (g < 2) ? (15 - s) : s;       // q-tile index 0..15
    const int b   = bh >> 4;
    const int h   = bh & 15;

    const ushort* qbase = qk + (size_t)b * SEQ * 2048 + h * HD;
    const ushort* kbase = qbase + EMB;
    const ushort* vbase = vt + (size_t)bh * HD * SEQ;        // [d][t]

    const int swz   = (l15 & 7) << 4;
    const int koff0 = ((l4 * 16) ^ swz) >> 1;        // ushort units
    const int koff1 = ((64 + l4 * 16) ^ swz) >> 1;

    // ---- prologue: stage Q (128x64), tiles 0 and 1 ----
#pragma unroll
    for (int it = 0; it < 4; ++it) {
        int i = tid + it * 256;              // 0..1023
        int r = i >> 3;                      // q row 0..127
        int c = ((i & 7) ^ (r & 7)) << 3;
        gload_lds16(qbase + (size_t)(qt * 128 + r) * 2048 + c, &QP[i * 8]);
    }
#pragma unroll
    for (int it = 0; it < 2; ++it) {
        int i = tid + it * 256;
        int r = i >> 3;
        int c = ((i & 7) ^ (r & 7)) << 3;
        gload_lds16(kbase + (size_t)r * 2048 + c, &Kl[0][i * 8]);
        gload_lds16(kbase + (size_t)(64 + r) * 2048 + c, &Kl[1][i * 8]);
    }
#pragma unroll
    for (int it = 0; it < 2; ++it) {
        int i = tid + it * 256;
        int d = i >> 3;
        int c = ((i & 7) ^ (d & 7)) << 3;
        gload_lds16(vbase + (size_t)d * 2048 + c, &Vl[0][i * 8]);
        gload_lds16(vbase + (size_t)d * 2048 + 64 + c, &Vl[1][i * 8]);
    }
    __syncthreads();

    // Q fragments for both q-subblocks (rows w*32 + qs*16 + l15)
    const int qrow0 = (w * 32 + l15) * 64;
    const int qrow1 = (w * 32 + 16 + l15) * 64;
    const bf16x8 qf00 = *reinterpret_cast<const bf16x8*>(&QP[qrow0 + koff0]);
    const bf16x8 qf01 = *reinterpret_cast<const bf16x8*>(&QP[qrow0 + koff1]);
    const bf16x8 qf10 = *reinterpret_cast<const bf16x8*>(&QP[qrow1 + koff0]);
    const bf16x8 qf11 = *reinterpret_cast<const bf16x8*>(&QP[qrow1 + koff1]);

    // P store offsets (loop-invariant)
    int pso[4];
#pragma unroll
    for (int n = 0; n < 4; ++n) pso[n] = ((n * 32 + l4 * 8) ^ swz) >> 1;

    const short OBF = (short)0x3F80;   // 1.0 bf16
    const bf16x8 ones = {OBF, OBF, OBF, OBF, OBF, OBF, OBF, OBF};

    f32x4 o0[4], o1[4];
#pragma unroll
    for (int n = 0; n < 4; ++n)
#pragma unroll
        for (int r = 0; r < 4; ++r) { o0[n][r] = 0.f; o1[n][r] = 0.f; }
    f32x4 lacc0 = {0.f, 0.f, 0.f, 0.f};   // row-sums of P, layout == o rows
    f32x4 lacc1 = {0.f, 0.f, 0.f, 0.f};
    float m0 = -3.0e38f;   // per-lane running max (log2 units)
    float m1 = -3.0e38f;

    const float BETA = 0.18033688f;  // 0.125 * log2(e)
    const int nkv = 2 * qt + 2;      // even: kv tiles of 64

    // one-tile compute (no barrier inside)
    auto computeTile = [&](const ushort* Kb, const ushort* Vb, int kkt) {
        bf16x8 kf[4][2];
#pragma unroll
        for (int n = 0; n < 4; ++n) {
            kf[n][0] = *reinterpret_cast<const bf16x8*>(
                &Kb[(n * 16 + l15) * 64 + koff0]);
            kf[n][1] = *reinterpret_cast<const bf16x8*>(
                &Kb[(n * 16 + l15) * 64 + koff1]);
        }
        f32x4 s0[4], s1[4];
        __builtin_amdgcn_s_setprio(1);
#pragma unroll
        for (int n = 0; n < 4; ++n) {
            f32x4 z0 = {0.f, 0.f, 0.f, 0.f};
            z0 = __builtin_amdgcn_mfma_f32_16x16x32_bf16(kf[n][0], qf00, z0, 0, 0, 0);
            s0[n] = __builtin_amdgcn_mfma_f32_16x16x32_bf16(kf[n][1], qf01, z0, 0, 0, 0);
            f32x4 z1 = {0.f, 0.f, 0.f, 0.f};
            z1 = __builtin_amdgcn_mfma_f32_16x16x32_bf16(kf[n][0], qf10, z1, 0, 0, 0);
            s1[n] = __builtin_amdgcn_mfma_f32_16x16x32_bf16(kf[n][1], qf11, z1, 0, 0, 0);
        }
        __builtin_amdgcn_s_setprio(0);

        bf16x8 vf[4][2];
#pragma unroll
        for (int n = 0; n < 4; ++n) {
            vf[n][0] = *reinterpret_cast<const bf16x8*>(
                &Vb[(n * 16 + l15) * 64 + koff0]);
            vf[n][1] = *reinterpret_cast<const bf16x8*>(
                &Vb[(n * 16 + l15) * 64 + koff1]);
        }

        // causal mask: only the last two kv tiles can violate causality
        if (kkt >= nkv - 2) {
            const int q0 = qt * 128 + w * 32 + l15;
            const int q1 = q0 + 16;
#pragma unroll
            for (int n = 0; n < 4; ++n)
#pragma unroll
                for (int r = 0; r < 4; ++r) {
                    int kg = kkt * 64 + n * 16 + l4 * 4 + r;
                    if (kg > q0) s0[n][r] = -3.0e38f;
                    if (kg > q1) s1[n][r] = -3.0e38f;
                }
        }

        // per-lane partial max (tree) -> conservative rescale check
        float pm0, pm1;
        {
            float a0 = fmaxf(fmaxf(s0[0][0], s0[0][1]), fmaxf(s0[0][2], s0[0][3]));
            float a1 = fmaxf(fmaxf(s0[1][0], s0[1][1]), fmaxf(s0[1][2], s0[1][3]));
            float a2 = fmaxf(fmaxf(s0[2][0], s0[2][1]), fmaxf(s0[2][2], s0[2][3]));
            float a3 = fmaxf(fmaxf(s0[3][0], s0[3][1]), fmaxf(s0[3][2], s0[3][3]));
            pm0 = fmaxf(fmaxf(a0, a1), fmaxf(a2, a3)) * BETA;
            float b0 = fmaxf(fmaxf(s1[0][0], s1[0][1]), fmaxf(s1[0][2], s1[0][3]));
            float b1 = fmaxf(fmaxf(s1[1][0], s1[1][1]), fmaxf(s1[1][2], s1[1][3]));
            float b2 = fmaxf(fmaxf(s1[2][0], s1[2][1]), fmaxf(s1[2][2], s1[2][3]));
            float b3 = fmaxf(fmaxf(s1[3][0], s1[3][1]), fmaxf(s1[3][2], s1[3][3]));
            pm1 = fmaxf(fmaxf(b0, b1), fmaxf(b2, b3)) * BETA;
        }

        // defer-max rescale (rare, wave-uniform); ballot covers all (k,q)
        if (__any((pm0 > m0 + 8.0f) || (pm1 > m1 + 8.0f))) {
            float tm0 = fmaxf(pm0, __shfl_xor(pm0, 16));
            tm0 = fmaxf(tm0, __shfl_xor(tm0, 32));
            float tm1 = fmaxf(pm1, __shfl_xor(pm1, 16));
            tm1 = fmaxf(tm1, __shfl_xor(tm1, 32));
            float mn0 = fmaxf(m0, tm0);
            float al0 = exp2f(m0 - mn0);
            m0 = mn0;
            float mn1 = fmaxf(m1, tm1);
            float al1 = exp2f(m1 - mn1);
            m1 = mn1;
            float a00 = __shfl(al0, l4 * 4 + 0, 16);
            float a01 = __shfl(al0, l4 * 4 + 1, 16);
            float a02 = __shfl(al0, l4 * 4 + 2, 16);
            float a03 = __shfl(al0, l4 * 4 + 3, 16);
            float a10 = __shfl(al1, l4 * 4 + 0, 16);
            float a11 = __shfl(al1, l4 * 4 + 1, 16);
            float a12 = __shfl(al1, l4 * 4 + 2, 16);
            float a13 = __shfl(al1, l4 * 4 + 3, 16);
            lacc0[0] *= a00; lacc0[1] *= a01; lacc0[2] *= a02; lacc0[3] *= a03;
            lacc1[0] *= a10; lacc1[1] *= a11; lacc1[2] *= a12; lacc1[3] *= a13;
#pragma unroll
            for (int n = 0; n < 4; ++n) {
                o0[n][0] *= a00; o0[n][1] *= a01; o0[n][2] *= a02; o0[n][3] *= a03;
                o1[n][0] *= a10; o1[n][1] *= a11; o1[n][2] *= a12; o1[n][3] *= a13;
            }
        }

        // p = 2^(s*BETA - m), pack + store P (wave-local rows)
#pragma unroll
        for (int n = 0; n < 4; ++n) {
            float pa = exp2f(fmaf(s0[n][0], BETA, -m0));
            float pb = exp2f(fmaf(s0[n][1], BETA, -m0));
            float pc = exp2f(fmaf(s0[n][2], BETA, -m0));
            float pd = exp2f(fmaf(s0[n][3], BETA, -m0));
            uint2 pk;
            pk.x = cvt_pk_bf16(pa, pb);
            pk.y = cvt_pk_bf16(pc, pd);
            *reinterpret_cast<uint2*>(&QP[qrow0 + pso[n]]) = pk;
            pa = exp2f(fmaf(s1[n][0], BETA, -m1));
            pb = exp2f(fmaf(s1[n][1], BETA, -m1));
            pc = exp2f(fmaf(s1[n][2], BETA, -m1));
            pd = exp2f(fmaf(s1[n][3], BETA, -m1));
            pk.x = cvt_pk_bf16(pa, pb);
            pk.y = cvt_pk_bf16(pc, pd);
            *reinterpret_cast<uint2*>(&QP[qrow1 + pso[n]]) = pk;
        }

        // O += P V, l += P·1
        bf16x8 pf00 = *reinterpret_cast<const bf16x8*>(&QP[qrow0 + koff0]);
        bf16x8 pf01 = *reinterpret_cast<const bf16x8*>(&QP[qrow0 + koff1]);
        bf16x8 pf10 = *reinterpret_cast<const bf16x8*>(&QP[qrow1 + koff0]);
        bf16x8 pf11 = *reinterpret_cast<const bf16x8*>(&QP[qrow1 + koff1]);
        __builtin_amdgcn_s_setprio(1);
        lacc0 = __builtin_amdgcn_mfma_f32_16x16x32_bf16(pf00, ones, lacc0, 0, 0, 0);
        lacc0 = __builtin_amdgcn_mfma_f32_16x16x32_bf16(pf01, ones, lacc0, 0, 0, 0);
        lacc1 = __builtin_amdgcn_mfma_f32_16x16x32_bf16(pf10, ones, lacc1, 0, 0, 0);
        lacc1 = __builtin_amdgcn_mfma_f32_16x16x32_bf16(pf11, ones, lacc1, 0, 0, 0);
#pragma unroll
        for (int n = 0; n < 4; ++n) {
            o0[n] = __builtin_amdgcn_mfma_f32_16x16x32_bf16(pf00, vf[n][0], o0[n], 0, 0, 0);
            o0[n] = __builtin_amdgcn_mfma_f32_16x16x32_bf16(pf01, vf[n][1], o0[n], 0, 0, 0);
            o1[n] = __builtin_amdgcn_mfma_f32_16x16x32_bf16(pf10, vf[n][0], o1[n], 0, 0, 0);
            o1[n] = __builtin_amdgcn_mfma_f32_16x16x32_bf16(pf11, vf[n][1], o1[n], 0, 0, 0);
        }
        __builtin_amdgcn_s_setprio(0);
    };

    for (int kk = 0; kk < nkv; kk += 2) {
        // stage tiles kk+2, kk+3 (buffers (kk+2)&3, (kk+3)&3)
        if (kk + 2 < nkv) {
            const int b2 = (kk + 2) & 3;
            const int b3 = (kk + 3) & 3;
#pragma unroll
            for (int it = 0; it < 2; ++it) {
                int i = tid + it * 256;
                int r = i >> 3;
                int c = ((i & 7) ^ (r & 7)) << 3;
                gload_lds16(kbase + (size_t)((kk + 2) * 64 + r) * 2048 + c,
                            &Kl[b2][i * 8]);
                gload_lds16(kbase + (size_t)((kk + 3) * 64 + r) * 2048 + c,
                            &Kl[b3][i * 8]);
            }
#pragma unroll
            for (int it = 0; it < 2; ++it) {
                int i = tid + it * 256;
                int d = i >> 3;
                int c = ((i & 7) ^ (d & 7)) << 3;
                gload_lds16(vbase + (size_t)d * 2048 + (kk + 2) * 64 + c,
                            &Vl[b2][i * 8]);
                gload_lds16(vbase + (size_t)d * 2048 + (kk + 3) * 64 + c,
                            &Vl[b3][i * 8]);
            }
        }

        computeTile(Kl[kk & 3], Vl[kk & 3], kk);
        computeTile(Kl[(kk + 1) & 3], Vl[(kk + 1) & 3], kk + 1);
        __syncthreads();
    }

    // epilogue: O rows q = qs*16 + l4*4 + r (within wave), cols d = n*16+l15
#pragma unroll
    for (int r = 0; r < 4; ++r) {
        float inv0 = 1.f / lacc0[r];
        float inv1 = 1.f / lacc1[r];
        int row0 = qt * 128 + w * 32 + l4 * 4 + r;
        int row1 = row0 + 16;
#pragma unroll
        for (int n = 0; n < 4; ++n) {
            y[(size_t)(b * SEQ + row0) * EMB + h * HD + n * 16 + l15] =
                f2bf(o0[n][r] * inv0);
            y[(size_t)(b * SEQ + row1) * EMB + h * HD + n * 16 + l15] =
                f2bf(o1[n][r] * inv1);
        }
    }
}

// ---------------------------------------------------------------------------
extern "C" void kernel_launch(void* const* d_in, const int* in_sizes, int n_in,
                              void* d_out, int out_size, void* d_ws, size_t ws_size,
                              hipStream_t stream)
{
    const float* x     = (const float*)d_in[0];   // [B,T,E]
    const float* qkv_w = (const float*)d_in[1];   // [3E,E]
    const float* qkv_b = (const float*)d_in[2];   // [3E]
    const float* o_w   = (const float*)d_in[3];   // [E,E]
    const float* o_b   = (const float*)d_in[4];   // [E]
    float* out = (float*)d_out;                   // [B,T,E] fp32

    // workspace (ushort units)
    ushort* xb    = (ushort*)d_ws;                       // 4M
    ushort* wqkvb = xb    + (size_t)M_ROWS * EMB;        // 3M
    ushort* owb   = wqkvb + (size_t)3 * EMB * EMB;       // 1M
    ushort* qkb   = owb   + (size_t)EMB * EMB;           // 8M  [4096][2048]
    ushort* vtb   = qkb   + (size_t)M_ROWS * 2 * EMB;    // 4M  [32][64][2048]
    ushort* ybb   = vtb   + (size_t)32 * HD * SEQ;       // 4M  [4096][1024]

    // 0) fused fp32 -> bf16 (x, qkv_w, o_w -> contiguous xb/wqkvb/owb)
    {
        int n1 = M_ROWS * EMB;        // 4M
        int n2 = 3 * EMB * EMB;       // 3M
        int ntot = n1 + n2 + EMB * EMB;
        cvt3_f32_bf16<<<ntot / 1024, 256, 0, stream>>>(
            x, qkv_w, o_w, xb, n1, n2);
    }

    // 1) QKV projection, split output: Q/K row-major, V transposed
    {
        dim3 grid(3 * EMB / 128, M_ROWS / 128);   // (24, 32)
        gemm_mfma_abt<1><<<grid, 256, 0, stream>>>(
            xb, wqkvb, qkv_b, nullptr, qkb, vtb, M_ROWS, 3 * EMB, EMB);
    }

    // 2) MFMA flash attention -> ybb (bf16 [M,E])
    {
        attn_mfma<<<512, 256, 0, stream>>>(qkb, vtb, ybb);
    }

    // 3) Output projection (fp32 out)
    {
        dim3 grid(EMB / 128, M_ROWS / 128);       // (8, 32)
        gemm_mfma_abt<0><<<grid, 256, 0, stream>>>(
            ybb, owb, o_b, out, nullptr, nullptr, M_ROWS, EMB, EMB);
    }
}

// Round 11
// 113.695 us; speedup vs baseline: 38.3840x; 1.1362x over previous
//
#include <hip/hip_runtime.h>
#include <hip/hip_bf16.h>
#include <math.h>

// Problem constants
#define BATCH 2
#define SEQ   2048
#define EMB   1024
#define NH    16
#define HD    64
#define M_ROWS (BATCH * SEQ)   // 4096

typedef __attribute__((ext_vector_type(8))) short bf16x8;
typedef __attribute__((ext_vector_type(4))) float f32x4;

// fp32 -> bf16 round-to-nearest-even, raw bits
__device__ __forceinline__ ushort f2bf(float f) {
    unsigned u = __float_as_uint(f);
    unsigned lsb = (u >> 16) & 1u;
    u += 0x7fffu + lsb;
    return (ushort)(u >> 16);
}

// packed f32 pair -> 2 bf16 in one u32 (RNE), single VALU op
__device__ __forceinline__ unsigned cvt_pk_bf16(float lo, float hi) {
    unsigned r;
    asm("v_cvt_pk_bf16_f32 %0, %1, %2" : "=v"(r) : "v"(lo), "v"(hi));
    return r;
}

__device__ __forceinline__ void gload_lds16(const void* g, void* l) {
    __builtin_amdgcn_global_load_lds(
        (const __attribute__((address_space(1))) unsigned int*)g,
        (__attribute__((address_space(3))) unsigned int*)l, 16, 0, 0);
}

// ---------------------------------------------------------------------------
// fused fp32 -> bf16 conversion of x, qkv_w, o_w (outputs contiguous in ws)
// ---------------------------------------------------------------------------
__global__ __launch_bounds__(256) void cvt3_f32_bf16(
    const float* __restrict__ s1, const float* __restrict__ s2,
    const float* __restrict__ s3, ushort* __restrict__ out,
    int n1, int n2)
{
    int i = (blockIdx.x * 256 + threadIdx.x) * 4;
    const float* src;
    int off;
    if (i < n1)            { src = s1; off = i; }
    else if (i < n1 + n2)  { src = s2; off = i - n1; }
    else                   { src = s3; off = i - n1 - n2; }
    float4 v = *reinterpret_cast<const float4*>(&src[off]);
    uint2 pk;
    pk.x = cvt_pk_bf16(v.x, v.y);
    pk.y = cvt_pk_bf16(v.z, v.w);
    *reinterpret_cast<uint2*>(&out[i]) = pk;
}

// ---------------------------------------------------------------------------
// bf16 MFMA GEMM: C[M,N] = A[M,K] * B[N,K]^T + bias[N]
// MODE 0: fp32 output to Cout (O-projection).
// MODE 1: QKV split — cols [0,2048) bf16 to qkb (stride 2048);
//         cols [2048,3072) = V written TRANSPOSED to vtb[b*16+h][d][t].
// ---------------------------------------------------------------------------
template <int MODE>
__global__ __launch_bounds__(256) void gemm_mfma_abt(
    const ushort* __restrict__ A, const ushort* __restrict__ B,
    const float* __restrict__ bias, float* __restrict__ Cout,
    ushort* __restrict__ qkb, ushort* __restrict__ vtb,
    int M, int N, int K)
{
    __shared__ ushort Al[128 * 64];
    __shared__ ushort Bl[128 * 64];

    const int tid  = threadIdx.x;
    const int lane = tid & 63;
    const int wave = tid >> 6;
    const int wr   = wave >> 1;
    const int wc   = wave & 1;
    const int l15  = lane & 15;
    const int l4   = lane >> 4;
    const int m0   = blockIdx.y * 128;
    const int n0   = blockIdx.x * 128;

    f32x4 acc[4][4];
#pragma unroll
    for (int m = 0; m < 4; ++m)
#pragma unroll
        for (int n = 0; n < 4; ++n)
#pragma unroll
            for (int r = 0; r < 4; ++r) acc[m][n][r] = 0.f;

    for (int k0 = 0; k0 < K; k0 += 64) {
#pragma unroll
        for (int it = 0; it < 4; ++it) {
            int chunk = tid + it * 256;
            int row = chunk >> 3;
            int kc  = (chunk & 7) * 8;
            gload_lds16(&A[(size_t)(m0 + row) * K + k0 + kc], &Al[chunk * 8]);
            gload_lds16(&B[(size_t)(n0 + row) * K + k0 + kc], &Bl[chunk * 8]);
        }
        __syncthreads();

#pragma unroll
        for (int kk = 0; kk < 2; ++kk) {
            const int ko = kk * 32 + l4 * 8;
            bf16x8 a[4], b[4];
#pragma unroll
            for (int m = 0; m < 4; ++m)
                a[m] = *reinterpret_cast<const bf16x8*>(
                    &Al[(wr * 64 + m * 16 + l15) * 64 + ko]);
#pragma unroll
            for (int n = 0; n < 4; ++n)
                b[n] = *reinterpret_cast<const bf16x8*>(
                    &Bl[(wc * 64 + n * 16 + l15) * 64 + ko]);
            __builtin_amdgcn_s_setprio(1);
#pragma unroll
            for (int m = 0; m < 4; ++m)
#pragma unroll
                for (int n = 0; n < 4; ++n)
                    acc[m][n] = __builtin_amdgcn_mfma_f32_16x16x32_bf16(
                        a[m], b[n], acc[m][n], 0, 0, 0);
            __builtin_amdgcn_s_setprio(0);
        }
        __syncthreads();
    }

    // epilogue; C/D: col = lane&15, row = (lane>>4)*4 + reg (verified)
#pragma unroll
    for (int n = 0; n < 4; ++n) {
        const int col = n0 + wc * 64 + n * 16 + l15;
        const float bv = bias[col];
        if (MODE == 0) {
#pragma unroll
            for (int m = 0; m < 4; ++m) {
                const int row0 = m0 + wr * 64 + m * 16 + l4 * 4;
#pragma unroll
                for (int r = 0; r < 4; ++r)
                    Cout[(size_t)(row0 + r) * N + col] = acc[m][n][r] + bv;
            }
        } else if (col < 2 * EMB) {
            // Q/K part, row-major bf16, stride 2048
#pragma unroll
            for (int m = 0; m < 4; ++m) {
                const int row0 = m0 + wr * 64 + m * 16 + l4 * 4;
#pragma unroll
                for (int r = 0; r < 4; ++r)
                    qkb[(size_t)(row0 + r) * 2048 + col] = f2bf(acc[m][n][r] + bv);
            }
        } else {
            // V part, transposed: vtb[(b*16+h)*64 + d][t], t = row
            const int h = (col - 2 * EMB) >> 6;
            const int d = col & 63;
#pragma unroll
            for (int m = 0; m < 4; ++m) {
                const int row0 = m0 + wr * 64 + m * 16 + l4 * 4;
                const int bb = row0 >> 11;
                const int t  = row0 & 2047;
                uint2 pk;
                pk.x = cvt_pk_bf16(acc[m][n][0] + bv, acc[m][n][1] + bv);
                pk.y = cvt_pk_bf16(acc[m][n][2] + bv, acc[m][n][3] + bv);
                *reinterpret_cast<uint2*>(
                    &vtb[((size_t)(bb * 16 + h) * 64 + d) * 2048 + t]) = pk;
            }
        }
    }
}

// ---------------------------------------------------------------------------
// MFMA flash attention, swapped-QK softmax. UNIFORM-WORK blocks:
// 512 threads (8 waves); block = (bh, pair p); processes q-tiles qt=p and
// qt=15-p SEQUENTIALLY -> every block runs exactly 34 kv-tile iterations.
// Grid 256 = 1 block/CU, constant 8 waves/CU, no imbalance tail.
// Wave w owns q rows [w*16, w*16+16) of the current 128-row q-tile.
// QUAD-buffered K/V; 2 kv-tiles per barrier; prefetch distance covers HBM.
// Critical-path-lean softmax (per-lane partial max + ballot; l via MFMA-ones).
// ---------------------------------------------------------------------------
__global__ __launch_bounds__(512) void attn_mfma(
    const ushort* __restrict__ qk, const ushort* __restrict__ vt,
    ushort* __restrict__ y)
{
    __shared__ alignas(16) ushort Kl[4][4096];
    __shared__ alignas(16) ushort Vl[4][4096];
    __shared__ alignas(16) ushort QP[8192];     // 128 rows x 64

    const int tid  = threadIdx.x;
    const int lane = tid & 63;
    const int w    = tid >> 6;     // wave 0..7
    const int l15  = lane & 15;
    const int l4   = lane >> 4;

    // block -> (bh, pair): 4 consecutive bh per XCD
    const int id  = blockIdx.x;                   // 0..255
    const int xcd = id & 7;
    const int bh  = xcd * 4 + ((id >> 3) & 3);    // 0..31
    const int pp  = id >> 5;                      // pair 0..7
    const int b   = bh >> 4;
    const int h   = bh & 15;

    const ushort* qbase = qk + (size_t)b * SEQ * 2048 + h * HD;
    const ushort* kbase = qbase + EMB;
    const ushort* vbase = vt + (size_t)bh * HD * SEQ;        // [d][t]

    const int swz   = (l15 & 7) << 4;
    const int koff0 = ((l4 * 16) ^ swz) >> 1;        // ushort units
    const int koff1 = ((64 + l4 * 16) ^ swz) >> 1;

    int pso[4];
#pragma unroll
    for (int n = 0; n < 4; ++n) pso[n] = ((n * 32 + l4 * 8) ^ swz) >> 1;

    const short OBF = (short)0x3F80;   // 1.0 bf16
    const bf16x8 ones = {OBF, OBF, OBF, OBF, OBF, OBF, OBF, OBF};
    const float BETA = 0.18033688f;    // 0.125 * log2(e)

    const int qrow = (w * 16 + l15) * 64;    // wave-local Q/P row base

    // staging coordinates (one 16B chunk per thread per 64x64 tile)
    const int sr = tid >> 3;                          // row 0..63
    const int sc = ((tid & 7) ^ (sr & 7)) << 3;       // swizzled col
    const int i2 = tid + 512;
    const int qr2 = i2 >> 3;
    const int qc2 = ((i2 & 7) ^ (qr2 & 7)) << 3;

#pragma unroll
    for (int pass = 0; pass < 2; ++pass) {
        const int qt  = pass ? (15 - pp) : pp;
        const int nkv = 2 * qt + 2;

        // ---- prologue: stage Q (128x64) + tiles 0,1 of K and V ----
        gload_lds16(qbase + (size_t)(qt * 128 + sr) * 2048 + sc, &QP[tid * 8]);
        gload_lds16(qbase + (size_t)(qt * 128 + qr2) * 2048 + qc2, &QP[i2 * 8]);
        gload_lds16(kbase + (size_t)sr * 2048 + sc, &Kl[0][tid * 8]);
        gload_lds16(kbase + (size_t)(64 + sr) * 2048 + sc, &Kl[1][tid * 8]);
        gload_lds16(vbase + (size_t)sr * 2048 + sc, &Vl[0][tid * 8]);
        gload_lds16(vbase + (size_t)sr * 2048 + 64 + sc, &Vl[1][tid * 8]);
        __syncthreads();

        const bf16x8 qf0 = *reinterpret_cast<const bf16x8*>(&QP[qrow + koff0]);
        const bf16x8 qf1 = *reinterpret_cast<const bf16x8*>(&QP[qrow + koff1]);

        f32x4 o[4];
#pragma unroll
        for (int n = 0; n < 4; ++n)
#pragma unroll
            for (int r = 0; r < 4; ++r) o[n][r] = 0.f;
        f32x4 lacc = {0.f, 0.f, 0.f, 0.f};
        float m = -3.0e38f;

        auto computeTile = [&](const ushort* Kb, const ushort* Vb, int kkt) {
            bf16x8 kf[4][2];
#pragma unroll
            for (int n = 0; n < 4; ++n) {
                kf[n][0] = *reinterpret_cast<const bf16x8*>(
                    &Kb[(n * 16 + l15) * 64 + koff0]);
                kf[n][1] = *reinterpret_cast<const bf16x8*>(
                    &Kb[(n * 16 + l15) * 64 + koff1]);
            }
            f32x4 s[4];
            __builtin_amdgcn_s_setprio(1);
#pragma unroll
            for (int n = 0; n < 4; ++n) {
                f32x4 z = {0.f, 0.f, 0.f, 0.f};
                z = __builtin_amdgcn_mfma_f32_16x16x32_bf16(kf[n][0], qf0, z, 0, 0, 0);
                s[n] = __builtin_amdgcn_mfma_f32_16x16x32_bf16(kf[n][1], qf1, z, 0, 0, 0);
            }
            __builtin_amdgcn_s_setprio(0);

            bf16x8 vf[4][2];
#pragma unroll
            for (int n = 0; n < 4; ++n) {
                vf[n][0] = *reinterpret_cast<const bf16x8*>(
                    &Vb[(n * 16 + l15) * 64 + koff0]);
                vf[n][1] = *reinterpret_cast<const bf16x8*>(
                    &Vb[(n * 16 + l15) * 64 + koff1]);
            }

            // causal mask: only the last two kv tiles can violate causality
            if (kkt >= nkv - 2) {
                const int q0 = qt * 128 + w * 16 + l15;
#pragma unroll
                for (int n = 0; n < 4; ++n)
#pragma unroll
                    for (int r = 0; r < 4; ++r) {
                        int kg = kkt * 64 + n * 16 + l4 * 4 + r;
                        if (kg > q0) s[n][r] = -3.0e38f;
                    }
            }

            // per-lane partial max (tree) -> conservative rescale check
            float a0 = fmaxf(fmaxf(s[0][0], s[0][1]), fmaxf(s[0][2], s[0][3]));
            float a1 = fmaxf(fmaxf(s[1][0], s[1][1]), fmaxf(s[1][2], s[1][3]));
            float a2 = fmaxf(fmaxf(s[2][0], s[2][1]), fmaxf(s[2][2], s[2][3]));
            float a3 = fmaxf(fmaxf(s[3][0], s[3][1]), fmaxf(s[3][2], s[3][3]));
            float pm = fmaxf(fmaxf(a0, a1), fmaxf(a2, a3)) * BETA;

            // defer-max rescale (rare, wave-uniform); ballot covers all (k,q)
            if (__any(pm > m + 8.0f)) {
                float tm = fmaxf(pm, __shfl_xor(pm, 16));
                tm = fmaxf(tm, __shfl_xor(tm, 32));
                float mn = fmaxf(m, tm);
                float al = exp2f(m - mn);
                m = mn;
                float b0 = __shfl(al, l4 * 4 + 0, 16);
                float b1 = __shfl(al, l4 * 4 + 1, 16);
                float b2 = __shfl(al, l4 * 4 + 2, 16);
                float b3 = __shfl(al, l4 * 4 + 3, 16);
                lacc[0] *= b0; lacc[1] *= b1; lacc[2] *= b2; lacc[3] *= b3;
#pragma unroll
                for (int n = 0; n < 4; ++n) {
                    o[n][0] *= b0; o[n][1] *= b1; o[n][2] *= b2; o[n][3] *= b3;
                }
            }

            // p = 2^(s*BETA - m), pack + store P (wave-local rows)
#pragma unroll
            for (int n = 0; n < 4; ++n) {
                float pa = exp2f(fmaf(s[n][0], BETA, -m));
                float pb = exp2f(fmaf(s[n][1], BETA, -m));
                float pc = exp2f(fmaf(s[n][2], BETA, -m));
                float pd = exp2f(fmaf(s[n][3], BETA, -m));
                uint2 pk;
                pk.x = cvt_pk_bf16(pa, pb);
                pk.y = cvt_pk_bf16(pc, pd);
                *reinterpret_cast<uint2*>(&QP[qrow + pso[n]]) = pk;
            }

            // O += P V, l += P·1
            bf16x8 pf0 = *reinterpret_cast<const bf16x8*>(&QP[qrow + koff0]);
            bf16x8 pf1 = *reinterpret_cast<const bf16x8*>(&QP[qrow + koff1]);
            __builtin_amdgcn_s_setprio(1);
            lacc = __builtin_amdgcn_mfma_f32_16x16x32_bf16(pf0, ones, lacc, 0, 0, 0);
            lacc = __builtin_amdgcn_mfma_f32_16x16x32_bf16(pf1, ones, lacc, 0, 0, 0);
#pragma unroll
            for (int n = 0; n < 4; ++n) {
                o[n] = __builtin_amdgcn_mfma_f32_16x16x32_bf16(pf0, vf[n][0], o[n], 0, 0, 0);
                o[n] = __builtin_amdgcn_mfma_f32_16x16x32_bf16(pf1, vf[n][1], o[n], 0, 0, 0);
            }
            __builtin_amdgcn_s_setprio(0);
        };

        for (int kk = 0; kk < nkv; kk += 2) {
            // stage tiles kk+2, kk+3 (one 16B chunk per thread per tile)
            if (kk + 2 < nkv) {
                const int b2 = (kk + 2) & 3;
                const int b3 = (kk + 3) & 3;
                gload_lds16(kbase + (size_t)((kk + 2) * 64 + sr) * 2048 + sc,
                            &Kl[b2][tid * 8]);
                gload_lds16(kbase + (size_t)((kk + 3) * 64 + sr) * 2048 + sc,
                            &Kl[b3][tid * 8]);
                gload_lds16(vbase + (size_t)sr * 2048 + (kk + 2) * 64 + sc,
                            &Vl[b2][tid * 8]);
                gload_lds16(vbase + (size_t)sr * 2048 + (kk + 3) * 64 + sc,
                            &Vl[b3][tid * 8]);
            }
            computeTile(Kl[kk & 3], Vl[kk & 3], kk);
            computeTile(Kl[(kk + 1) & 3], Vl[(kk + 1) & 3], kk + 1);
            __syncthreads();
        }

        // epilogue: O rows q = w*16 + l4*4 + r, cols d = n*16 + l15
#pragma unroll
        for (int r = 0; r < 4; ++r) {
            float inv = 1.f / lacc[r];
            int row = qt * 128 + w * 16 + l4 * 4 + r;
#pragma unroll
            for (int n = 0; n < 4; ++n) {
                y[(size_t)(b * SEQ + row) * EMB + h * HD + n * 16 + l15] =
                    f2bf(o[n][r] * inv);
            }
        }
        __syncthreads();   // LDS safe before next pass's prologue
    }
}

// ---------------------------------------------------------------------------
extern "C" void kernel_launch(void* const* d_in, const int* in_sizes, int n_in,
                              void* d_out, int out_size, void* d_ws, size_t ws_size,
                              hipStream_t stream)
{
    const float* x     = (const float*)d_in[0];   // [B,T,E]
    const float* qkv_w = (const float*)d_in[1];   // [3E,E]
    const float* qkv_b = (const float*)d_in[2];   // [3E]
    const float* o_w   = (const float*)d_in[3];   // [E,E]
    const float* o_b   = (const float*)d_in[4];   // [E]
    float* out = (float*)d_out;                   // [B,T,E] fp32

    // workspace (ushort units)
    ushort* xb    = (ushort*)d_ws;                       // 4M
    ushort* wqkvb = xb    + (size_t)M_ROWS * EMB;        // 3M
    ushort* owb   = wqkvb + (size_t)3 * EMB * EMB;       // 1M
    ushort* qkb   = owb   + (size_t)EMB * EMB;           // 8M  [4096][2048]
    ushort* vtb   = qkb   + (size_t)M_ROWS * 2 * EMB;    // 4M  [32][64][2048]
    ushort* ybb   = vtb   + (size_t)32 * HD * SEQ;       // 4M  [4096][1024]

    // 0) fused fp32 -> bf16 (x, qkv_w, o_w -> contiguous xb/wqkvb/owb)
    {
        int n1 = M_ROWS * EMB;        // 4M
        int n2 = 3 * EMB * EMB;       // 3M
        int ntot = n1 + n2 + EMB * EMB;
        cvt3_f32_bf16<<<ntot / 1024, 256, 0, stream>>>(
            x, qkv_w, o_w, xb, n1, n2);
    }

    // 1) QKV projection, split output: Q/K row-major, V transposed
    {
        dim3 grid(3 * EMB / 128, M_ROWS / 128);   // (24, 32)
        gemm_mfma_abt<1><<<grid, 256, 0, stream>>>(
            xb, wqkvb, qkv_b, nullptr, qkb, vtb, M_ROWS, 3 * EMB, EMB);
    }

    // 2) MFMA flash attention -> ybb (bf16 [M,E]); uniform-work blocks
    {
        attn_mfma<<<256, 512, 0, stream>>>(qkb, vtb, ybb);
    }

    // 3) Output projection (fp32 out)
    {
        dim3 grid(EMB / 128, M_ROWS / 128);       // (8, 32)
        gemm_mfma_abt<0><<<grid, 256, 0, stream>>>(
            ybb, owb, o_b, out, nullptr, nullptr, M_ROWS, EMB, EMB);
    }
}